// Round 1
// baseline (623.841 us; speedup 1.0000x reference)
//
#include <hip/hip_runtime.h>
#include <cstdint>

#define T_LEN 1024
#define NBIG  6272     // padded N for fused projection GEMM (6160 real cols)
#define SCALE_Q 0.08838834764831843f   // DK^-0.5

typedef __bf16 bf16;
typedef __bf16 bf16x8 __attribute__((ext_vector_type(8)));
typedef float  f32x4  __attribute__((ext_vector_type(4)));

__device__ __forceinline__ unsigned short f2bf(float f) {
  unsigned int u = __builtin_bit_cast(unsigned int, f);
  u += 0x7FFFu + ((u >> 16) & 1u);          // RNE
  return (unsigned short)(u >> 16);
}
__device__ __forceinline__ float silu_f(float x) { return x / (1.f + __expf(-x)); }

// ---------------- fp32 -> bf16 conversion (4 elems/thread) ----------------
__global__ __launch_bounds__(256) void cvt_bf16(const float* __restrict__ in,
                                                unsigned short* __restrict__ out, int n4) {
  int idx = blockIdx.x * 256 + threadIdx.x;
  if (idx >= n4) return;
  float4 f = ((const float4*)in)[idx];
  ushort4 o = { f2bf(f.x), f2bf(f.y), f2bf(f.z), f2bf(f.w) };
  ((ushort4*)out)[idx] = o;
}

// ------------- build concatenated weight matrix W[NBIG][2048] bf16 -------------
__global__ __launch_bounds__(256) void build_w(
    const float* __restrict__ qw, const float* __restrict__ kw,
    const float* __restrict__ vw, const float* __restrict__ gw,
    const float* __restrict__ aw, const float* __restrict__ bw,
    unsigned short* __restrict__ W) {
  int idx = blockIdx.x * 256 + threadIdx.x;   // quad id, exact grid
  int r = idx >> 9;                           // row (2048/4 = 512 quads per row)
  int c = (idx & 511) << 2;
  const float* src;
  if      (r < 1024) src = qw + (size_t)r * 2048;
  else if (r < 2048) src = kw + (size_t)(r - 1024) * 2048;
  else if (r < 4096) src = vw + (size_t)(r - 2048) * 2048;
  else if (r < 6144) src = gw + (size_t)(r - 4096) * 2048;
  else if (r < 6152) src = aw + (size_t)(r - 6144) * 2048;
  else if (r < 6160) src = bw + (size_t)(r - 6152) * 2048;
  else               src = nullptr;
  ushort4 o;
  if (src) {
    float4 f = *(const float4*)(src + c);
    o = { f2bf(f.x), f2bf(f.y), f2bf(f.z), f2bf(f.w) };
  } else {
    o = { 0, 0, 0, 0 };
  }
  *(ushort4*)(W + (size_t)r * 2048 + c) = o;
}

// ---------------- NT GEMM: C[M][N] = A[M][K] * B[N][K]^T, bf16 in, fp32 out ----------------
// m97 structure: 128x128 tile, BK=64, 4 waves (2x2), 16x16x32 MFMA, global_load_lds 16B
__global__ __launch_bounds__(256) void gemm_nt(
    const bf16* __restrict__ A, const bf16* __restrict__ Bm,
    float* __restrict__ C, int M, int N, int K) {
  __shared__ bf16 As[128 * 64];
  __shared__ bf16 Bs[128 * 64];
  const int tid = threadIdx.x;
  const int l = tid & 63;
  const int w = tid >> 6;
  const int wm = w >> 1, wn = w & 1;
  const long brow = (long)blockIdx.y * 128;
  const long bcol = (long)blockIdx.x * 128;

  f32x4 acc[4][4];
#pragma unroll
  for (int i = 0; i < 4; ++i)
#pragma unroll
    for (int j = 0; j < 4; ++j)
#pragma unroll
      for (int r = 0; r < 4; ++r) acc[i][j][r] = 0.f;

  const int rs = w * 8 + (l >> 3);   // staging row within 32-row group
  const int cs = (l & 7) * 8;        // staging col (elems)
  const bf16* Ag = A + (brow + rs) * (long)K + cs;
  const bf16* Bg = Bm + (bcol + rs) * (long)K + cs;
  bf16* AsW = As + tid * 8;          // == (rs*64 + cs), linear in lane order
  bf16* BsW = Bs + tid * 8;

  const int nkt = K >> 6;
  for (int kt = 0; kt < nkt; ++kt) {
    __syncthreads();
    const long ko = (long)kt * 64;
#pragma unroll
    for (int i = 0; i < 4; ++i) {
      __builtin_amdgcn_global_load_lds(
          (__attribute__((address_space(1))) void*)(void*)(Ag + (long)i * 32 * K + ko),
          (__attribute__((address_space(3))) void*)(AsW + i * 32 * 64), 16, 0, 0);
      __builtin_amdgcn_global_load_lds(
          (__attribute__((address_space(1))) void*)(void*)(Bg + (long)i * 32 * K + ko),
          (__attribute__((address_space(3))) void*)(BsW + i * 32 * 64), 16, 0, 0);
    }
    __syncthreads();
    const int row = l & 15;
    const int kof = (l >> 4) * 8;
#pragma unroll
    for (int kk = 0; kk < 2; ++kk) {
      bf16x8 af[4], bfr[4];
#pragma unroll
      for (int m = 0; m < 4; ++m)
        af[m] = *(const bf16x8*)(As + (wm * 64 + m * 16 + row) * 64 + kk * 32 + kof);
#pragma unroll
      for (int n = 0; n < 4; ++n)
        bfr[n] = *(const bf16x8*)(Bs + (wn * 64 + n * 16 + row) * 64 + kk * 32 + kof);
#pragma unroll
      for (int m = 0; m < 4; ++m)
#pragma unroll
        for (int n = 0; n < 4; ++n)
          acc[m][n] = __builtin_amdgcn_mfma_f32_16x16x32_bf16(af[m], bfr[n], acc[m][n], 0, 0, 0);
    }
  }
  // epilogue: C/D layout col=lane&15, row=(lane>>4)*4+r  [m89/m91 verified]
  const long row0 = brow + wm * 64 + ((l >> 4) * 4);
  const long col0 = bcol + wn * 64 + (l & 15);
#pragma unroll
  for (int m = 0; m < 4; ++m)
#pragma unroll
    for (int n = 0; n < 4; ++n)
#pragma unroll
      for (int r = 0; r < 4; ++r)
        C[(row0 + m * 16 + r) * (long)N + col0 + n * 16] = acc[m][n][r];
}

// ------------- conv(K=4)+SiLU+l2norm for q,k ; conv+SiLU for v ; gates ; qk dot -------------
__global__ __launch_bounds__(256) void convnorm(
    const float* __restrict__ Y,
    const float* __restrict__ qcw, const float* __restrict__ kcw, const float* __restrict__ vcw,
    const float* __restrict__ A_log, const float* __restrict__ dt_bias,
    float* __restrict__ qb, float* __restrict__ kb, float* __restrict__ vb,
    float* __restrict__ egb, float* __restrict__ betab, float* __restrict__ qkb) {
  const int bt = blockIdx.x;            // b*T + t
  const int t = bt & (T_LEN - 1);
  const int tid = threadIdx.x;

  float qn[4], kn[4];
  // ---- q: channels tid*4 .. +3 ----
  {
    const int c = tid * 4;
    float acc[4] = {0.f, 0.f, 0.f, 0.f};
#pragma unroll
    for (int j = 0; j < 4; ++j) {
      const int tt = t - 3 + j;
      if (tt < 0) continue;
      const float4 x = *(const float4*)(Y + (size_t)(bt - 3 + j) * NBIG + c);
      const float xv[4] = {x.x, x.y, x.z, x.w};
#pragma unroll
      for (int e = 0; e < 4; ++e) acc[e] += qcw[(c + e) * 4 + j] * xv[e];
    }
    float ss = 0.f;
#pragma unroll
    for (int e = 0; e < 4; ++e) { acc[e] = silu_f(acc[e]); ss += acc[e] * acc[e]; }
#pragma unroll
    for (int m = 16; m >= 1; m >>= 1) ss += __shfl_xor(ss, m);
    const float rn = rsqrtf(ss + 1e-6f) * SCALE_Q;   // fold DK^-0.5 into q
#pragma unroll
    for (int e = 0; e < 4; ++e) qn[e] = acc[e] * rn;
    float4 o = {qn[0], qn[1], qn[2], qn[3]};
    *(float4*)(qb + (size_t)bt * 1024 + c) = o;
  }
  // ---- k ----
  {
    const int c = tid * 4;
    float acc[4] = {0.f, 0.f, 0.f, 0.f};
#pragma unroll
    for (int j = 0; j < 4; ++j) {
      const int tt = t - 3 + j;
      if (tt < 0) continue;
      const float4 x = *(const float4*)(Y + (size_t)(bt - 3 + j) * NBIG + 1024 + c);
      const float xv[4] = {x.x, x.y, x.z, x.w};
#pragma unroll
      for (int e = 0; e < 4; ++e) acc[e] += kcw[(c + e) * 4 + j] * xv[e];
    }
    float ss = 0.f;
#pragma unroll
    for (int e = 0; e < 4; ++e) { acc[e] = silu_f(acc[e]); ss += acc[e] * acc[e]; }
#pragma unroll
    for (int m = 16; m >= 1; m >>= 1) ss += __shfl_xor(ss, m);
    const float rn = rsqrtf(ss + 1e-6f);
#pragma unroll
    for (int e = 0; e < 4; ++e) kn[e] = acc[e] * rn;
    float4 o = {kn[0], kn[1], kn[2], kn[3]};
    *(float4*)(kb + (size_t)bt * 1024 + c) = o;
  }
  // ---- qk[b,t,h] = q_scaled . k  (hoisted out of the scan) ----
  {
    float dp = qn[0] * kn[0] + qn[1] * kn[1] + qn[2] * kn[2] + qn[3] * kn[3];
#pragma unroll
    for (int m = 16; m >= 1; m >>= 1) dp += __shfl_xor(dp, m);
    if ((tid & 31) == 0) qkb[(size_t)bt * 8 + (tid >> 5)] = dp;
  }
  // ---- v: channels tid*8 .. +7 ----
  {
    const int c = tid * 8;
#pragma unroll
    for (int half = 0; half < 2; ++half) {
      const int c2 = c + half * 4;
      float acc[4] = {0.f, 0.f, 0.f, 0.f};
#pragma unroll
      for (int j = 0; j < 4; ++j) {
        const int tt = t - 3 + j;
        if (tt < 0) continue;
        const float4 x = *(const float4*)(Y + (size_t)(bt - 3 + j) * NBIG + 2048 + c2);
        const float xv[4] = {x.x, x.y, x.z, x.w};
#pragma unroll
        for (int e = 0; e < 4; ++e) acc[e] += vcw[(c2 + e) * 4 + j] * xv[e];
      }
#pragma unroll
      for (int e = 0; e < 4; ++e) acc[e] = silu_f(acc[e]);
      float4 o = {acc[0], acc[1], acc[2], acc[3]};
      *(float4*)(vb + (size_t)bt * 2048 + c2) = o;
    }
  }
  // ---- gates: eg = exp(g), beta = sigmoid ----
  if (tid < 8) {
    const int hh = tid;
    const float* Yb = Y + (size_t)bt * NBIG;
    float a = Yb[6144 + hh] + dt_bias[hh];
    float sp = (a > 20.f) ? a : log1pf(expf(a));
    float g = -expf(A_log[hh]) * sp;
    egb[(size_t)bt * 8 + hh] = expf(g);
    float bp = Yb[6152 + hh];
    betab[(size_t)bt * 8 + hh] = 1.f / (1.f + expf(-bp));
  }
}

// ---------------- gated delta-rule scan, per-v-column parallel ----------------
template <int CTRL>
__device__ __forceinline__ float dppadd(float x) {
  int y = __builtin_amdgcn_update_dpp(0, __builtin_bit_cast(int, x), CTRL, 0xF, 0xF, true);
  return x + __builtin_bit_cast(float, y);
}

__device__ __forceinline__ float dot8(const float4 a0, const float4 a1, const float S[8]) {
  float x = a0.x * S[0];
  x = fmaf(a0.y, S[1], x);
  x = fmaf(a0.z, S[2], x);
  x = fmaf(a0.w, S[3], x);
  float y = a1.x * S[4];
  y = fmaf(a1.y, S[5], y);
  y = fmaf(a1.z, S[6], y);
  y = fmaf(a1.w, S[7], y);
  return x + y;
}

__global__ __launch_bounds__(256) void scan_kernel(
    const float* __restrict__ qb, const float* __restrict__ kb, const float* __restrict__ vb,
    const float* __restrict__ egb, const float* __restrict__ betab, const float* __restrict__ qkb,
    float* __restrict__ ob) {
  const int tid = threadIdx.x;
  const int colg = tid >> 4;            // 16 columns per block
  const int s = tid & 15;               // 16 lanes per column, 8 k-elems each
  const int blk = blockIdx.x;           // 256 blocks = 16 bh * 16 vblk
  const int bh = blk >> 4;
  const int vblk = blk & 15;
  const int b = bh >> 3, h = bh & 7;
  const int vcol = vblk * 16 + colg;

  const float* qp = qb + (size_t)b * T_LEN * 1024 + h * 128 + s * 8;
  const float* kp = kb + (size_t)b * T_LEN * 1024 + h * 128 + s * 8;
  const float* vp = vb + (size_t)b * T_LEN * 2048 + h * 256 + vcol;
  const float* egp = egb + (size_t)b * T_LEN * 8 + h;
  const float* bep = betab + (size_t)b * T_LEN * 8 + h;
  const float* qkp = qkb + (size_t)b * T_LEN * 8 + h;
  float* op = ob + ((size_t)b * T_LEN * 8 + h) * 256 + vcol;

  float S[8];
#pragma unroll
  for (int i = 0; i < 8; ++i) S[i] = 0.f;

  float4 ck0 = *(const float4*)kp, ck1 = *(const float4*)(kp + 4);
  float4 cq0 = *(const float4*)qp, cq1 = *(const float4*)(qp + 4);
  float cd = *egp, cbt = *bep, cqk = *qkp, cvt = *vp;

  for (int t = 0; t < T_LEN; ++t) {
    // prefetch next step (one-row overread at the end lands in adjacent ws buffers)
    kp += 1024; qp += 1024; vp += 2048; egp += 8; bep += 8; qkp += 8;
    const float4 nk0 = *(const float4*)kp, nk1 = *(const float4*)(kp + 4);
    const float4 nq0 = *(const float4*)qp, nq1 = *(const float4*)(qp + 4);
    const float nd = *egp, nbt = *bep, nqk = *qkp, nvt = *vp;

    // both dots on OLD state; decay folded in after reduction
    float p1 = dot8(ck0, ck1, S);   // k . S_old
    float p2 = dot8(cq0, cq1, S);   // q . S_old
    // dual interleaved 16-lane DPP rotate-reduce
    p1 = dppadd<0x128>(p1); p2 = dppadd<0x128>(p2);
    p1 = dppadd<0x124>(p1); p2 = dppadd<0x124>(p2);
    p1 = dppadd<0x122>(p1); p2 = dppadd<0x122>(p2);
    p1 = dppadd<0x121>(p1); p2 = dppadd<0x121>(p2);

    const float u = (cvt - cd * p1) * cbt;          // u = (v - k.S_d) * beta
    const float ov = fmaf(cd, p2, cqk * u);         // o = q.S_d + (q.k)*u
    const float kk[8] = {ck0.x, ck0.y, ck0.z, ck0.w, ck1.x, ck1.y, ck1.z, ck1.w};
#pragma unroll
    for (int i = 0; i < 8; ++i) S[i] = fmaf(cd, S[i], kk[i] * u);

    if (s == 0) *op = ov;
    op += 2048;
    ck0 = nk0; ck1 = nk1; cq0 = nq0; cq1 = nq1;
    cd = nd; cbt = nbt; cqk = nqk; cvt = nvt;
  }
}

// ---------------- gated RMSNorm + silu(gate) -> bf16 ----------------
__global__ __launch_bounds__(256) void rmsgate(
    const float* __restrict__ ob, const float* __restrict__ Y,
    const float* __restrict__ onw, unsigned short* __restrict__ Obf) {
  const int bt = blockIdx.x;
  const int tid = threadIdx.x;
  const int c = tid * 8;                // head = c/256 = tid/32
  const float* orow = ob + (size_t)bt * 2048 + c;
  const float* grow = Y + (size_t)bt * NBIG + 4096 + c;
  const float4 o0 = *(const float4*)orow, o1 = *(const float4*)(orow + 4);
  const float4 g0 = *(const float4*)grow, g1 = *(const float4*)(grow + 4);
  const float ov[8] = {o0.x, o0.y, o0.z, o0.w, o1.x, o1.y, o1.z, o1.w};
  const float gv[8] = {g0.x, g0.y, g0.z, g0.w, g1.x, g1.y, g1.z, g1.w};
  float ss = 0.f;
#pragma unroll
  for (int e = 0; e < 8; ++e) ss += ov[e] * ov[e];
#pragma unroll
  for (int m = 16; m >= 1; m >>= 1) ss += __shfl_xor(ss, m);
  const float rn = rsqrtf(ss * (1.f / 256.f) + 1e-5f);
  const int dv = c & 255;
  unsigned short rr[8];
#pragma unroll
  for (int e = 0; e < 8; ++e) {
    const float val = ov[e] * rn * onw[dv + e] * silu_f(gv[e]);
    rr[e] = f2bf(val);
  }
  ushort4 r0 = {rr[0], rr[1], rr[2], rr[3]};
  ushort4 r1 = {rr[4], rr[5], rr[6], rr[7]};
  *(ushort4*)(Obf + (size_t)bt * 2048 + c) = r0;
  *(ushort4*)(Obf + (size_t)bt * 2048 + c + 4) = r1;
}

extern "C" void kernel_launch(void* const* d_in, const int* in_sizes, int n_in,
                              void* d_out, int out_size, void* d_ws, size_t ws_size,
                              hipStream_t stream) {
  (void)in_sizes; (void)n_in; (void)out_size; (void)ws_size;
  const float* h    = (const float*)d_in[0];
  const float* qw   = (const float*)d_in[1];
  const float* kw   = (const float*)d_in[2];
  const float* vw   = (const float*)d_in[3];
  const float* aw   = (const float*)d_in[4];
  const float* bw   = (const float*)d_in[5];
  const float* gw   = (const float*)d_in[6];
  const float* ow   = (const float*)d_in[7];
  const float* qcw  = (const float*)d_in[8];
  const float* kcw  = (const float*)d_in[9];
  const float* vcw  = (const float*)d_in[10];
  const float* Alog = (const float*)d_in[11];
  const float* dtb  = (const float*)d_in[12];
  const float* onw  = (const float*)d_in[13];

  char* ws = (char*)d_ws;
  size_t off = 0;
  auto alloc = [&](size_t bytes) {
    char* p = ws + off;
    off = (off + bytes + 255) & ~(size_t)255;
    return p;
  };
  // order matters: scan prefetch overreads one row; keep scan inputs followed by other buffers
  float* qb            = (float*)alloc(2048ull * 1024 * 4);
  float* kb            = (float*)alloc(2048ull * 1024 * 4);
  float* vb            = (float*)alloc(2048ull * 2048 * 4);
  float* egb           = (float*)alloc(2048ull * 8 * 4);
  float* betab         = (float*)alloc(2048ull * 8 * 4);
  float* qkb           = (float*)alloc(2048ull * 8 * 4);
  unsigned short* hbf  = (unsigned short*)alloc(2048ull * 2048 * 2);
  unsigned short* Wb   = (unsigned short*)alloc((size_t)NBIG * 2048 * 2);
  unsigned short* owb  = (unsigned short*)alloc(2048ull * 2048 * 2);
  float* Y             = (float*)alloc(2048ull * NBIG * 4);
  float* osc           = (float*)alloc(2048ull * 2048 * 4);
  unsigned short* Obf  = (unsigned short*)alloc(2048ull * 2048 * 2);

  cvt_bf16<<<4096, 256, 0, stream>>>(h, hbf, 1048576);
  build_w<<<12544, 256, 0, stream>>>(qw, kw, vw, gw, aw, bw, Wb);
  cvt_bf16<<<4096, 256, 0, stream>>>(ow, owb, 1048576);
  gemm_nt<<<dim3(NBIG / 128, 16), 256, 0, stream>>>((const bf16*)hbf, (const bf16*)Wb, Y,
                                                    2048, NBIG, 2048);
  convnorm<<<2048, 256, 0, stream>>>(Y, qcw, kcw, vcw, Alog, dtb, qb, kb, vb, egb, betab, qkb);
  scan_kernel<<<256, 256, 0, stream>>>(qb, kb, vb, egb, betab, qkb, osc);
  rmsgate<<<2048, 256, 0, stream>>>(osc, Y, onw, Obf);
  gemm_nt<<<dim3(16, 16), 256, 0, stream>>>((const bf16*)Obf, (const bf16*)owb, (float*)d_out,
                                            2048, 2048, 2048);
}

// Round 2
// 423.880 us; speedup vs baseline: 1.4717x; 1.4717x over previous
//
#include <hip/hip_runtime.h>
#include <cstdint>

#define T_LEN 1024
#define NBIG  6272     // padded N for fused projection GEMM (6160 real cols)
#define SCALE_Q 0.08838834764831843f   // DK^-0.5
#define CH 32          // scan steps per LDS chunk

typedef __bf16 bf16;
typedef __bf16 bf16x8 __attribute__((ext_vector_type(8)));
typedef float  f32x4  __attribute__((ext_vector_type(4)));

__device__ __forceinline__ unsigned short f2bf(float f) {
  unsigned int u = __builtin_bit_cast(unsigned int, f);
  u += 0x7FFFu + ((u >> 16) & 1u);          // RNE
  return (unsigned short)(u >> 16);
}
__device__ __forceinline__ float silu_f(float x) { return x / (1.f + __expf(-x)); }

// ---------------- fp32 -> bf16 conversion (4 elems/thread) ----------------
__global__ __launch_bounds__(256) void cvt_bf16(const float* __restrict__ in,
                                                unsigned short* __restrict__ out, int n4) {
  int idx = blockIdx.x * 256 + threadIdx.x;
  if (idx >= n4) return;
  float4 f = ((const float4*)in)[idx];
  ushort4 o = { f2bf(f.x), f2bf(f.y), f2bf(f.z), f2bf(f.w) };
  ((ushort4*)out)[idx] = o;
}

// ------------- build concatenated weight matrix W[NBIG][2048] bf16 -------------
__global__ __launch_bounds__(256) void build_w(
    const float* __restrict__ qw, const float* __restrict__ kw,
    const float* __restrict__ vw, const float* __restrict__ gw,
    const float* __restrict__ aw, const float* __restrict__ bw,
    unsigned short* __restrict__ W) {
  int idx = blockIdx.x * 256 + threadIdx.x;   // quad id, exact grid
  int r = idx >> 9;                           // row (2048/4 = 512 quads per row)
  int c = (idx & 511) << 2;
  const float* src;
  if      (r < 1024) src = qw + (size_t)r * 2048;
  else if (r < 2048) src = kw + (size_t)(r - 1024) * 2048;
  else if (r < 4096) src = vw + (size_t)(r - 2048) * 2048;
  else if (r < 6144) src = gw + (size_t)(r - 4096) * 2048;
  else if (r < 6152) src = aw + (size_t)(r - 6144) * 2048;
  else if (r < 6160) src = bw + (size_t)(r - 6152) * 2048;
  else               src = nullptr;
  ushort4 o;
  if (src) {
    float4 f = *(const float4*)(src + c);
    o = { f2bf(f.x), f2bf(f.y), f2bf(f.z), f2bf(f.w) };
  } else {
    o = { 0, 0, 0, 0 };
  }
  *(ushort4*)(W + (size_t)r * 2048 + c) = o;
}

// ---------------- NT GEMM: C[M][N] = A[M][K] * B[N][K]^T, bf16 in, fp32 out ----------------
// m97 structure: 128x128 tile, BK=64, 4 waves (2x2), 16x16x32 MFMA, global_load_lds 16B
__global__ __launch_bounds__(256) void gemm_nt(
    const bf16* __restrict__ A, const bf16* __restrict__ Bm,
    float* __restrict__ C, int M, int N, int K) {
  __shared__ bf16 As[128 * 64];
  __shared__ bf16 Bs[128 * 64];
  const int tid = threadIdx.x;
  const int l = tid & 63;
  const int w = tid >> 6;
  const int wm = w >> 1, wn = w & 1;
  const long brow = (long)blockIdx.y * 128;
  const long bcol = (long)blockIdx.x * 128;

  f32x4 acc[4][4];
#pragma unroll
  for (int i = 0; i < 4; ++i)
#pragma unroll
    for (int j = 0; j < 4; ++j)
#pragma unroll
      for (int r = 0; r < 4; ++r) acc[i][j][r] = 0.f;

  const int rs = w * 8 + (l >> 3);   // staging row within 32-row group
  const int cs = (l & 7) * 8;        // staging col (elems)
  const bf16* Ag = A + (brow + rs) * (long)K + cs;
  const bf16* Bg = Bm + (bcol + rs) * (long)K + cs;
  bf16* AsW = As + tid * 8;          // == (rs*64 + cs), linear in lane order
  bf16* BsW = Bs + tid * 8;

  const int nkt = K >> 6;
  for (int kt = 0; kt < nkt; ++kt) {
    __syncthreads();
    const long ko = (long)kt * 64;
#pragma unroll
    for (int i = 0; i < 4; ++i) {
      __builtin_amdgcn_global_load_lds(
          (__attribute__((address_space(1))) void*)(void*)(Ag + (long)i * 32 * K + ko),
          (__attribute__((address_space(3))) void*)(AsW + i * 32 * 64), 16, 0, 0);
      __builtin_amdgcn_global_load_lds(
          (__attribute__((address_space(1))) void*)(void*)(Bg + (long)i * 32 * K + ko),
          (__attribute__((address_space(3))) void*)(BsW + i * 32 * 64), 16, 0, 0);
    }
    __syncthreads();
    const int row = l & 15;
    const int kof = (l >> 4) * 8;
#pragma unroll
    for (int kk = 0; kk < 2; ++kk) {
      bf16x8 af[4], bfr[4];
#pragma unroll
      for (int m = 0; m < 4; ++m)
        af[m] = *(const bf16x8*)(As + (wm * 64 + m * 16 + row) * 64 + kk * 32 + kof);
#pragma unroll
      for (int n = 0; n < 4; ++n)
        bfr[n] = *(const bf16x8*)(Bs + (wn * 64 + n * 16 + row) * 64 + kk * 32 + kof);
#pragma unroll
      for (int m = 0; m < 4; ++m)
#pragma unroll
        for (int n = 0; n < 4; ++n)
          acc[m][n] = __builtin_amdgcn_mfma_f32_16x16x32_bf16(af[m], bfr[n], acc[m][n], 0, 0, 0);
    }
  }
  // epilogue: C/D layout col=lane&15, row=(lane>>4)*4+r  [m89/m91 verified]
  const long row0 = brow + wm * 64 + ((l >> 4) * 4);
  const long col0 = bcol + wn * 64 + (l & 15);
#pragma unroll
  for (int m = 0; m < 4; ++m)
#pragma unroll
    for (int n = 0; n < 4; ++n)
#pragma unroll
      for (int r = 0; r < 4; ++r)
        C[(row0 + m * 16 + r) * (long)N + col0 + n * 16] = acc[m][n][r];
}

// ------------- conv(K=4)+SiLU+l2norm for q,k ; conv+SiLU for v ; packed scalars -------------
__global__ __launch_bounds__(256) void convnorm(
    const float* __restrict__ Y,
    const float* __restrict__ qcw, const float* __restrict__ kcw, const float* __restrict__ vcw,
    const float* __restrict__ A_log, const float* __restrict__ dt_bias,
    float* __restrict__ qb, float* __restrict__ kb, float* __restrict__ vb,
    float* __restrict__ scb) {
  const int bt = blockIdx.x;            // b*T + t
  const int t = bt & (T_LEN - 1);
  const int tid = threadIdx.x;
  __shared__ float qk_sh[8];

  float qn[4], kn[4];
  // ---- q: channels tid*4 .. +3 ----
  {
    const int c = tid * 4;
    float acc[4] = {0.f, 0.f, 0.f, 0.f};
#pragma unroll
    for (int j = 0; j < 4; ++j) {
      const int tt = t - 3 + j;
      if (tt < 0) continue;
      const float4 x = *(const float4*)(Y + (size_t)(bt - 3 + j) * NBIG + c);
      const float xv[4] = {x.x, x.y, x.z, x.w};
#pragma unroll
      for (int e = 0; e < 4; ++e) acc[e] += qcw[(c + e) * 4 + j] * xv[e];
    }
    float ss = 0.f;
#pragma unroll
    for (int e = 0; e < 4; ++e) { acc[e] = silu_f(acc[e]); ss += acc[e] * acc[e]; }
#pragma unroll
    for (int m = 16; m >= 1; m >>= 1) ss += __shfl_xor(ss, m);
    const float rn = rsqrtf(ss + 1e-6f) * SCALE_Q;   // fold DK^-0.5 into q
#pragma unroll
    for (int e = 0; e < 4; ++e) qn[e] = acc[e] * rn;
    float4 o = {qn[0], qn[1], qn[2], qn[3]};
    *(float4*)(qb + (size_t)bt * 1024 + c) = o;
  }
  // ---- k ----
  {
    const int c = tid * 4;
    float acc[4] = {0.f, 0.f, 0.f, 0.f};
#pragma unroll
    for (int j = 0; j < 4; ++j) {
      const int tt = t - 3 + j;
      if (tt < 0) continue;
      const float4 x = *(const float4*)(Y + (size_t)(bt - 3 + j) * NBIG + 1024 + c);
      const float xv[4] = {x.x, x.y, x.z, x.w};
#pragma unroll
      for (int e = 0; e < 4; ++e) acc[e] += kcw[(c + e) * 4 + j] * xv[e];
    }
    float ss = 0.f;
#pragma unroll
    for (int e = 0; e < 4; ++e) { acc[e] = silu_f(acc[e]); ss += acc[e] * acc[e]; }
#pragma unroll
    for (int m = 16; m >= 1; m >>= 1) ss += __shfl_xor(ss, m);
    const float rn = rsqrtf(ss + 1e-6f);
#pragma unroll
    for (int e = 0; e < 4; ++e) kn[e] = acc[e] * rn;
    float4 o = {kn[0], kn[1], kn[2], kn[3]};
    *(float4*)(kb + (size_t)bt * 1024 + c) = o;
  }
  // ---- qk[b,t,h] = q_scaled . k  (hoisted out of the scan) ----
  {
    float dp = qn[0] * kn[0] + qn[1] * kn[1] + qn[2] * kn[2] + qn[3] * kn[3];
#pragma unroll
    for (int m = 16; m >= 1; m >>= 1) dp += __shfl_xor(dp, m);
    if ((tid & 31) == 0) qk_sh[tid >> 5] = dp;
  }
  // ---- v: channels tid*8 .. +7 ----
  {
    const int c = tid * 8;
#pragma unroll
    for (int half = 0; half < 2; ++half) {
      const int c2 = c + half * 4;
      float acc[4] = {0.f, 0.f, 0.f, 0.f};
#pragma unroll
      for (int j = 0; j < 4; ++j) {
        const int tt = t - 3 + j;
        if (tt < 0) continue;
        const float4 x = *(const float4*)(Y + (size_t)(bt - 3 + j) * NBIG + 2048 + c2);
        const float xv[4] = {x.x, x.y, x.z, x.w};
#pragma unroll
        for (int e = 0; e < 4; ++e) acc[e] += vcw[(c2 + e) * 4 + j] * xv[e];
      }
#pragma unroll
      for (int e = 0; e < 4; ++e) acc[e] = silu_f(acc[e]);
      float4 o = {acc[0], acc[1], acc[2], acc[3]};
      *(float4*)(vb + (size_t)bt * 2048 + c2) = o;
    }
  }
  __syncthreads();
  // ---- packed per-step scalars: {exp(g), beta, q.k, 0} ----
  if (tid < 8) {
    const int hh = tid;
    const float* Yb = Y + (size_t)bt * NBIG;
    float a = Yb[6144 + hh] + dt_bias[hh];
    float sp = (a > 20.f) ? a : log1pf(expf(a));
    float g = -expf(A_log[hh]) * sp;
    float eg = expf(g);
    float bp = Yb[6152 + hh];
    float be = 1.f / (1.f + expf(-bp));
    float4 o = {eg, be, qk_sh[hh], 0.f};
    *(float4*)(scb + ((size_t)bt * 8 + hh) * 4) = o;
  }
}

// ---------------- gated delta-rule scan, per-v-column parallel, LDS-chunked ----------------
template <int CTRL>
__device__ __forceinline__ float dppadd(float x) {
  int y = __builtin_amdgcn_update_dpp(0, __builtin_bit_cast(int, x), CTRL, 0xF, 0xF, true);
  return x + __builtin_bit_cast(float, y);
}

__device__ __forceinline__ float dot8(const float4 a0, const float4 a1, const float S[8]) {
  float x = a0.x * S[0];
  x = fmaf(a0.y, S[1], x);
  x = fmaf(a0.z, S[2], x);
  x = fmaf(a0.w, S[3], x);
  float y = a1.x * S[4];
  y = fmaf(a1.y, S[5], y);
  y = fmaf(a1.z, S[6], y);
  y = fmaf(a1.w, S[7], y);
  return x + y;
}

// LDS layout per chunk buffer:
//   qld/kld: [CH][32 float4-slots]; slot s   = row[t] floats s*8..s*8+3  (lane s low half)
//                                   slot 16+s= row[t] floats s*8+4..+7   (lane s high half)
//   vld: [CH][16 floats] (block's 16 v-columns);  scld: [CH] float4 {eg,beta,qk,0}
__device__ __forceinline__ void stage_chunk(
    const float* __restrict__ qb, const float* __restrict__ kb,
    const float* __restrict__ vb, const float* __restrict__ scb,
    float* qld, float* kld, float* vld, float* scld,
    int bt0, int h, int vblk, int tid) {
#pragma unroll
  for (int i = 0; i < 4; ++i) {
    const int f = i * 256 + tid;
    const int t = f >> 5, slot = f & 31;
    const int col4 = (slot < 16) ? (slot << 1) : (((slot - 16) << 1) | 1);
    __builtin_amdgcn_global_load_lds(
        (__attribute__((address_space(1))) void*)(void*)(qb + (size_t)(bt0 + t) * 1024 + h * 128 + col4 * 4),
        (__attribute__((address_space(3))) void*)(qld + (size_t)f * 4), 16, 0, 0);
  }
#pragma unroll
  for (int i = 0; i < 4; ++i) {
    const int f = i * 256 + tid;
    const int t = f >> 5, slot = f & 31;
    const int col4 = (slot < 16) ? (slot << 1) : (((slot - 16) << 1) | 1);
    __builtin_amdgcn_global_load_lds(
        (__attribute__((address_space(1))) void*)(void*)(kb + (size_t)(bt0 + t) * 1024 + h * 128 + col4 * 4),
        (__attribute__((address_space(3))) void*)(kld + (size_t)f * 4), 16, 0, 0);
  }
  if (tid < 128) {                       // v: 32 t x 16 cols = 128 float4-slots
    const int t = tid >> 2, c4 = tid & 3;
    __builtin_amdgcn_global_load_lds(
        (__attribute__((address_space(1))) void*)(void*)(vb + (size_t)(bt0 + t) * 2048 + h * 256 + vblk * 16 + c4 * 4),
        (__attribute__((address_space(3))) void*)(vld + (size_t)tid * 4), 16, 0, 0);
  } else if (tid < 160) {                // scalars: 32 float4 slots
    const int t = tid - 128;
    __builtin_amdgcn_global_load_lds(
        (__attribute__((address_space(1))) void*)(void*)(scb + ((size_t)(bt0 + t) * 8 + h) * 4),
        (__attribute__((address_space(3))) void*)(scld + (size_t)t * 4), 16, 0, 0);
  }
}

__global__ __launch_bounds__(256) void scan_kernel(
    const float* __restrict__ qb, const float* __restrict__ kb, const float* __restrict__ vb,
    const float* __restrict__ scb, float* __restrict__ ob) {
  __shared__ float qld[2][CH * 128];
  __shared__ float kld[2][CH * 128];
  __shared__ float vld[2][CH * 16];
  __shared__ float scld[2][CH * 4];

  const int tid = threadIdx.x;
  const int colg = tid >> 4;            // 16 columns per block
  const int s = tid & 15;               // 16 lanes per column, 8 k-elems each
  const int blk = blockIdx.x;           // 256 blocks = 16 bh * 16 vblk
  const int bh = blk >> 4;
  const int vblk = blk & 15;
  const int b = bh >> 3, h = bh & 7;
  const int vcol = vblk * 16 + colg;

  float* op = ob + (size_t)b * T_LEN * 2048 + h * 256 + vcol;

  float S[8];
#pragma unroll
  for (int i = 0; i < 8; ++i) S[i] = 0.f;

  stage_chunk(qb, kb, vb, scb, qld[0], kld[0], vld[0], scld[0],
              b * T_LEN, h, vblk, tid);

  const int NC = T_LEN / CH;
  int buf = 0;
  for (int c = 0; c < NC; ++c) {
    __syncthreads();                    // compiler drains vmcnt before s_barrier
    if (c + 1 < NC)
      stage_chunk(qb, kb, vb, scb, qld[buf ^ 1], kld[buf ^ 1], vld[buf ^ 1], scld[buf ^ 1],
                  b * T_LEN + (c + 1) * CH, h, vblk, tid);

    const float* qL = qld[buf];
    const float* kL = kld[buf];
    const float* vL = vld[buf];
    const float* sL = scld[buf];

    float4 ck0 = *(const float4*)(kL + (size_t)s * 4);
    float4 ck1 = *(const float4*)(kL + (size_t)(16 + s) * 4);
    float4 cq0 = *(const float4*)(qL + (size_t)s * 4);
    float4 cq1 = *(const float4*)(qL + (size_t)(16 + s) * 4);
    float4 csc = *(const float4*)(sL);
    float  cvt = vL[colg];

#pragma unroll
    for (int t = 0; t < CH; ++t) {
      float4 nk0, nk1, nq0, nq1, nsc;
      float nvt;
      if (t < CH - 1) {
        nk0 = *(const float4*)(kL + ((size_t)(t + 1) * 32 + s) * 4);
        nk1 = *(const float4*)(kL + ((size_t)(t + 1) * 32 + 16 + s) * 4);
        nq0 = *(const float4*)(qL + ((size_t)(t + 1) * 32 + s) * 4);
        nq1 = *(const float4*)(qL + ((size_t)(t + 1) * 32 + 16 + s) * 4);
        nsc = *(const float4*)(sL + (size_t)(t + 1) * 4);
        nvt = vL[(t + 1) * 16 + colg];
      }
      const float cd = csc.x, cbt = csc.y, cqk = csc.z;

      // both dots on OLD state; decay folded in after reduction
      float p1 = dot8(ck0, ck1, S);   // k . S_old
      float p2 = dot8(cq0, cq1, S);   // q . S_old
      p1 = dppadd<0x128>(p1); p2 = dppadd<0x128>(p2);
      p1 = dppadd<0x124>(p1); p2 = dppadd<0x124>(p2);
      p1 = dppadd<0x122>(p1); p2 = dppadd<0x122>(p2);
      p1 = dppadd<0x121>(p1); p2 = dppadd<0x121>(p2);

      const float u = (cvt - cd * p1) * cbt;          // u = (v - k.S_d) * beta
      const float ov = fmaf(cd, p2, cqk * u);         // o = q.S_d + (q.k)*u
      const float kk[8] = {ck0.x, ck0.y, ck0.z, ck0.w, ck1.x, ck1.y, ck1.z, ck1.w};
#pragma unroll
      for (int i = 0; i < 8; ++i) S[i] = fmaf(cd, S[i], kk[i] * u);

      if (s == 0) *op = ov;
      op += 2048;
      if (t < CH - 1) {
        ck0 = nk0; ck1 = nk1; cq0 = nq0; cq1 = nq1; csc = nsc; cvt = nvt;
      }
    }
    buf ^= 1;
  }
}

// ---------------- gated RMSNorm + silu(gate) -> bf16 ----------------
__global__ __launch_bounds__(256) void rmsgate(
    const float* __restrict__ ob, const float* __restrict__ Y,
    const float* __restrict__ onw, unsigned short* __restrict__ Obf) {
  const int bt = blockIdx.x;
  const int tid = threadIdx.x;
  const int c = tid * 8;                // head = c/256 = tid/32
  const float* orow = ob + (size_t)bt * 2048 + c;
  const float* grow = Y + (size_t)bt * NBIG + 4096 + c;
  const float4 o0 = *(const float4*)orow, o1 = *(const float4*)(orow + 4);
  const float4 g0 = *(const float4*)grow, g1 = *(const float4*)(grow + 4);
  const float ov[8] = {o0.x, o0.y, o0.z, o0.w, o1.x, o1.y, o1.z, o1.w};
  const float gv[8] = {g0.x, g0.y, g0.z, g0.w, g1.x, g1.y, g1.z, g1.w};
  float ss = 0.f;
#pragma unroll
  for (int e = 0; e < 8; ++e) ss += ov[e] * ov[e];
#pragma unroll
  for (int m = 16; m >= 1; m >>= 1) ss += __shfl_xor(ss, m);
  const float rn = rsqrtf(ss * (1.f / 256.f) + 1e-5f);
  const int dv = c & 255;
  unsigned short rr[8];
#pragma unroll
  for (int e = 0; e < 8; ++e) {
    const float val = ov[e] * rn * onw[dv + e] * silu_f(gv[e]);
    rr[e] = f2bf(val);
  }
  ushort4 r0 = {rr[0], rr[1], rr[2], rr[3]};
  ushort4 r1 = {rr[4], rr[5], rr[6], rr[7]};
  *(ushort4*)(Obf + (size_t)bt * 2048 + c) = r0;
  *(ushort4*)(Obf + (size_t)bt * 2048 + c + 4) = r1;
}

extern "C" void kernel_launch(void* const* d_in, const int* in_sizes, int n_in,
                              void* d_out, int out_size, void* d_ws, size_t ws_size,
                              hipStream_t stream) {
  (void)in_sizes; (void)n_in; (void)out_size; (void)ws_size;
  const float* h    = (const float*)d_in[0];
  const float* qw   = (const float*)d_in[1];
  const float* kw   = (const float*)d_in[2];
  const float* vw   = (const float*)d_in[3];
  const float* aw   = (const float*)d_in[4];
  const float* bw   = (const float*)d_in[5];
  const float* gw   = (const float*)d_in[6];
  const float* ow   = (const float*)d_in[7];
  const float* qcw  = (const float*)d_in[8];
  const float* kcw  = (const float*)d_in[9];
  const float* vcw  = (const float*)d_in[10];
  const float* Alog = (const float*)d_in[11];
  const float* dtb  = (const float*)d_in[12];
  const float* onw  = (const float*)d_in[13];

  char* ws = (char*)d_ws;
  size_t off = 0;
  auto alloc = [&](size_t bytes) {
    char* p = ws + off;
    off = (off + bytes + 255) & ~(size_t)255;
    return p;
  };
  float* qb            = (float*)alloc(2048ull * 1024 * 4);
  float* kb            = (float*)alloc(2048ull * 1024 * 4);
  float* vb            = (float*)alloc(2048ull * 2048 * 4);
  float* scb           = (float*)alloc(2048ull * 8 * 16);
  unsigned short* hbf  = (unsigned short*)alloc(2048ull * 2048 * 2);
  unsigned short* Wb   = (unsigned short*)alloc((size_t)NBIG * 2048 * 2);
  unsigned short* owb  = (unsigned short*)alloc(2048ull * 2048 * 2);
  float* Y             = (float*)alloc(2048ull * NBIG * 4);
  float* osc           = (float*)alloc(2048ull * 2048 * 4);
  unsigned short* Obf  = (unsigned short*)alloc(2048ull * 2048 * 2);

  cvt_bf16<<<4096, 256, 0, stream>>>(h, hbf, 1048576);
  build_w<<<12544, 256, 0, stream>>>(qw, kw, vw, gw, aw, bw, Wb);
  cvt_bf16<<<4096, 256, 0, stream>>>(ow, owb, 1048576);
  gemm_nt<<<dim3(NBIG / 128, 16), 256, 0, stream>>>((const bf16*)hbf, (const bf16*)Wb, Y,
                                                    2048, NBIG, 2048);
  convnorm<<<2048, 256, 0, stream>>>(Y, qcw, kcw, vcw, Alog, dtb, qb, kb, vb, scb);
  scan_kernel<<<256, 256, 0, stream>>>(qb, kb, vb, scb, osc);
  rmsgate<<<2048, 256, 0, stream>>>(osc, Y, onw, Obf);
  gemm_nt<<<dim3(16, 16), 256, 0, stream>>>((const bf16*)Obf, (const bf16*)owb, (float*)d_out,
                                            2048, 2048, 2048);
}

// Round 3
// 337.213 us; speedup vs baseline: 1.8500x; 1.2570x over previous
//
#include <hip/hip_runtime.h>
#include <cstdint>

#define T_LEN 1024
#define NBIG  6272     // padded N for fused projection GEMM (6160 real cols)
#define SCALE_Q 0.08838834764831843f   // DK^-0.5

typedef __bf16 bf16;
typedef __bf16 bf16x8 __attribute__((ext_vector_type(8)));
typedef float  f32x4  __attribute__((ext_vector_type(4)));

__device__ __forceinline__ unsigned short f2bf(float f) {
  unsigned int u = __builtin_bit_cast(unsigned int, f);
  u += 0x7FFFu + ((u >> 16) & 1u);          // RNE
  return (unsigned short)(u >> 16);
}
__device__ __forceinline__ float bf2f(unsigned short u) {
  return __builtin_bit_cast(float, (unsigned int)u << 16);
}
__device__ __forceinline__ float silu_f(float x) { return x / (1.f + __expf(-x)); }

#define GLDS(src, dst) \
  __builtin_amdgcn_global_load_lds( \
      (__attribute__((address_space(1))) void*)(void*)(src), \
      (__attribute__((address_space(3))) void*)(void*)(dst), 16, 0, 0)

// ---------------- fp32 -> bf16 conversion (4 elems/thread) ----------------
__global__ __launch_bounds__(256) void cvt_bf16(const float* __restrict__ in,
                                                unsigned short* __restrict__ out, int n4) {
  int idx = blockIdx.x * 256 + threadIdx.x;
  if (idx >= n4) return;
  float4 f = ((const float4*)in)[idx];
  ushort4 o = { f2bf(f.x), f2bf(f.y), f2bf(f.z), f2bf(f.w) };
  ((ushort4*)out)[idx] = o;
}

// ------------- build concatenated weight matrix W[NBIG][2048] bf16 -------------
__global__ __launch_bounds__(256) void build_w(
    const float* __restrict__ qw, const float* __restrict__ kw,
    const float* __restrict__ vw, const float* __restrict__ gw,
    const float* __restrict__ aw, const float* __restrict__ bw,
    unsigned short* __restrict__ W) {
  int idx = blockIdx.x * 256 + threadIdx.x;   // quad id, exact grid
  int r = idx >> 9;                           // row (2048/4 = 512 quads per row)
  int c = (idx & 511) << 2;
  const float* src;
  if      (r < 1024) src = qw + (size_t)r * 2048;
  else if (r < 2048) src = kw + (size_t)(r - 1024) * 2048;
  else if (r < 4096) src = vw + (size_t)(r - 2048) * 2048;
  else if (r < 6144) src = gw + (size_t)(r - 4096) * 2048;
  else if (r < 6152) src = aw + (size_t)(r - 6144) * 2048;
  else if (r < 6160) src = bw + (size_t)(r - 6152) * 2048;
  else               src = nullptr;
  ushort4 o;
  if (src) {
    float4 f = *(const float4*)(src + c);
    o = { f2bf(f.x), f2bf(f.y), f2bf(f.z), f2bf(f.w) };
  } else {
    o = { 0, 0, 0, 0 };
  }
  *(ushort4*)(W + (size_t)r * 2048 + c) = o;
}

// ---------------- NT GEMM: C[M][N] = A[M][K] * B[N][K]^T, bf16 in ----------------
// m97 structure: 128x128 tile, BK=64, 4 waves (2x2), 16x16x32 MFMA, global_load_lds 16B
template <bool BF16OUT>
__global__ __launch_bounds__(256) void gemm_nt(
    const bf16* __restrict__ A, const bf16* __restrict__ Bm,
    void* __restrict__ Cv, int M, int N, int K) {
  __shared__ bf16 As[128 * 64];
  __shared__ bf16 Bs[128 * 64];
  const int tid = threadIdx.x;
  const int l = tid & 63;
  const int w = tid >> 6;
  const int wm = w >> 1, wn = w & 1;
  const long brow = (long)blockIdx.y * 128;
  const long bcol = (long)blockIdx.x * 128;

  f32x4 acc[4][4];
#pragma unroll
  for (int i = 0; i < 4; ++i)
#pragma unroll
    for (int j = 0; j < 4; ++j)
#pragma unroll
      for (int r = 0; r < 4; ++r) acc[i][j][r] = 0.f;

  const int rs = w * 8 + (l >> 3);   // staging row within 32-row group
  const int cs = (l & 7) * 8;        // staging col (elems)
  const bf16* Ag = A + (brow + rs) * (long)K + cs;
  const bf16* Bg = Bm + (bcol + rs) * (long)K + cs;
  bf16* AsW = As + tid * 8;          // == (rs*64 + cs), linear in lane order
  bf16* BsW = Bs + tid * 8;

  const int nkt = K >> 6;
  for (int kt = 0; kt < nkt; ++kt) {
    __syncthreads();
    const long ko = (long)kt * 64;
#pragma unroll
    for (int i = 0; i < 4; ++i) {
      GLDS(Ag + (long)i * 32 * K + ko, AsW + i * 32 * 64);
      GLDS(Bg + (long)i * 32 * K + ko, BsW + i * 32 * 64);
    }
    __syncthreads();
    const int row = l & 15;
    const int kof = (l >> 4) * 8;
#pragma unroll
    for (int kk = 0; kk < 2; ++kk) {
      bf16x8 af[4], bfr[4];
#pragma unroll
      for (int m = 0; m < 4; ++m)
        af[m] = *(const bf16x8*)(As + (wm * 64 + m * 16 + row) * 64 + kk * 32 + kof);
#pragma unroll
      for (int n = 0; n < 4; ++n)
        bfr[n] = *(const bf16x8*)(Bs + (wn * 64 + n * 16 + row) * 64 + kk * 32 + kof);
#pragma unroll
      for (int m = 0; m < 4; ++m)
#pragma unroll
        for (int n = 0; n < 4; ++n)
          acc[m][n] = __builtin_amdgcn_mfma_f32_16x16x32_bf16(af[m], bfr[n], acc[m][n], 0, 0, 0);
    }
  }
  // epilogue: C/D layout col=lane&15, row=(lane>>4)*4+r  [m89/m91 verified]
  const long row0 = brow + wm * 64 + ((l >> 4) * 4);
  const long col0 = bcol + wn * 64 + (l & 15);
#pragma unroll
  for (int m = 0; m < 4; ++m)
#pragma unroll
    for (int n = 0; n < 4; ++n)
#pragma unroll
      for (int r = 0; r < 4; ++r) {
        if constexpr (BF16OUT)
          ((unsigned short*)Cv)[(row0 + m * 16 + r) * (long)N + col0 + n * 16] = f2bf(acc[m][n][r]);
        else
          ((float*)Cv)[(row0 + m * 16 + r) * (long)N + col0 + n * 16] = acc[m][n][r];
      }
}

// ------------- conv(K=4)+SiLU+l2norm for q,k (bf16 out); conv+SiLU for v; scalars -------------
__global__ __launch_bounds__(256) void convnorm(
    const unsigned short* __restrict__ Y,
    const float* __restrict__ qcw, const float* __restrict__ kcw, const float* __restrict__ vcw,
    const float* __restrict__ A_log, const float* __restrict__ dt_bias,
    unsigned short* __restrict__ qb, unsigned short* __restrict__ kb,
    float* __restrict__ vb, float2* __restrict__ scb) {
  const int bt = blockIdx.x;            // b*T + t
  const int t = bt & (T_LEN - 1);
  const int tid = threadIdx.x;

  // ---- q: channels tid*4 .. +3 ----
  {
    const int c = tid * 4;
    float acc[4] = {0.f, 0.f, 0.f, 0.f};
#pragma unroll
    for (int j = 0; j < 4; ++j) {
      const int tt = t - 3 + j;
      if (tt < 0) continue;
      const ushort4 x = *(const ushort4*)(Y + (size_t)(bt - 3 + j) * NBIG + c);
      const float xv[4] = {bf2f(x.x), bf2f(x.y), bf2f(x.z), bf2f(x.w)};
#pragma unroll
      for (int e = 0; e < 4; ++e) acc[e] += qcw[(c + e) * 4 + j] * xv[e];
    }
    float ss = 0.f;
#pragma unroll
    for (int e = 0; e < 4; ++e) { acc[e] = silu_f(acc[e]); ss += acc[e] * acc[e]; }
#pragma unroll
    for (int m = 16; m >= 1; m >>= 1) ss += __shfl_xor(ss, m);
    const float rn = rsqrtf(ss + 1e-6f) * SCALE_Q;   // fold DK^-0.5 into q
    ushort4 o = {f2bf(acc[0] * rn), f2bf(acc[1] * rn), f2bf(acc[2] * rn), f2bf(acc[3] * rn)};
    *(ushort4*)(qb + (size_t)bt * 1024 + c) = o;
  }
  // ---- k ----
  {
    const int c = tid * 4;
    float acc[4] = {0.f, 0.f, 0.f, 0.f};
#pragma unroll
    for (int j = 0; j < 4; ++j) {
      const int tt = t - 3 + j;
      if (tt < 0) continue;
      const ushort4 x = *(const ushort4*)(Y + (size_t)(bt - 3 + j) * NBIG + 1024 + c);
      const float xv[4] = {bf2f(x.x), bf2f(x.y), bf2f(x.z), bf2f(x.w)};
#pragma unroll
      for (int e = 0; e < 4; ++e) acc[e] += kcw[(c + e) * 4 + j] * xv[e];
    }
    float ss = 0.f;
#pragma unroll
    for (int e = 0; e < 4; ++e) { acc[e] = silu_f(acc[e]); ss += acc[e] * acc[e]; }
#pragma unroll
    for (int m = 16; m >= 1; m >>= 1) ss += __shfl_xor(ss, m);
    const float rn = rsqrtf(ss + 1e-6f);
    ushort4 o = {f2bf(acc[0] * rn), f2bf(acc[1] * rn), f2bf(acc[2] * rn), f2bf(acc[3] * rn)};
    *(ushort4*)(kb + (size_t)bt * 1024 + c) = o;
  }
  // ---- v: channels tid*8 .. +7 (fp32 out; beta applied in chunk_prep) ----
  {
    const int c = tid * 8;
#pragma unroll
    for (int half = 0; half < 2; ++half) {
      const int c2 = c + half * 4;
      float acc[4] = {0.f, 0.f, 0.f, 0.f};
#pragma unroll
      for (int j = 0; j < 4; ++j) {
        const int tt = t - 3 + j;
        if (tt < 0) continue;
        const ushort4 x = *(const ushort4*)(Y + (size_t)(bt - 3 + j) * NBIG + 2048 + c2);
        const float xv[4] = {bf2f(x.x), bf2f(x.y), bf2f(x.z), bf2f(x.w)};
#pragma unroll
        for (int e = 0; e < 4; ++e) acc[e] += vcw[(c2 + e) * 4 + j] * xv[e];
      }
#pragma unroll
      for (int e = 0; e < 4; ++e) acc[e] = silu_f(acc[e]);
      float4 o = {acc[0], acc[1], acc[2], acc[3]};
      *(float4*)(vb + (size_t)bt * 2048 + c2) = o;
    }
  }
  // ---- per-step scalars: {g (log decay), beta} ----
  if (tid < 8) {
    const int hh = tid;
    const unsigned short* Yb = Y + (size_t)bt * NBIG;
    float a = bf2f(Yb[6144 + hh]) + dt_bias[hh];
    float sp = (a > 20.f) ? a : log1pf(expf(a));
    float g = -expf(A_log[hh]) * sp;
    float bp = bf2f(Yb[6152 + hh]);
    float be = 1.f / (1.f + expf(-bp));
    float2 o; o.x = g; o.y = be;
    scb[(size_t)bt * 8 + hh] = o;
  }
}

// ---------------- small NT GEMM on LDS operands: OUT[i][j] = sum_k A[i][k]*B[j][k] ----------------
// A: [M][K] bf16 LDS, B: [N][K] bf16 LDS. 4 waves. Output fp32 LDS (ld=N) or bf16 global (ldg).
template <int M, int N, int K, bool TOGLOB>
__device__ __forceinline__ void mm_nt_lds(const unsigned short* A, const unsigned short* B,
                                          float* outF, unsigned short* outG, int ldg, int tid) {
  constexpr int NT16 = N / 16;
  constexpr int PW = (M / 16) * NT16 / 4;
  const int w = tid >> 6, l = tid & 63;
  const int row = l & 15, ko = (l >> 4) * 8;
  f32x4 acc[PW];
#pragma unroll
  for (int i = 0; i < PW; ++i)
#pragma unroll
    for (int r = 0; r < 4; ++r) acc[i][r] = 0.f;
#pragma unroll
  for (int i = 0; i < PW; ++i) {
    const int ti = w + 4 * i;
    const int rt = ti / NT16, ct = ti % NT16;
#pragma unroll
    for (int kk = 0; kk < K / 32; ++kk) {
      bf16x8 af = *(const bf16x8*)(A + (rt * 16 + row) * K + kk * 32 + ko);
      bf16x8 bf = *(const bf16x8*)(B + (ct * 16 + row) * K + kk * 32 + ko);
      acc[i] = __builtin_amdgcn_mfma_f32_16x16x32_bf16(af, bf, acc[i], 0, 0, 0);
    }
  }
#pragma unroll
  for (int i = 0; i < PW; ++i) {
    const int ti = w + 4 * i;
    const int rt = ti / NT16, ct = ti % NT16;
    const int r0 = rt * 16 + (l >> 4) * 4;
    const int col = ct * 16 + (l & 15);
#pragma unroll
    for (int r = 0; r < 4; ++r) {
      if constexpr (TOGLOB) outG[(size_t)(r0 + r) * ldg + col] = f2bf(acc[i][r]);
      else                  outF[(r0 + r) * N + col] = acc[i][r];
    }
  }
}

// ---------------- phase 1: per-chunk UT transform (chunk C=64) ----------------
// per chunk-head ch = bh*16 + p: outputs W, Ub, Att, Qg, KgT, dec.
__global__ __launch_bounds__(256, 1) void chunk_prep(
    const unsigned short* __restrict__ qb, const unsigned short* __restrict__ kb,
    const float* __restrict__ vb, const float2* __restrict__ scb,
    unsigned short* __restrict__ Wg, unsigned short* __restrict__ Ubg,
    unsigned short* __restrict__ Attg, unsigned short* __restrict__ Qgg,
    unsigned short* __restrict__ KgTg, float* __restrict__ decg) {
  __shared__ unsigned short Kb_s[64 * 128];
  __shared__ unsigned short Qb_s[64 * 128];     // later reused as KbgT [128][64]
  __shared__ unsigned short VbT_s[256 * 64];    // beta*V transposed
  __shared__ unsigned short Mb_s[4096];         // I + A (bf16)
  __shared__ unsigned short Xrow_s[4096];       // X row-major bf16
  __shared__ unsigned short Xt_s[4096];         // X^T bf16
  __shared__ unsigned short Yt_s[4096];         // Y^T bf16
  __shared__ float F1_s[4096];                  // X fp32
  __shared__ float F2_s[4096];                  // GEMM scratch fp32
  __shared__ float carr_s[64];
  __shared__ float beta_s[64];

  const int tid = threadIdx.x;
  const int ch = blockIdx.x;
  const int bh = ch >> 4, p = ch & 15;
  const int b = bh >> 3, h = bh & 7;
  const size_t tbase = (size_t)b * T_LEN + p * 64;

  // 1. per-step scalars + cumulative log-decay (inclusive scan over 64 lanes of wave 0)
  if (tid < 64) {
    float2 gb = scb[(tbase + tid) * 8 + h];
    float c = gb.x;
#pragma unroll
    for (int d = 1; d < 64; d <<= 1) {
      float y = __shfl_up(c, d);
      if (tid >= d) c += y;
    }
    carr_s[tid] = c;
    beta_s[tid] = gb.y;
    if (tid == 63) decg[ch] = __expf(c);
  }
  // 2. stage K, Q chunks (bf16) via global_load_lds
#pragma unroll
  for (int i = 0; i < 4; ++i) {
    const int f = i * 256 + tid;
    const int t = f >> 4, c8 = f & 15;
    GLDS(kb + (tbase + t) * 1024 + h * 128 + c8 * 8, (char*)Kb_s + f * 16);
    GLDS(qb + (tbase + t) * 1024 + h * 128 + c8 * 8, (char*)Qb_s + f * 16);
  }
  __syncthreads();
  // 3. VbT[v][t] = bf16(beta_t * v[t][v])
#pragma unroll
  for (int i = 0; i < 16; ++i) {
    const int m = i * 256 + tid;
    const int t = m >> 6, c4 = (m & 63) * 4;
    float4 v = *(const float4*)(vb + (tbase + t) * 2048 + h * 256 + c4);
    const float bt = beta_s[t];
    VbT_s[(c4 + 0) * 64 + t] = f2bf(bt * v.x);
    VbT_s[(c4 + 1) * 64 + t] = f2bf(bt * v.y);
    VbT_s[(c4 + 2) * 64 + t] = f2bf(bt * v.z);
    VbT_s[(c4 + 3) * 64 + t] = f2bf(bt * v.w);
  }
  __syncthreads();
  // 4. A_raw = K K^T
  mm_nt_lds<64, 64, 128, false>(Kb_s, Kb_s, F2_s, nullptr, 0, tid);
  __syncthreads();
  // 5. M = I + A, X0 = I - A  (A[t][j] = beta_t exp(c_t-c_j) (k_t.k_j), j<t)
#pragma unroll
  for (int i = 0; i < 16; ++i) {
    const int idx = i * 256 + tid;
    const int t = idx >> 6, j = idx & 63;
    const float kk = F2_s[idx];
    const float av = (j < t) ? beta_s[t] * __expf(carr_s[t] - carr_s[j]) * kk : 0.f;
    const float dg = (t == j) ? 1.f : 0.f;
    Mb_s[idx] = f2bf(dg + av);
    const float x0 = dg - av;
    F1_s[idx] = x0;
    const unsigned short xb = f2bf(x0);
    Xrow_s[idx] = xb;
    Xt_s[j * 64 + t] = xb;
  }
  __syncthreads();
  // 6. Newton x5: X <- X(2I - M X)   (exact: A nilpotent, err = A^64 = 0)
  for (int it = 0; it < 5; ++it) {
    mm_nt_lds<64, 64, 64, false>(Mb_s, Xt_s, F2_s, nullptr, 0, tid);   // Y = M X
    __syncthreads();
#pragma unroll
    for (int i = 0; i < 16; ++i) {
      const int idx = i * 256 + tid;
      Yt_s[(idx & 63) * 64 + (idx >> 6)] = f2bf(F2_s[idx]);
    }
    __syncthreads();
    mm_nt_lds<64, 64, 64, false>(Xrow_s, Yt_s, F2_s, nullptr, 0, tid); // P = X Y
    __syncthreads();
#pragma unroll
    for (int i = 0; i < 16; ++i) {
      const int idx = i * 256 + tid;
      const float xn = 2.f * F1_s[idx] - F2_s[idx];
      F1_s[idx] = xn;
      const unsigned short xb = f2bf(xn);
      Xrow_s[idx] = xb;
      Xt_s[(idx & 63) * 64 + (idx >> 6)] = xb;
    }
    __syncthreads();
  }
  // 7. AttRaw = Q K^T
  mm_nt_lds<64, 64, 128, false>(Qb_s, Kb_s, F2_s, nullptr, 0, tid);
  __syncthreads();
  const float ctot = carr_s[63];
  // 8. Att (incl diag), Qg, KgT -> global
#pragma unroll
  for (int i = 0; i < 16; ++i) {
    const int idx = i * 256 + tid;
    const int t = idx >> 6, j = idx & 63;
    const float av = (j <= t) ? __expf(carr_s[t] - carr_s[j]) * F2_s[idx] : 0.f;
    Attg[(size_t)ch * 4096 + idx] = f2bf(av);
  }
#pragma unroll
  for (int i = 0; i < 32; ++i) {
    const int idx = i * 256 + tid;
    const int t = idx >> 7, d = idx & 127;
    Qgg[(size_t)ch * 8192 + idx] = f2bf(__expf(carr_s[t]) * bf2f(Qb_s[idx]));
  }
#pragma unroll
  for (int i = 0; i < 32; ++i) {
    const int idx = i * 256 + tid;
    const int d = idx >> 6, t = idx & 63;
    KgTg[(size_t)ch * 8192 + idx] = f2bf(__expf(ctot - carr_s[t]) * bf2f(Kb_s[t * 128 + d]));
  }
  __syncthreads();   // Qb reads done before reuse
  // 9. KbgT[d][t] = bf16(beta_t exp(c_t) k[t][d])  (into Qb space)
  unsigned short* KbgT = Qb_s;
#pragma unroll
  for (int i = 0; i < 32; ++i) {
    const int idx = i * 256 + tid;
    const int d = idx >> 6, t = idx & 63;
    KbgT[idx] = f2bf(beta_s[t] * __expf(carr_s[t]) * bf2f(Kb_s[t * 128 + d]));
  }
  __syncthreads();
  // 10. W = T (betaG.K)  [64x128];  Ub = T (betaV)  [64x256]  -> global bf16
  mm_nt_lds<64, 128, 64, true>(Xrow_s, KbgT, nullptr, Wg + (size_t)ch * 8192, 128, tid);
  mm_nt_lds<64, 256, 64, true>(Xrow_s, VbT_s, nullptr, Ubg + (size_t)ch * 16384, 256, tid);
}

// ---------------- phase 2: serial chunk recurrence (MFMA), 16 bh x 8 v-blocks ----------------
// stage buffer (ushort offsets): W@0(8192) Att@8192(4096) Qg@12288(8192) KgT@20480(8192) Ub@28672(2048)
__device__ __forceinline__ void p2_stage(
    const unsigned short* Wg, const unsigned short* Attg, const unsigned short* Qgg,
    const unsigned short* KgTg, const unsigned short* Ubg,
    int ch, int vb, unsigned short* buf, int tid) {
#pragma unroll
  for (int i = 0; i < 4; ++i) {
    const int f = i * 256 + tid;
    GLDS(Wg + (size_t)ch * 8192 + f * 8, (char*)buf + f * 16);
  }
#pragma unroll
  for (int i = 0; i < 2; ++i) {
    const int f = i * 256 + tid;
    GLDS(Attg + (size_t)ch * 4096 + f * 8, (char*)(buf + 8192) + f * 16);
  }
#pragma unroll
  for (int i = 0; i < 4; ++i) {
    const int f = i * 256 + tid;
    GLDS(Qgg + (size_t)ch * 8192 + f * 8, (char*)(buf + 12288) + f * 16);
  }
#pragma unroll
  for (int i = 0; i < 4; ++i) {
    const int f = i * 256 + tid;
    GLDS(KgTg + (size_t)ch * 8192 + f * 8, (char*)(buf + 20480) + f * 16);
  }
  {
    const int f = tid;
    const int t = f >> 2, c8 = f & 3;
    GLDS(Ubg + (size_t)ch * 16384 + t * 256 + vb * 32 + c8 * 8, (char*)(buf + 28672) + f * 16);
  }
}

__global__ __launch_bounds__(256, 1) void scan_chunks(
    const unsigned short* __restrict__ Wg, const unsigned short* __restrict__ Ubg,
    const unsigned short* __restrict__ Attg, const unsigned short* __restrict__ Qgg,
    const unsigned short* __restrict__ KgTg, const float* __restrict__ decg,
    float* __restrict__ osc) {
  __shared__ float StT_s[32 * 128];            // S^T fp32 [vcol][d]
  __shared__ unsigned short StTb_s[32 * 128];  // S^T bf16
  __shared__ unsigned short uT_s[32 * 64];     // u^T bf16 [vcol][t]
  __shared__ unsigned short stage_s[2][30720];

  const int tid = threadIdx.x;
  const int w = tid >> 6, l = tid & 63;
  const int row = l & 15, ko = (l >> 4) * 8;
  const int blk = blockIdx.x;                  // vb*16 + bh  (same-bh blocks share an XCD)
  const int vb = blk >> 4, bh = blk & 15;
  const int b = bh >> 3, h = bh & 7;

  for (int i = tid; i < 4096; i += 256) { StT_s[i] = 0.f; StTb_s[i] = 0; }
  p2_stage(Wg, Attg, Qgg, KgTg, Ubg, bh * 16, vb, stage_s[0], tid);

  for (int p = 0; p < 16; ++p) {
    unsigned short* bufc = stage_s[p & 1];
    const unsigned short* Wl   = bufc;
    const unsigned short* Attl = bufc + 8192;
    const unsigned short* Qgl  = bufc + 12288;
    const unsigned short* KgTl = bufc + 20480;
    const unsigned short* Ubl  = bufc + 28672;
    __syncthreads();   // staged buf + previous S writes visible (vmcnt drained)

    // ---- u = Ub - W S : acc [64x32], 8 tiles, 2/wave ----
    f32x4 uacc[2];
#pragma unroll
    for (int i = 0; i < 2; ++i)
#pragma unroll
      for (int r = 0; r < 4; ++r) uacc[i][r] = 0.f;
#pragma unroll
    for (int i = 0; i < 2; ++i) {
      const int ti = w + 4 * i;
      const int rt = ti >> 1, ct = ti & 1;
#pragma unroll
      for (int kk = 0; kk < 4; ++kk) {
        bf16x8 af = *(const bf16x8*)(Wl + (rt * 16 + row) * 128 + kk * 32 + ko);
        bf16x8 bf = *(const bf16x8*)(StTb_s + (ct * 16 + row) * 128 + kk * 32 + ko);
        uacc[i] = __builtin_amdgcn_mfma_f32_16x16x32_bf16(af, bf, uacc[i], 0, 0, 0);
      }
    }
#pragma unroll
    for (int i = 0; i < 2; ++i) {
      const int ti = w + 4 * i;
      const int rt = ti >> 1, ct = ti & 1;
      const int r0 = rt * 16 + (l >> 4) * 4;
      const int col = ct * 16 + (l & 15);
#pragma unroll
      for (int r = 0; r < 4; ++r) {
        const int t = r0 + r;
        const float ubv = bf2f(Ubl[t * 32 + col]);
        uT_s[col * 64 + t] = f2bf(ubv - uacc[i][r]);
      }
    }
    __syncthreads();   // uT ready
    if (p < 15)
      p2_stage(Wg, Attg, Qgg, KgTg, Ubg, bh * 16 + p + 1, vb, stage_s[(p + 1) & 1], tid);

    // ---- O = Qg S + Att u : acc [64x32] ----
    f32x4 oacc[2];
#pragma unroll
    for (int i = 0; i < 2; ++i)
#pragma unroll
      for (int r = 0; r < 4; ++r) oacc[i][r] = 0.f;
#pragma unroll
    for (int i = 0; i < 2; ++i) {
      const int ti = w + 4 * i;
      const int rt = ti >> 1, ct = ti & 1;
#pragma unroll
      for (int kk = 0; kk < 4; ++kk) {
        bf16x8 af = *(const bf16x8*)(Qgl + (rt * 16 + row) * 128 + kk * 32 + ko);
        bf16x8 bf = *(const bf16x8*)(StTb_s + (ct * 16 + row) * 128 + kk * 32 + ko);
        oacc[i] = __builtin_amdgcn_mfma_f32_16x16x32_bf16(af, bf, oacc[i], 0, 0, 0);
      }
#pragma unroll
      for (int kk = 0; kk < 2; ++kk) {
        bf16x8 af = *(const bf16x8*)(Attl + (rt * 16 + row) * 64 + kk * 32 + ko);
        bf16x8 bf = *(const bf16x8*)(uT_s + (ct * 16 + row) * 64 + kk * 32 + ko);
        oacc[i] = __builtin_amdgcn_mfma_f32_16x16x32_bf16(af, bf, oacc[i], 0, 0, 0);
      }
    }
    // ---- Snew^T = dec*S^T + (u^T)(KgT^T) : acc [32x128], 16 tiles, 4/wave ----
    f32x4 sacc[4];
#pragma unroll
    for (int i = 0; i < 4; ++i)
#pragma unroll
      for (int r = 0; r < 4; ++r) sacc[i][r] = 0.f;
#pragma unroll
    for (int i = 0; i < 4; ++i) {
      const int ti = w + 4 * i;
      const int srt = ti >> 3, sct = ti & 7;
#pragma unroll
      for (int kk = 0; kk < 2; ++kk) {
        bf16x8 af = *(const bf16x8*)(uT_s + (srt * 16 + row) * 64 + kk * 32 + ko);
        bf16x8 bf = *(const bf16x8*)(KgTl + (sct * 16 + row) * 64 + kk * 32 + ko);
        sacc[i] = __builtin_amdgcn_mfma_f32_16x16x32_bf16(af, bf, sacc[i], 0, 0, 0);
      }
    }
    const float dec = decg[bh * 16 + p];
    __syncthreads();   // all reads of StT/StTb done before overwrite

    // epilogues
#pragma unroll
    for (int i = 0; i < 2; ++i) {
      const int ti = w + 4 * i;
      const int rt = ti >> 1, ct = ti & 1;
      const int r0 = rt * 16 + (l >> 4) * 4;
      const int col = ct * 16 + (l & 15);
#pragma unroll
      for (int r = 0; r < 4; ++r) {
        const size_t trow = (size_t)b * T_LEN + p * 64 + r0 + r;
        osc[(trow * 8 + h) * 256 + vb * 32 + col] = oacc[i][r];
      }
    }
#pragma unroll
    for (int i = 0; i < 4; ++i) {
      const int ti = w + 4 * i;
      const int srt = ti >> 3, sct = ti & 7;
      const int r0 = srt * 16 + (l >> 4) * 4;
      const int cold = sct * 16 + (l & 15);
#pragma unroll
      for (int r = 0; r < 4; ++r) {
        const int idx = (r0 + r) * 128 + cold;
        const float sn = fmaf(dec, StT_s[idx], sacc[i][r]);
        StT_s[idx] = sn;
        StTb_s[idx] = f2bf(sn);
      }
    }
  }
}

// ---------------- gated RMSNorm + silu(gate) -> bf16 ----------------
__global__ __launch_bounds__(256) void rmsgate(
    const float* __restrict__ ob, const unsigned short* __restrict__ Y,
    const float* __restrict__ onw, unsigned short* __restrict__ Obf) {
  const int bt = blockIdx.x;
  const int tid = threadIdx.x;
  const int c = tid * 8;                // head = c/256 = tid/32
  const float* orow = ob + (size_t)bt * 2048 + c;
  const unsigned short* grow = Y + (size_t)bt * NBIG + 4096 + c;
  const float4 o0 = *(const float4*)orow, o1 = *(const float4*)(orow + 4);
  const ushort4 g0 = *(const ushort4*)grow, g1 = *(const ushort4*)(grow + 4);
  const float ov[8] = {o0.x, o0.y, o0.z, o0.w, o1.x, o1.y, o1.z, o1.w};
  const float gv[8] = {bf2f(g0.x), bf2f(g0.y), bf2f(g0.z), bf2f(g0.w),
                       bf2f(g1.x), bf2f(g1.y), bf2f(g1.z), bf2f(g1.w)};
  float ss = 0.f;
#pragma unroll
  for (int e = 0; e < 8; ++e) ss += ov[e] * ov[e];
#pragma unroll
  for (int m = 16; m >= 1; m >>= 1) ss += __shfl_xor(ss, m);
  const float rn = rsqrtf(ss * (1.f / 256.f) + 1e-5f);
  const int dv = c & 255;
  unsigned short rr[8];
#pragma unroll
  for (int e = 0; e < 8; ++e) {
    const float val = ov[e] * rn * onw[dv + e] * silu_f(gv[e]);
    rr[e] = f2bf(val);
  }
  ushort4 r0 = {rr[0], rr[1], rr[2], rr[3]};
  ushort4 r1 = {rr[4], rr[5], rr[6], rr[7]};
  *(ushort4*)(Obf + (size_t)bt * 2048 + c) = r0;
  *(ushort4*)(Obf + (size_t)bt * 2048 + c + 4) = r1;
}

extern "C" void kernel_launch(void* const* d_in, const int* in_sizes, int n_in,
                              void* d_out, int out_size, void* d_ws, size_t ws_size,
                              hipStream_t stream) {
  (void)in_sizes; (void)n_in; (void)out_size; (void)ws_size;
  const float* h    = (const float*)d_in[0];
  const float* qw   = (const float*)d_in[1];
  const float* kw   = (const float*)d_in[2];
  const float* vw   = (const float*)d_in[3];
  const float* aw   = (const float*)d_in[4];
  const float* bw   = (const float*)d_in[5];
  const float* gw   = (const float*)d_in[6];
  const float* ow   = (const float*)d_in[7];
  const float* qcw  = (const float*)d_in[8];
  const float* kcw  = (const float*)d_in[9];
  const float* vcw  = (const float*)d_in[10];
  const float* Alog = (const float*)d_in[11];
  const float* dtb  = (const float*)d_in[12];
  const float* onw  = (const float*)d_in[13];

  char* ws = (char*)d_ws;
  size_t off = 0;
  auto alloc = [&](size_t bytes) {
    char* p = ws + off;
    off = (off + bytes + 255) & ~(size_t)255;
    return p;
  };
  unsigned short* qb   = (unsigned short*)alloc(2048ull * 1024 * 2);
  unsigned short* kb   = (unsigned short*)alloc(2048ull * 1024 * 2);
  float* vb            = (float*)alloc(2048ull * 2048 * 4);
  float2* scb          = (float2*)alloc(2048ull * 8 * 8);
  unsigned short* hbf  = (unsigned short*)alloc(2048ull * 2048 * 2);
  unsigned short* Wb   = (unsigned short*)alloc((size_t)NBIG * 2048 * 2);
  unsigned short* owb  = (unsigned short*)alloc(2048ull * 2048 * 2);
  unsigned short* Ybf  = (unsigned short*)alloc(2048ull * NBIG * 2);
  float* osc           = (float*)alloc(2048ull * 2048 * 4);
  unsigned short* Obf  = (unsigned short*)alloc(2048ull * 2048 * 2);
  unsigned short* Wg   = (unsigned short*)alloc(256ull * 8192 * 2);
  unsigned short* Ubg  = (unsigned short*)alloc(256ull * 16384 * 2);
  unsigned short* Attg = (unsigned short*)alloc(256ull * 4096 * 2);
  unsigned short* Qgg  = (unsigned short*)alloc(256ull * 8192 * 2);
  unsigned short* KgTg = (unsigned short*)alloc(256ull * 8192 * 2);
  float* decg          = (float*)alloc(256ull * 4);

  cvt_bf16<<<4096, 256, 0, stream>>>(h, hbf, 1048576);
  build_w<<<12544, 256, 0, stream>>>(qw, kw, vw, gw, aw, bw, Wb);
  cvt_bf16<<<4096, 256, 0, stream>>>(ow, owb, 1048576);
  gemm_nt<true><<<dim3(NBIG / 128, 16), 256, 0, stream>>>((const bf16*)hbf, (const bf16*)Wb,
                                                          Ybf, 2048, NBIG, 2048);
  convnorm<<<2048, 256, 0, stream>>>(Ybf, qcw, kcw, vcw, Alog, dtb, qb, kb, vb, scb);
  chunk_prep<<<256, 256, 0, stream>>>(qb, kb, vb, scb, Wg, Ubg, Attg, Qgg, KgTg, decg);
  scan_chunks<<<128, 256, 0, stream>>>(Wg, Ubg, Attg, Qgg, KgTg, decg, osc);
  rmsgate<<<2048, 256, 0, stream>>>(osc, Ybf, onw, Obf);
  gemm_nt<false><<<dim3(16, 16), 256, 0, stream>>>((const bf16*)Obf, (const bf16*)owb,
                                                   d_out, 2048, 2048, 2048);
}

// Round 4
// 324.761 us; speedup vs baseline: 1.9209x; 1.0383x over previous
//
#include <hip/hip_runtime.h>
#include <cstdint>

#define T_LEN 1024
#define NBIG  6400     // padded N for fused projection GEMM (6160 real cols, 25 x 256 tiles)
#define SCALE_Q 0.08838834764831843f   // DK^-0.5

typedef __bf16 bf16;
typedef __bf16 bf16x8 __attribute__((ext_vector_type(8)));
typedef float  f32x4  __attribute__((ext_vector_type(4)));

__device__ __forceinline__ unsigned short f2bf(float f) {
  unsigned int u = __builtin_bit_cast(unsigned int, f);
  u += 0x7FFFu + ((u >> 16) & 1u);          // RNE
  return (unsigned short)(u >> 16);
}
__device__ __forceinline__ float bf2f(unsigned short u) {
  return __builtin_bit_cast(float, (unsigned int)u << 16);
}
__device__ __forceinline__ float silu_f(float x) { return x / (1.f + __expf(-x)); }

#define GLDS(src, dst) \
  __builtin_amdgcn_global_load_lds( \
      (__attribute__((address_space(1))) void*)(void*)(src), \
      (__attribute__((address_space(3))) void*)(void*)(dst), 16, 0, 0)

// ---------------- fp32 -> bf16 conversion (4 elems/thread) ----------------
__global__ __launch_bounds__(256) void cvt_bf16(const float* __restrict__ in,
                                                unsigned short* __restrict__ out, int n4) {
  int idx = blockIdx.x * 256 + threadIdx.x;
  if (idx >= n4) return;
  float4 f = ((const float4*)in)[idx];
  ushort4 o = { f2bf(f.x), f2bf(f.y), f2bf(f.z), f2bf(f.w) };
  ((ushort4*)out)[idx] = o;
}

// ------------- build concatenated weight matrix W[NBIG][2048] bf16 -------------
__global__ __launch_bounds__(256) void build_w(
    const float* __restrict__ qw, const float* __restrict__ kw,
    const float* __restrict__ vw, const float* __restrict__ gw,
    const float* __restrict__ aw, const float* __restrict__ bw,
    unsigned short* __restrict__ W) {
  int idx = blockIdx.x * 256 + threadIdx.x;   // quad id, exact grid
  int r = idx >> 9;                           // row (2048/4 = 512 quads per row)
  int c = (idx & 511) << 2;
  const float* src;
  if      (r < 1024) src = qw + (size_t)r * 2048;
  else if (r < 2048) src = kw + (size_t)(r - 1024) * 2048;
  else if (r < 4096) src = vw + (size_t)(r - 2048) * 2048;
  else if (r < 6144) src = gw + (size_t)(r - 4096) * 2048;
  else if (r < 6152) src = aw + (size_t)(r - 6144) * 2048;
  else if (r < 6160) src = bw + (size_t)(r - 6152) * 2048;
  else               src = nullptr;
  ushort4 o;
  if (src) {
    float4 f = *(const float4*)(src + c);
    o = { f2bf(f.x), f2bf(f.y), f2bf(f.z), f2bf(f.w) };
  } else {
    o = { 0, 0, 0, 0 };
  }
  *(ushort4*)(W + (size_t)r * 2048 + c) = o;
}

// ============ big NT GEMM: 256x256 tile, BK=32, 4-deep ring LDS, counted vmcnt ============
// C[M][N] = A[M][K] * B[N][K]^T, bf16 in, bf16 out. 512 threads = 8 waves (2M x 4N).
// LDS swizzle: logical k-slot s of row r stored at physical slot s ^ ((r>>1)&3)
// (applied via pre-swizzled global SOURCE on the linear global_load_lds dest, and on reads).
__global__ __launch_bounds__(512, 2) void gemm_big(
    const bf16* __restrict__ A, const bf16* __restrict__ Bm,
    unsigned short* __restrict__ C, int M, int N, int K) {
  __shared__ bf16 LA[4][256 * 32];
  __shared__ bf16 LB[4][256 * 32];
  const int tid = threadIdx.x;
  const int lane = tid & 63;
  const int wid = tid >> 6;
  const int wm = wid >> 2, wn = wid & 3;
  const int bid = blockIdx.x;
  const long brow = (long)(bid & 7) * 256;    // XCD x owns row-panel x (A panel L2-resident)
  const long bcol = (long)(bid >> 3) * 256;

  f32x4 acc[8][4];
#pragma unroll
  for (int m = 0; m < 8; ++m)
#pragma unroll
    for (int n = 0; n < 4; ++n)
#pragma unroll
      for (int r = 0; r < 4; ++r) acc[m][n][r] = 0.f;

  // staging: thread tid covers physical (row = tid>>2, pslot = tid&3); its global
  // source is the logical slot that belongs there: lsl = pslot ^ ((row>>1)&3).
  const int srow = tid >> 2;
  const int slsl = (tid & 3) ^ ((tid >> 3) & 3);
  const bf16* Ag = A + (brow + srow) * (long)K + slsl * 8;
  const bf16* Bg = Bm + (bcol + srow) * (long)K + slsl * 8;
  bf16* la0 = &LA[0][0] + tid * 8;   // linear dest: base + tid*16B
  bf16* lb0 = &LB[0][0] + tid * 8;

  const int nkt = K >> 5;
#define STAGE(kt, bb)                                               \
  {                                                                 \
    const long ko = (long)(kt) * 32;                                \
    GLDS(Ag + ko,                 la0 + (bb) * 8192);               \
    GLDS(Bg + ko,                 lb0 + (bb) * 8192);               \
    GLDS(Ag + (long)128 * K + ko, la0 + (bb) * 8192 + 4096);        \
    GLDS(Bg + (long)128 * K + ko, lb0 + (bb) * 8192 + 4096);        \
  }

  STAGE(0, 0); STAGE(1, 1); STAGE(2, 2);   // 12 loads in flight

  const int r16 = lane & 15;
  const int ps = (lane >> 4) ^ ((r16 >> 1) & 3);       // swizzled read slot
  const int rdoff = r16 * 32 + ps * 8;                 // halfword offset within tile

  for (int kt = 0; kt < nkt; ++kt) {
    asm volatile("s_waitcnt vmcnt(8)" ::: "memory");   // kt's 4 loads landed; kt+1,kt+2 in flight
    __builtin_amdgcn_s_barrier();
    const int kt3 = (kt + 3 < nkt) ? kt + 3 : nkt - 1; // clamp src, keep count uniform
    STAGE(kt3, (kt + 3) & 3);                          // buf (kt+3)&3 == (kt-1)&3: read-complete
    __builtin_amdgcn_sched_barrier(0);                 // pin: no ds_read hoists above barrier
    const int bb = kt & 3;
    const bf16* lA = &LA[bb][0] + wm * (128 * 32) + rdoff;
    const bf16* lB = &LB[bb][0] + wn * (64 * 32) + rdoff;
    bf16x8 af[8], bfr[4];
#pragma unroll
    for (int m = 0; m < 8; ++m) af[m] = *(const bf16x8*)(lA + m * (16 * 32));
#pragma unroll
    for (int n = 0; n < 4; ++n) bfr[n] = *(const bf16x8*)(lB + n * (16 * 32));
    __builtin_amdgcn_s_setprio(1);
#pragma unroll
    for (int m = 0; m < 8; ++m)
#pragma unroll
      for (int n = 0; n < 4; ++n)
        acc[m][n] = __builtin_amdgcn_mfma_f32_16x16x32_bf16(af[m], bfr[n], acc[m][n], 0, 0, 0);
    __builtin_amdgcn_s_setprio(0);
  }
#undef STAGE

  // epilogue: C/D layout col=lane&15, row=(lane>>4)*4+r
  const long row0 = brow + wm * 128 + ((lane >> 4) * 4);
  const long col0 = bcol + wn * 64 + (lane & 15);
#pragma unroll
  for (int m = 0; m < 8; ++m)
#pragma unroll
    for (int n = 0; n < 4; ++n)
#pragma unroll
      for (int r = 0; r < 4; ++r)
        C[(row0 + m * 16 + r) * (long)N + col0 + n * 16] = f2bf(acc[m][n][r]);
}

// ---------------- NT GEMM: C[M][N] = A[M][K] * B[N][K]^T, bf16 in ----------------
// m97 structure: 128x128 tile, BK=64, 4 waves (2x2), 16x16x32 MFMA, global_load_lds 16B
template <bool BF16OUT>
__global__ __launch_bounds__(256) void gemm_nt(
    const bf16* __restrict__ A, const bf16* __restrict__ Bm,
    void* __restrict__ Cv, int M, int N, int K) {
  __shared__ bf16 As[128 * 64];
  __shared__ bf16 Bs[128 * 64];
  const int tid = threadIdx.x;
  const int l = tid & 63;
  const int w = tid >> 6;
  const int wm = w >> 1, wn = w & 1;
  const long brow = (long)blockIdx.y * 128;
  const long bcol = (long)blockIdx.x * 128;

  f32x4 acc[4][4];
#pragma unroll
  for (int i = 0; i < 4; ++i)
#pragma unroll
    for (int j = 0; j < 4; ++j)
#pragma unroll
      for (int r = 0; r < 4; ++r) acc[i][j][r] = 0.f;

  const int rs = w * 8 + (l >> 3);   // staging row within 32-row group
  const int cs = (l & 7) * 8;        // staging col (elems)
  const bf16* Ag = A + (brow + rs) * (long)K + cs;
  const bf16* Bg = Bm + (bcol + rs) * (long)K + cs;
  bf16* AsW = As + tid * 8;          // == (rs*64 + cs), linear in lane order
  bf16* BsW = Bs + tid * 8;

  const int nkt = K >> 6;
  for (int kt = 0; kt < nkt; ++kt) {
    __syncthreads();
    const long ko = (long)kt * 64;
#pragma unroll
    for (int i = 0; i < 4; ++i) {
      GLDS(Ag + (long)i * 32 * K + ko, AsW + i * 32 * 64);
      GLDS(Bg + (long)i * 32 * K + ko, BsW + i * 32 * 64);
    }
    __syncthreads();
    const int row = l & 15;
    const int kof = (l >> 4) * 8;
#pragma unroll
    for (int kk = 0; kk < 2; ++kk) {
      bf16x8 af[4], bfr[4];
#pragma unroll
      for (int m = 0; m < 4; ++m)
        af[m] = *(const bf16x8*)(As + (wm * 64 + m * 16 + row) * 64 + kk * 32 + kof);
#pragma unroll
      for (int n = 0; n < 4; ++n)
        bfr[n] = *(const bf16x8*)(Bs + (wn * 64 + n * 16 + row) * 64 + kk * 32 + kof);
#pragma unroll
      for (int m = 0; m < 4; ++m)
#pragma unroll
        for (int n = 0; n < 4; ++n)
          acc[m][n] = __builtin_amdgcn_mfma_f32_16x16x32_bf16(af[m], bfr[n], acc[m][n], 0, 0, 0);
    }
  }
  // epilogue: C/D layout col=lane&15, row=(lane>>4)*4+r  [m89/m91 verified]
  const long row0 = brow + wm * 64 + ((l >> 4) * 4);
  const long col0 = bcol + wn * 64 + (l & 15);
#pragma unroll
  for (int m = 0; m < 4; ++m)
#pragma unroll
    for (int n = 0; n < 4; ++n)
#pragma unroll
      for (int r = 0; r < 4; ++r) {
        if constexpr (BF16OUT)
          ((unsigned short*)Cv)[(row0 + m * 16 + r) * (long)N + col0 + n * 16] = f2bf(acc[m][n][r]);
        else
          ((float*)Cv)[(row0 + m * 16 + r) * (long)N + col0 + n * 16] = acc[m][n][r];
      }
}

// ------------- conv(K=4)+SiLU+l2norm for q,k (bf16 out); conv+SiLU for v; scalars -------------
__global__ __launch_bounds__(256) void convnorm(
    const unsigned short* __restrict__ Y,
    const float* __restrict__ qcw, const float* __restrict__ kcw, const float* __restrict__ vcw,
    const float* __restrict__ A_log, const float* __restrict__ dt_bias,
    unsigned short* __restrict__ qb, unsigned short* __restrict__ kb,
    float* __restrict__ vb, float2* __restrict__ scb) {
  const int bt = blockIdx.x;            // b*T + t
  const int t = bt & (T_LEN - 1);
  const int tid = threadIdx.x;

  // ---- q: channels tid*4 .. +3 ----
  {
    const int c = tid * 4;
    float acc[4] = {0.f, 0.f, 0.f, 0.f};
#pragma unroll
    for (int j = 0; j < 4; ++j) {
      const int tt = t - 3 + j;
      if (tt < 0) continue;
      const ushort4 x = *(const ushort4*)(Y + (size_t)(bt - 3 + j) * NBIG + c);
      const float xv[4] = {bf2f(x.x), bf2f(x.y), bf2f(x.z), bf2f(x.w)};
#pragma unroll
      for (int e = 0; e < 4; ++e) acc[e] += qcw[(c + e) * 4 + j] * xv[e];
    }
    float ss = 0.f;
#pragma unroll
    for (int e = 0; e < 4; ++e) { acc[e] = silu_f(acc[e]); ss += acc[e] * acc[e]; }
#pragma unroll
    for (int m = 16; m >= 1; m >>= 1) ss += __shfl_xor(ss, m);
    const float rn = rsqrtf(ss + 1e-6f) * SCALE_Q;   // fold DK^-0.5 into q
    ushort4 o = {f2bf(acc[0] * rn), f2bf(acc[1] * rn), f2bf(acc[2] * rn), f2bf(acc[3] * rn)};
    *(ushort4*)(qb + (size_t)bt * 1024 + c) = o;
  }
  // ---- k ----
  {
    const int c = tid * 4;
    float acc[4] = {0.f, 0.f, 0.f, 0.f};
#pragma unroll
    for (int j = 0; j < 4; ++j) {
      const int tt = t - 3 + j;
      if (tt < 0) continue;
      const ushort4 x = *(const ushort4*)(Y + (size_t)(bt - 3 + j) * NBIG + 1024 + c);
      const float xv[4] = {bf2f(x.x), bf2f(x.y), bf2f(x.z), bf2f(x.w)};
#pragma unroll
      for (int e = 0; e < 4; ++e) acc[e] += kcw[(c + e) * 4 + j] * xv[e];
    }
    float ss = 0.f;
#pragma unroll
    for (int e = 0; e < 4; ++e) { acc[e] = silu_f(acc[e]); ss += acc[e] * acc[e]; }
#pragma unroll
    for (int m = 16; m >= 1; m >>= 1) ss += __shfl_xor(ss, m);
    const float rn = rsqrtf(ss + 1e-6f);
    ushort4 o = {f2bf(acc[0] * rn), f2bf(acc[1] * rn), f2bf(acc[2] * rn), f2bf(acc[3] * rn)};
    *(ushort4*)(kb + (size_t)bt * 1024 + c) = o;
  }
  // ---- v: channels tid*8 .. +7 (fp32 out; beta applied in chunk_prep) ----
  {
    const int c = tid * 8;
#pragma unroll
    for (int half = 0; half < 2; ++half) {
      const int c2 = c + half * 4;
      float acc[4] = {0.f, 0.f, 0.f, 0.f};
#pragma unroll
      for (int j = 0; j < 4; ++j) {
        const int tt = t - 3 + j;
        if (tt < 0) continue;
        const ushort4 x = *(const ushort4*)(Y + (size_t)(bt - 3 + j) * NBIG + 2048 + c2);
        const float xv[4] = {bf2f(x.x), bf2f(x.y), bf2f(x.z), bf2f(x.w)};
#pragma unroll
        for (int e = 0; e < 4; ++e) acc[e] += vcw[(c2 + e) * 4 + j] * xv[e];
      }
#pragma unroll
      for (int e = 0; e < 4; ++e) acc[e] = silu_f(acc[e]);
      float4 o = {acc[0], acc[1], acc[2], acc[3]};
      *(float4*)(vb + (size_t)bt * 2048 + c2) = o;
    }
  }
  // ---- per-step scalars: {g (log decay), beta} ----
  if (tid < 8) {
    const int hh = tid;
    const unsigned short* Yb = Y + (size_t)bt * NBIG;
    float a = bf2f(Yb[6144 + hh]) + dt_bias[hh];
    float sp = (a > 20.f) ? a : log1pf(expf(a));
    float g = -expf(A_log[hh]) * sp;
    float bp = bf2f(Yb[6152 + hh]);
    float be = 1.f / (1.f + expf(-bp));
    float2 o; o.x = g; o.y = be;
    scb[(size_t)bt * 8 + hh] = o;
  }
}

// ---------------- small NT GEMM on LDS operands: OUT[i][j] = sum_k A[i][k]*B[j][k] ----------------
// A: [M][K] bf16 LDS, B: [N][K] bf16 LDS. 4 waves. Output fp32 LDS (ld=N) or bf16 global (ldg).
template <int M, int N, int K, bool TOGLOB>
__device__ __forceinline__ void mm_nt_lds(const unsigned short* A, const unsigned short* B,
                                          float* outF, unsigned short* outG, int ldg, int tid) {
  constexpr int NT16 = N / 16;
  constexpr int PW = (M / 16) * NT16 / 4;
  const int w = tid >> 6, l = tid & 63;
  const int row = l & 15, ko = (l >> 4) * 8;
  f32x4 acc[PW];
#pragma unroll
  for (int i = 0; i < PW; ++i)
#pragma unroll
    for (int r = 0; r < 4; ++r) acc[i][r] = 0.f;
#pragma unroll
  for (int i = 0; i < PW; ++i) {
    const int ti = w + 4 * i;
    const int rt = ti / NT16, ct = ti % NT16;
#pragma unroll
    for (int kk = 0; kk < K / 32; ++kk) {
      bf16x8 af = *(const bf16x8*)(A + (rt * 16 + row) * K + kk * 32 + ko);
      bf16x8 bf = *(const bf16x8*)(B + (ct * 16 + row) * K + kk * 32 + ko);
      acc[i] = __builtin_amdgcn_mfma_f32_16x16x32_bf16(af, bf, acc[i], 0, 0, 0);
    }
  }
#pragma unroll
  for (int i = 0; i < PW; ++i) {
    const int ti = w + 4 * i;
    const int rt = ti / NT16, ct = ti % NT16;
    const int r0 = rt * 16 + (l >> 4) * 4;
    const int col = ct * 16 + (l & 15);
#pragma unroll
    for (int r = 0; r < 4; ++r) {
      if constexpr (TOGLOB) outG[(size_t)(r0 + r) * ldg + col] = f2bf(acc[i][r]);
      else                  outF[(r0 + r) * N + col] = acc[i][r];
    }
  }
}

// ---------------- phase 1: per-chunk UT transform (chunk C=64) ----------------
// per chunk-head ch = bh*16 + p: outputs W, Ub, Att, Qg, KgT, dec.
__global__ __launch_bounds__(256, 1) void chunk_prep(
    const unsigned short* __restrict__ qb, const unsigned short* __restrict__ kb,
    const float* __restrict__ vb, const float2* __restrict__ scb,
    unsigned short* __restrict__ Wg, unsigned short* __restrict__ Ubg,
    unsigned short* __restrict__ Attg, unsigned short* __restrict__ Qgg,
    unsigned short* __restrict__ KgTg, float* __restrict__ decg) {
  __shared__ unsigned short Kb_s[64 * 128];
  __shared__ unsigned short Qb_s[64 * 128];     // later reused as KbgT [128][64]
  __shared__ unsigned short VbT_s[256 * 64];    // beta*V transposed
  __shared__ unsigned short Mb_s[4096];         // I + A (bf16)
  __shared__ unsigned short Xrow_s[4096];       // X row-major bf16
  __shared__ unsigned short Xt_s[4096];         // X^T bf16
  __shared__ unsigned short Yt_s[4096];         // Y^T bf16
  __shared__ float F1_s[4096];                  // X fp32
  __shared__ float F2_s[4096];                  // GEMM scratch fp32
  __shared__ float carr_s[64];
  __shared__ float beta_s[64];

  const int tid = threadIdx.x;
  const int ch = blockIdx.x;
  const int bh = ch >> 4, p = ch & 15;
  const int b = bh >> 3, h = bh & 7;
  const size_t tbase = (size_t)b * T_LEN + p * 64;

  // 1. per-step scalars + cumulative log-decay (inclusive scan over 64 lanes of wave 0)
  if (tid < 64) {
    float2 gb = scb[(tbase + tid) * 8 + h];
    float c = gb.x;
#pragma unroll
    for (int d = 1; d < 64; d <<= 1) {
      float y = __shfl_up(c, d);
      if (tid >= d) c += y;
    }
    carr_s[tid] = c;
    beta_s[tid] = gb.y;
    if (tid == 63) decg[ch] = __expf(c);
  }
  // 2. stage K, Q chunks (bf16) via global_load_lds
#pragma unroll
  for (int i = 0; i < 4; ++i) {
    const int f = i * 256 + tid;
    const int t = f >> 4, c8 = f & 15;
    GLDS(kb + (tbase + t) * 1024 + h * 128 + c8 * 8, (char*)Kb_s + f * 16);
    GLDS(qb + (tbase + t) * 1024 + h * 128 + c8 * 8, (char*)Qb_s + f * 16);
  }
  __syncthreads();
  // 3. VbT[v][t] = bf16(beta_t * v[t][v])
#pragma unroll
  for (int i = 0; i < 16; ++i) {
    const int m = i * 256 + tid;
    const int t = m >> 6, c4 = (m & 63) * 4;
    float4 v = *(const float4*)(vb + (tbase + t) * 2048 + h * 256 + c4);
    const float bt = beta_s[t];
    VbT_s[(c4 + 0) * 64 + t] = f2bf(bt * v.x);
    VbT_s[(c4 + 1) * 64 + t] = f2bf(bt * v.y);
    VbT_s[(c4 + 2) * 64 + t] = f2bf(bt * v.z);
    VbT_s[(c4 + 3) * 64 + t] = f2bf(bt * v.w);
  }
  __syncthreads();
  // 4. A_raw = K K^T
  mm_nt_lds<64, 64, 128, false>(Kb_s, Kb_s, F2_s, nullptr, 0, tid);
  __syncthreads();
  // 5. M = I + A, X0 = I - A  (A[t][j] = beta_t exp(c_t-c_j) (k_t.k_j), j<t)
#pragma unroll
  for (int i = 0; i < 16; ++i) {
    const int idx = i * 256 + tid;
    const int t = idx >> 6, j = idx & 63;
    const float kk = F2_s[idx];
    const float av = (j < t) ? beta_s[t] * __expf(carr_s[t] - carr_s[j]) * kk : 0.f;
    const float dg = (t == j) ? 1.f : 0.f;
    Mb_s[idx] = f2bf(dg + av);
    const float x0 = dg - av;
    F1_s[idx] = x0;
    const unsigned short xb = f2bf(x0);
    Xrow_s[idx] = xb;
    Xt_s[j * 64 + t] = xb;
  }
  __syncthreads();
  // 6. Newton x5: X <- X(2I - M X)   (exact: A nilpotent, err = A^64 = 0)
  for (int it = 0; it < 5; ++it) {
    mm_nt_lds<64, 64, 64, false>(Mb_s, Xt_s, F2_s, nullptr, 0, tid);   // Y = M X
    __syncthreads();
#pragma unroll
    for (int i = 0; i < 16; ++i) {
      const int idx = i * 256 + tid;
      Yt_s[(idx & 63) * 64 + (idx >> 6)] = f2bf(F2_s[idx]);
    }
    __syncthreads();
    mm_nt_lds<64, 64, 64, false>(Xrow_s, Yt_s, F2_s, nullptr, 0, tid); // P = X Y
    __syncthreads();
#pragma unroll
    for (int i = 0; i < 16; ++i) {
      const int idx = i * 256 + tid;
      const float xn = 2.f * F1_s[idx] - F2_s[idx];
      F1_s[idx] = xn;
      const unsigned short xb = f2bf(xn);
      Xrow_s[idx] = xb;
      Xt_s[(idx & 63) * 64 + (idx >> 6)] = xb;
    }
    __syncthreads();
  }
  // 7. AttRaw = Q K^T
  mm_nt_lds<64, 64, 128, false>(Qb_s, Kb_s, F2_s, nullptr, 0, tid);
  __syncthreads();
  const float ctot = carr_s[63];
  // 8. Att (incl diag), Qg, KgT -> global
#pragma unroll
  for (int i = 0; i < 16; ++i) {
    const int idx = i * 256 + tid;
    const int t = idx >> 6, j = idx & 63;
    const float av = (j <= t) ? __expf(carr_s[t] - carr_s[j]) * F2_s[idx] : 0.f;
    Attg[(size_t)ch * 4096 + idx] = f2bf(av);
  }
#pragma unroll
  for (int i = 0; i < 32; ++i) {
    const int idx = i * 256 + tid;
    const int t = idx >> 7, d = idx & 127;
    Qgg[(size_t)ch * 8192 + idx] = f2bf(__expf(carr_s[t]) * bf2f(Qb_s[idx]));
  }
#pragma unroll
  for (int i = 0; i < 32; ++i) {
    const int idx = i * 256 + tid;
    const int d = idx >> 6, t = idx & 63;
    KgTg[(size_t)ch * 8192 + idx] = f2bf(__expf(ctot - carr_s[t]) * bf2f(Kb_s[t * 128 + d]));
  }
  __syncthreads();   // Qb reads done before reuse
  // 9. KbgT[d][t] = bf16(beta_t exp(c_t) k[t][d])  (into Qb space)
  unsigned short* KbgT = Qb_s;
#pragma unroll
  for (int i = 0; i < 32; ++i) {
    const int idx = i * 256 + tid;
    const int d = idx >> 6, t = idx & 63;
    KbgT[idx] = f2bf(beta_s[t] * __expf(carr_s[t]) * bf2f(Kb_s[t * 128 + d]));
  }
  __syncthreads();
  // 10. W = T (betaG.K)  [64x128];  Ub = T (betaV)  [64x256]  -> global bf16
  mm_nt_lds<64, 128, 64, true>(Xrow_s, KbgT, nullptr, Wg + (size_t)ch * 8192, 128, tid);
  mm_nt_lds<64, 256, 64, true>(Xrow_s, VbT_s, nullptr, Ubg + (size_t)ch * 16384, 256, tid);
}

// ---------------- phase 2: serial chunk recurrence (MFMA), 16 bh x 8 v-blocks ----------------
// stage buffer (ushort offsets): W@0(8192) Att@8192(4096) Qg@12288(8192) KgT@20480(8192) Ub@28672(2048)
__device__ __forceinline__ void p2_stage(
    const unsigned short* Wg, const unsigned short* Attg, const unsigned short* Qgg,
    const unsigned short* KgTg, const unsigned short* Ubg,
    int ch, int vb, unsigned short* buf, int tid) {
#pragma unroll
  for (int i = 0; i < 4; ++i) {
    const int f = i * 256 + tid;
    GLDS(Wg + (size_t)ch * 8192 + f * 8, (char*)buf + f * 16);
  }
#pragma unroll
  for (int i = 0; i < 2; ++i) {
    const int f = i * 256 + tid;
    GLDS(Attg + (size_t)ch * 4096 + f * 8, (char*)(buf + 8192) + f * 16);
  }
#pragma unroll
  for (int i = 0; i < 4; ++i) {
    const int f = i * 256 + tid;
    GLDS(Qgg + (size_t)ch * 8192 + f * 8, (char*)(buf + 12288) + f * 16);
  }
#pragma unroll
  for (int i = 0; i < 4; ++i) {
    const int f = i * 256 + tid;
    GLDS(KgTg + (size_t)ch * 8192 + f * 8, (char*)(buf + 20480) + f * 16);
  }
  {
    const int f = tid;
    const int t = f >> 2, c8 = f & 3;
    GLDS(Ubg + (size_t)ch * 16384 + t * 256 + vb * 32 + c8 * 8, (char*)(buf + 28672) + f * 16);
  }
}

__global__ __launch_bounds__(256, 1) void scan_chunks(
    const unsigned short* __restrict__ Wg, const unsigned short* __restrict__ Ubg,
    const unsigned short* __restrict__ Attg, const unsigned short* __restrict__ Qgg,
    const unsigned short* __restrict__ KgTg, const float* __restrict__ decg,
    float* __restrict__ osc) {
  __shared__ float StT_s[32 * 128];            // S^T fp32 [vcol][d]
  __shared__ unsigned short StTb_s[32 * 128];  // S^T bf16
  __shared__ unsigned short uT_s[32 * 64];     // u^T bf16 [vcol][t]
  __shared__ unsigned short stage_s[2][30720];

  const int tid = threadIdx.x;
  const int w = tid >> 6, l = tid & 63;
  const int row = l & 15, ko = (l >> 4) * 8;
  const int blk = blockIdx.x;                  // vb*16 + bh  (same-bh blocks share an XCD)
  const int vb = blk >> 4, bh = blk & 15;
  const int b = bh >> 3, h = bh & 7;

  for (int i = tid; i < 4096; i += 256) { StT_s[i] = 0.f; StTb_s[i] = 0; }
  p2_stage(Wg, Attg, Qgg, KgTg, Ubg, bh * 16, vb, stage_s[0], tid);

  for (int p = 0; p < 16; ++p) {
    unsigned short* bufc = stage_s[p & 1];
    const unsigned short* Wl   = bufc;
    const unsigned short* Attl = bufc + 8192;
    const unsigned short* Qgl  = bufc + 12288;
    const unsigned short* KgTl = bufc + 20480;
    const unsigned short* Ubl  = bufc + 28672;
    __syncthreads();   // staged buf + previous S writes visible (vmcnt drained)

    // ---- u = Ub - W S : acc [64x32], 8 tiles, 2/wave ----
    f32x4 uacc[2];
#pragma unroll
    for (int i = 0; i < 2; ++i)
#pragma unroll
      for (int r = 0; r < 4; ++r) uacc[i][r] = 0.f;
#pragma unroll
    for (int i = 0; i < 2; ++i) {
      const int ti = w + 4 * i;
      const int rt = ti >> 1, ct = ti & 1;
#pragma unroll
      for (int kk = 0; kk < 4; ++kk) {
        bf16x8 af = *(const bf16x8*)(Wl + (rt * 16 + row) * 128 + kk * 32 + ko);
        bf16x8 bf = *(const bf16x8*)(StTb_s + (ct * 16 + row) * 128 + kk * 32 + ko);
        uacc[i] = __builtin_amdgcn_mfma_f32_16x16x32_bf16(af, bf, uacc[i], 0, 0, 0);
      }
    }
#pragma unroll
    for (int i = 0; i < 2; ++i) {
      const int ti = w + 4 * i;
      const int rt = ti >> 1, ct = ti & 1;
      const int r0 = rt * 16 + (l >> 4) * 4;
      const int col = ct * 16 + (l & 15);
#pragma unroll
      for (int r = 0; r < 4; ++r) {
        const int t = r0 + r;
        const float ubv = bf2f(Ubl[t * 32 + col]);
        uT_s[col * 64 + t] = f2bf(ubv - uacc[i][r]);
      }
    }
    __syncthreads();   // uT ready
    if (p < 15)
      p2_stage(Wg, Attg, Qgg, KgTg, Ubg, bh * 16 + p + 1, vb, stage_s[(p + 1) & 1], tid);

    // ---- O = Qg S + Att u : acc [64x32] ----
    f32x4 oacc[2];
#pragma unroll
    for (int i = 0; i < 2; ++i)
#pragma unroll
      for (int r = 0; r < 4; ++r) oacc[i][r] = 0.f;
#pragma unroll
    for (int i = 0; i < 2; ++i) {
      const int ti = w + 4 * i;
      const int rt = ti >> 1, ct = ti & 1;
#pragma unroll
      for (int kk = 0; kk < 4; ++kk) {
        bf16x8 af = *(const bf16x8*)(Qgl + (rt * 16 + row) * 128 + kk * 32 + ko);
        bf16x8 bf = *(const bf16x8*)(StTb_s + (ct * 16 + row) * 128 + kk * 32 + ko);
        oacc[i] = __builtin_amdgcn_mfma_f32_16x16x32_bf16(af, bf, oacc[i], 0, 0, 0);
      }
#pragma unroll
      for (int kk = 0; kk < 2; ++kk) {
        bf16x8 af = *(const bf16x8*)(Attl + (rt * 16 + row) * 64 + kk * 32 + ko);
        bf16x8 bf = *(const bf16x8*)(uT_s + (ct * 16 + row) * 64 + kk * 32 + ko);
        oacc[i] = __builtin_amdgcn_mfma_f32_16x16x32_bf16(af, bf, oacc[i], 0, 0, 0);
      }
    }
    // ---- Snew^T = dec*S^T + (u^T)(KgT^T) : acc [32x128], 16 tiles, 4/wave ----
    f32x4 sacc[4];
#pragma unroll
    for (int i = 0; i < 4; ++i)
#pragma unroll
      for (int r = 0; r < 4; ++r) sacc[i][r] = 0.f;
#pragma unroll
    for (int i = 0; i < 4; ++i) {
      const int ti = w + 4 * i;
      const int srt = ti >> 3, sct = ti & 7;
#pragma unroll
      for (int kk = 0; kk < 2; ++kk) {
        bf16x8 af = *(const bf16x8*)(uT_s + (srt * 16 + row) * 64 + kk * 32 + ko);
        bf16x8 bf = *(const bf16x8*)(KgTl + (sct * 16 + row) * 64 + kk * 32 + ko);
        sacc[i] = __builtin_amdgcn_mfma_f32_16x16x32_bf16(af, bf, sacc[i], 0, 0, 0);
      }
    }
    const float dec = decg[bh * 16 + p];
    __syncthreads();   // all reads of StT/StTb done before overwrite

    // epilogues
#pragma unroll
    for (int i = 0; i < 2; ++i) {
      const int ti = w + 4 * i;
      const int rt = ti >> 1, ct = ti & 1;
      const int r0 = rt * 16 + (l >> 4) * 4;
      const int col = ct * 16 + (l & 15);
#pragma unroll
      for (int r = 0; r < 4; ++r) {
        const size_t trow = (size_t)b * T_LEN + p * 64 + r0 + r;
        osc[(trow * 8 + h) * 256 + vb * 32 + col] = oacc[i][r];
      }
    }
#pragma unroll
    for (int i = 0; i < 4; ++i) {
      const int ti = w + 4 * i;
      const int srt = ti >> 3, sct = ti & 7;
      const int r0 = srt * 16 + (l >> 4) * 4;
      const int cold = sct * 16 + (l & 15);
#pragma unroll
      for (int r = 0; r < 4; ++r) {
        const int idx = (r0 + r) * 128 + cold;
        const float sn = fmaf(dec, StT_s[idx], sacc[i][r]);
        StT_s[idx] = sn;
        StTb_s[idx] = f2bf(sn);
      }
    }
  }
}

// ---------------- gated RMSNorm + silu(gate) -> bf16 ----------------
__global__ __launch_bounds__(256) void rmsgate(
    const float* __restrict__ ob, const unsigned short* __restrict__ Y,
    const float* __restrict__ onw, unsigned short* __restrict__ Obf) {
  const int bt = blockIdx.x;
  const int tid = threadIdx.x;
  const int c = tid * 8;                // head = c/256 = tid/32
  const float* orow = ob + (size_t)bt * 2048 + c;
  const unsigned short* grow = Y + (size_t)bt * NBIG + 4096 + c;
  const float4 o0 = *(const float4*)orow, o1 = *(const float4*)(orow + 4);
  const ushort4 g0 = *(const ushort4*)grow, g1 = *(const ushort4*)(grow + 4);
  const float ov[8] = {o0.x, o0.y, o0.z, o0.w, o1.x, o1.y, o1.z, o1.w};
  const float gv[8] = {bf2f(g0.x), bf2f(g0.y), bf2f(g0.z), bf2f(g0.w),
                       bf2f(g1.x), bf2f(g1.y), bf2f(g1.z), bf2f(g1.w)};
  float ss = 0.f;
#pragma unroll
  for (int e = 0; e < 8; ++e) ss += ov[e] * ov[e];
#pragma unroll
  for (int m = 16; m >= 1; m >>= 1) ss += __shfl_xor(ss, m);
  const float rn = rsqrtf(ss * (1.f / 256.f) + 1e-5f);
  const int dv = c & 255;
  unsigned short rr[8];
#pragma unroll
  for (int e = 0; e < 8; ++e) {
    const float val = ov[e] * rn * onw[dv + e] * silu_f(gv[e]);
    rr[e] = f2bf(val);
  }
  ushort4 r0 = {rr[0], rr[1], rr[2], rr[3]};
  ushort4 r1 = {rr[4], rr[5], rr[6], rr[7]};
  *(ushort4*)(Obf + (size_t)bt * 2048 + c) = r0;
  *(ushort4*)(Obf + (size_t)bt * 2048 + c + 4) = r1;
}

extern "C" void kernel_launch(void* const* d_in, const int* in_sizes, int n_in,
                              void* d_out, int out_size, void* d_ws, size_t ws_size,
                              hipStream_t stream) {
  (void)in_sizes; (void)n_in; (void)out_size; (void)ws_size;
  const float* h    = (const float*)d_in[0];
  const float* qw   = (const float*)d_in[1];
  const float* kw   = (const float*)d_in[2];
  const float* vw   = (const float*)d_in[3];
  const float* aw   = (const float*)d_in[4];
  const float* bw   = (const float*)d_in[5];
  const float* gw   = (const float*)d_in[6];
  const float* ow   = (const float*)d_in[7];
  const float* qcw  = (const float*)d_in[8];
  const float* kcw  = (const float*)d_in[9];
  const float* vcw  = (const float*)d_in[10];
  const float* Alog = (const float*)d_in[11];
  const float* dtb  = (const float*)d_in[12];
  const float* onw  = (const float*)d_in[13];

  char* ws = (char*)d_ws;
  size_t off = 0;
  auto alloc = [&](size_t bytes) {
    char* p = ws + off;
    off = (off + bytes + 255) & ~(size_t)255;
    return p;
  };
  unsigned short* qb   = (unsigned short*)alloc(2048ull * 1024 * 2);
  unsigned short* kb   = (unsigned short*)alloc(2048ull * 1024 * 2);
  float* vb            = (float*)alloc(2048ull * 2048 * 4);
  float2* scb          = (float2*)alloc(2048ull * 8 * 8);
  unsigned short* hbf  = (unsigned short*)alloc(2048ull * 2048 * 2);
  unsigned short* Wb   = (unsigned short*)alloc((size_t)NBIG * 2048 * 2);
  unsigned short* owb  = (unsigned short*)alloc(2048ull * 2048 * 2);
  unsigned short* Ybf  = (unsigned short*)alloc(2048ull * NBIG * 2);
  float* osc           = (float*)alloc(2048ull * 2048 * 4);
  unsigned short* Obf  = (unsigned short*)alloc(2048ull * 2048 * 2);
  unsigned short* Wg   = (unsigned short*)alloc(256ull * 8192 * 2);
  unsigned short* Ubg  = (unsigned short*)alloc(256ull * 16384 * 2);
  unsigned short* Attg = (unsigned short*)alloc(256ull * 4096 * 2);
  unsigned short* Qgg  = (unsigned short*)alloc(256ull * 8192 * 2);
  unsigned short* KgTg = (unsigned short*)alloc(256ull * 8192 * 2);
  float* decg          = (float*)alloc(256ull * 4);

  cvt_bf16<<<4096, 256, 0, stream>>>(h, hbf, 1048576);
  build_w<<<12800, 256, 0, stream>>>(qw, kw, vw, gw, aw, bw, Wb);
  cvt_bf16<<<4096, 256, 0, stream>>>(ow, owb, 1048576);
  gemm_big<<<200, 512, 0, stream>>>((const bf16*)hbf, (const bf16*)Wb, Ybf, 2048, NBIG, 2048);
  convnorm<<<2048, 256, 0, stream>>>(Ybf, qcw, kcw, vcw, Alog, dtb, qb, kb, vb, scb);
  chunk_prep<<<256, 256, 0, stream>>>(qb, kb, vb, scb, Wg, Ubg, Attg, Qgg, KgTg, decg);
  scan_chunks<<<128, 256, 0, stream>>>(Wg, Ubg, Attg, Qgg, KgTg, decg, osc);
  rmsgate<<<2048, 256, 0, stream>>>(osc, Ybf, onw, Obf);
  gemm_nt<false><<<dim3(16, 16), 256, 0, stream>>>((const bf16*)Obf, (const bf16*)owb,
                                                   d_out, 2048, 2048, 2048);
}

// Round 5
// 320.745 us; speedup vs baseline: 1.9450x; 1.0125x over previous
//
#include <hip/hip_runtime.h>
#include <cstdint>

#define T_LEN 1024
#define NBIG  6400     // padded N for fused projection GEMM (6160 real cols, 25 x 256 tiles)
#define SCALE_Q 0.08838834764831843f   // DK^-0.5

typedef __bf16 bf16;
typedef __bf16 bf16x8 __attribute__((ext_vector_type(8)));
typedef float  f32x4  __attribute__((ext_vector_type(4)));

__device__ __forceinline__ unsigned short f2bf(float f) {
  unsigned int u = __builtin_bit_cast(unsigned int, f);
  u += 0x7FFFu + ((u >> 16) & 1u);          // RNE
  return (unsigned short)(u >> 16);
}
__device__ __forceinline__ float bf2f(unsigned short u) {
  return __builtin_bit_cast(float, (unsigned int)u << 16);
}
__device__ __forceinline__ float silu_f(float x) { return x / (1.f + __expf(-x)); }

#define GLDS(src, dst) \
  __builtin_amdgcn_global_load_lds( \
      (__attribute__((address_space(1))) void*)(void*)(src), \
      (__attribute__((address_space(3))) void*)(void*)(dst), 16, 0, 0)

// ---------------- fp32 -> bf16 conversion (4 elems/thread) ----------------
__global__ __launch_bounds__(256) void cvt_bf16(const float* __restrict__ in,
                                                unsigned short* __restrict__ out, int n4) {
  int idx = blockIdx.x * 256 + threadIdx.x;
  if (idx >= n4) return;
  float4 f = ((const float4*)in)[idx];
  ushort4 o = { f2bf(f.x), f2bf(f.y), f2bf(f.z), f2bf(f.w) };
  ((ushort4*)out)[idx] = o;
}

// ------------- build concatenated weight matrix W[NBIG][2048] bf16 -------------
__global__ __launch_bounds__(256) void build_w(
    const float* __restrict__ qw, const float* __restrict__ kw,
    const float* __restrict__ vw, const float* __restrict__ gw,
    const float* __restrict__ aw, const float* __restrict__ bw,
    unsigned short* __restrict__ W) {
  int idx = blockIdx.x * 256 + threadIdx.x;   // quad id, exact grid
  int r = idx >> 9;                           // row (2048/4 = 512 quads per row)
  int c = (idx & 511) << 2;
  const float* src;
  if      (r < 1024) src = qw + (size_t)r * 2048;
  else if (r < 2048) src = kw + (size_t)(r - 1024) * 2048;
  else if (r < 4096) src = vw + (size_t)(r - 2048) * 2048;
  else if (r < 6144) src = gw + (size_t)(r - 4096) * 2048;
  else if (r < 6152) src = aw + (size_t)(r - 6144) * 2048;
  else if (r < 6160) src = bw + (size_t)(r - 6152) * 2048;
  else               src = nullptr;
  ushort4 o;
  if (src) {
    float4 f = *(const float4*)(src + c);
    o = { f2bf(f.x), f2bf(f.y), f2bf(f.z), f2bf(f.w) };
  } else {
    o = { 0, 0, 0, 0 };
  }
  *(ushort4*)(W + (size_t)r * 2048 + c) = o;
}

// ============ big NT GEMM: 256x256 tile, BK=32, 4-deep ring, phase-split schedule ============
// C[M][N] = A[M][K] * B[N][K]^T, bf16 in, bf16 out. 512 threads = 8 waves (2M x 4N).
// Per K-step: 2 phases x {2 gloads stage kt+3; [vmcnt(10) P0 only]; s_barrier; ds_reads;
// setprio(1); 16 MFMA; setprio(0); s_barrier}. Counted vmcnt never reaches 0 (T3+T4).
// LDS swizzle (proven 0-conflict in R3): logical k-slot s of row r at physical s ^ ((r>>1)&3).
__global__ __launch_bounds__(512, 2) void gemm_big(
    const bf16* __restrict__ A, const bf16* __restrict__ Bm,
    unsigned short* __restrict__ C, int M, int N, int K) {
  __shared__ bf16 LA[4][256 * 32];
  __shared__ bf16 LB[4][256 * 32];
  const int tid = threadIdx.x;
  const int lane = tid & 63;
  const int wid = tid >> 6;
  const int wm = wid >> 2, wn = wid & 3;
  const int bid = blockIdx.x;
  const long brow = (long)(bid & 7) * 256;    // XCD x owns row-panel x (A panel L2-resident)
  const long bcol = (long)(bid >> 3) * 256;

  f32x4 acc[8][4];
#pragma unroll
  for (int m = 0; m < 8; ++m)
#pragma unroll
    for (int n = 0; n < 4; ++n)
#pragma unroll
      for (int r = 0; r < 4; ++r) acc[m][n][r] = 0.f;

  // staging: thread covers physical (row = tid>>2 [+128 for 2nd load], pslot = tid&3);
  // its global source is the logical slot that belongs there: lsl = pslot ^ ((row>>1)&3).
  const int srow = tid >> 2;
  const int slsl = (tid & 3) ^ ((tid >> 3) & 3);
  const bf16* Ag0 = A + (brow + srow) * (long)K + slsl * 8;
  const bf16* Ag1 = A + (brow + 128 + srow) * (long)K + slsl * 8;
  const bf16* Bg0 = Bm + (bcol + srow) * (long)K + slsl * 8;
  const bf16* Bg1 = Bm + (bcol + 128 + srow) * (long)K + slsl * 8;
  bf16* la0 = &LA[0][0] + tid * 8;   // linear dest: base + tid*16B
  bf16* lb0 = &LB[0][0] + tid * 8;

#define STAGEA(kt, bb)                                         \
  {                                                            \
    const long ko = (long)(kt) * 32;                           \
    GLDS(Ag0 + ko, la0 + (bb) * 8192);                         \
    GLDS(Ag1 + ko, la0 + (bb) * 8192 + 4096);                  \
  }
#define STAGEB(kt, bb)                                         \
  {                                                            \
    const long ko = (long)(kt) * 32;                           \
    GLDS(Bg0 + ko, lb0 + (bb) * 8192);                         \
    GLDS(Bg1 + ko, lb0 + (bb) * 8192 + 4096);                  \
  }

  // read offsets (halfwords): row*32 + (ks ^ ((r16>>1)&3))*8
  const int r16 = lane & 15;
  const int ks = lane >> 4;
  const int pso = (ks ^ ((r16 >> 1) & 3)) * 8;
  int rdA[8], rdB[4];
#pragma unroll
  for (int i = 0; i < 8; ++i) rdA[i] = (wm * 128 + i * 16 + r16) * 32 + pso;
#pragma unroll
  for (int j = 0; j < 4; ++j) rdB[j] = (wn * 64 + j * 16 + r16) * 32 + pso;

  const int nkt = K >> 5;
  STAGEA(0, 0); STAGEB(0, 0);
  STAGEA(1, 1); STAGEB(1, 1);
  STAGEA(2, 2); STAGEB(2, 2);   // 12 loads in flight

  for (int kt = 0; kt < nkt; ++kt) {
    const int kts = (kt + 3 < nkt) ? kt + 3 : nkt - 1;  // clamp src, keep count uniform
    const int bs = (kt + 3) & 3;                        // == (kt-1)&3: read-complete buffer
    const int bb = kt & 3;
    const bf16* lA = &LA[bb][0];
    const bf16* lB = &LB[bb][0];

    // ---------------- phase 0: C-rows wm*128 + [0,64) ----------------
    STAGEA(kts, bs);
    asm volatile("s_waitcnt vmcnt(10)" ::: "memory");   // A(kt),B(kt) landed; 10 newer in flight
    __builtin_amdgcn_s_barrier();                       // => ALL waves' kt loads landed
    __builtin_amdgcn_sched_barrier(0);
    bf16x8 bfr[4], af[4];
#pragma unroll
    for (int j = 0; j < 4; ++j) bfr[j] = *(const bf16x8*)(lB + rdB[j]);
#pragma unroll
    for (int i = 0; i < 4; ++i) af[i] = *(const bf16x8*)(lA + rdA[i]);
    __builtin_amdgcn_s_setprio(1);
#pragma unroll
    for (int i = 0; i < 4; ++i)
#pragma unroll
      for (int j = 0; j < 4; ++j)
        acc[i][j] = __builtin_amdgcn_mfma_f32_16x16x32_bf16(af[i], bfr[j], acc[i][j], 0, 0, 0);
    __builtin_amdgcn_s_setprio(0);
    __builtin_amdgcn_sched_barrier(0);
    __builtin_amdgcn_s_barrier();

    // ---------------- phase 1: C-rows wm*128 + [64,128) (B-frags reused in regs) ----------------
    STAGEB(kts, bs);
    __builtin_amdgcn_s_barrier();
    __builtin_amdgcn_sched_barrier(0);
#pragma unroll
    for (int i = 0; i < 4; ++i) af[i] = *(const bf16x8*)(lA + rdA[4 + i]);
    __builtin_amdgcn_s_setprio(1);
#pragma unroll
    for (int i = 0; i < 4; ++i)
#pragma unroll
      for (int j = 0; j < 4; ++j)
        acc[4 + i][j] = __builtin_amdgcn_mfma_f32_16x16x32_bf16(af[i], bfr[j], acc[4 + i][j], 0, 0, 0);
    __builtin_amdgcn_s_setprio(0);
    __builtin_amdgcn_sched_barrier(0);
    __builtin_amdgcn_s_barrier();
  }
#undef STAGEA
#undef STAGEB

  // epilogue: C/D layout col=lane&15, row=(lane>>4)*4+r
  const long row0 = brow + wm * 128 + ((lane >> 4) * 4);
  const long col0 = bcol + wn * 64 + (lane & 15);
#pragma unroll
  for (int m = 0; m < 8; ++m)
#pragma unroll
    for (int n = 0; n < 4; ++n)
#pragma unroll
      for (int r = 0; r < 4; ++r)
        C[(row0 + m * 16 + r) * (long)N + col0 + n * 16] = f2bf(acc[m][n][r]);
}

// ---------------- NT GEMM: C[M][N] = A[M][K] * B[N][K]^T, bf16 in ----------------
// m97 structure: 128x128 tile, BK=64, 4 waves (2x2), 16x16x32 MFMA, global_load_lds 16B
template <bool BF16OUT>
__global__ __launch_bounds__(256) void gemm_nt(
    const bf16* __restrict__ A, const bf16* __restrict__ Bm,
    void* __restrict__ Cv, int M, int N, int K) {
  __shared__ bf16 As[128 * 64];
  __shared__ bf16 Bs[128 * 64];
  const int tid = threadIdx.x;
  const int l = tid & 63;
  const int w = tid >> 6;
  const int wm = w >> 1, wn = w & 1;
  const long brow = (long)blockIdx.y * 128;
  const long bcol = (long)blockIdx.x * 128;

  f32x4 acc[4][4];
#pragma unroll
  for (int i = 0; i < 4; ++i)
#pragma unroll
    for (int j = 0; j < 4; ++j)
#pragma unroll
      for (int r = 0; r < 4; ++r) acc[i][j][r] = 0.f;

  const int rs = w * 8 + (l >> 3);   // staging row within 32-row group
  const int cs = (l & 7) * 8;        // staging col (elems)
  const bf16* Ag = A + (brow + rs) * (long)K + cs;
  const bf16* Bg = Bm + (bcol + rs) * (long)K + cs;
  bf16* AsW = As + tid * 8;          // == (rs*64 + cs), linear in lane order
  bf16* BsW = Bs + tid * 8;

  const int nkt = K >> 6;
  for (int kt = 0; kt < nkt; ++kt) {
    __syncthreads();
    const long ko = (long)kt * 64;
#pragma unroll
    for (int i = 0; i < 4; ++i) {
      GLDS(Ag + (long)i * 32 * K + ko, AsW + i * 32 * 64);
      GLDS(Bg + (long)i * 32 * K + ko, BsW + i * 32 * 64);
    }
    __syncthreads();
    const int row = l & 15;
    const int kof = (l >> 4) * 8;
#pragma unroll
    for (int kk = 0; kk < 2; ++kk) {
      bf16x8 af[4], bfr[4];
#pragma unroll
      for (int m = 0; m < 4; ++m)
        af[m] = *(const bf16x8*)(As + (wm * 64 + m * 16 + row) * 64 + kk * 32 + kof);
#pragma unroll
      for (int n = 0; n < 4; ++n)
        bfr[n] = *(const bf16x8*)(Bs + (wn * 64 + n * 16 + row) * 64 + kk * 32 + kof);
#pragma unroll
      for (int m = 0; m < 4; ++m)
#pragma unroll
        for (int n = 0; n < 4; ++n)
          acc[m][n] = __builtin_amdgcn_mfma_f32_16x16x32_bf16(af[m], bfr[n], acc[m][n], 0, 0, 0);
    }
  }
  // epilogue: C/D layout col=lane&15, row=(lane>>4)*4+r  [m89/m91 verified]
  const long row0 = brow + wm * 64 + ((l >> 4) * 4);
  const long col0 = bcol + wn * 64 + (l & 15);
#pragma unroll
  for (int m = 0; m < 4; ++m)
#pragma unroll
    for (int n = 0; n < 4; ++n)
#pragma unroll
      for (int r = 0; r < 4; ++r) {
        if constexpr (BF16OUT)
          ((unsigned short*)Cv)[(row0 + m * 16 + r) * (long)N + col0 + n * 16] = f2bf(acc[m][n][r]);
        else
          ((float*)Cv)[(row0 + m * 16 + r) * (long)N + col0 + n * 16] = acc[m][n][r];
      }
}

// ------------- conv(K=4)+SiLU+l2norm for q,k (bf16 out); conv+SiLU for v; scalars -------------
__global__ __launch_bounds__(256) void convnorm(
    const unsigned short* __restrict__ Y,
    const float* __restrict__ qcw, const float* __restrict__ kcw, const float* __restrict__ vcw,
    const float* __restrict__ A_log, const float* __restrict__ dt_bias,
    unsigned short* __restrict__ qb, unsigned short* __restrict__ kb,
    float* __restrict__ vb, float2* __restrict__ scb) {
  const int bt = blockIdx.x;            // b*T + t
  const int t = bt & (T_LEN - 1);
  const int tid = threadIdx.x;

  // ---- q: channels tid*4 .. +3 ----
  {
    const int c = tid * 4;
    float acc[4] = {0.f, 0.f, 0.f, 0.f};
#pragma unroll
    for (int j = 0; j < 4; ++j) {
      const int tt = t - 3 + j;
      if (tt < 0) continue;
      const ushort4 x = *(const ushort4*)(Y + (size_t)(bt - 3 + j) * NBIG + c);
      const float xv[4] = {bf2f(x.x), bf2f(x.y), bf2f(x.z), bf2f(x.w)};
#pragma unroll
      for (int e = 0; e < 4; ++e) acc[e] += qcw[(c + e) * 4 + j] * xv[e];
    }
    float ss = 0.f;
#pragma unroll
    for (int e = 0; e < 4; ++e) { acc[e] = silu_f(acc[e]); ss += acc[e] * acc[e]; }
#pragma unroll
    for (int m = 16; m >= 1; m >>= 1) ss += __shfl_xor(ss, m);
    const float rn = rsqrtf(ss + 1e-6f) * SCALE_Q;   // fold DK^-0.5 into q
    ushort4 o = {f2bf(acc[0] * rn), f2bf(acc[1] * rn), f2bf(acc[2] * rn), f2bf(acc[3] * rn)};
    *(ushort4*)(qb + (size_t)bt * 1024 + c) = o;
  }
  // ---- k ----
  {
    const int c = tid * 4;
    float acc[4] = {0.f, 0.f, 0.f, 0.f};
#pragma unroll
    for (int j = 0; j < 4; ++j) {
      const int tt = t - 3 + j;
      if (tt < 0) continue;
      const ushort4 x = *(const ushort4*)(Y + (size_t)(bt - 3 + j) * NBIG + 1024 + c);
      const float xv[4] = {bf2f(x.x), bf2f(x.y), bf2f(x.z), bf2f(x.w)};
#pragma unroll
      for (int e = 0; e < 4; ++e) acc[e] += kcw[(c + e) * 4 + j] * xv[e];
    }
    float ss = 0.f;
#pragma unroll
    for (int e = 0; e < 4; ++e) { acc[e] = silu_f(acc[e]); ss += acc[e] * acc[e]; }
#pragma unroll
    for (int m = 16; m >= 1; m >>= 1) ss += __shfl_xor(ss, m);
    const float rn = rsqrtf(ss + 1e-6f);
    ushort4 o = {f2bf(acc[0] * rn), f2bf(acc[1] * rn), f2bf(acc[2] * rn), f2bf(acc[3] * rn)};
    *(ushort4*)(kb + (size_t)bt * 1024 + c) = o;
  }
  // ---- v: channels tid*8 .. +7 (fp32 out; beta applied in chunk_prep) ----
  {
    const int c = tid * 8;
#pragma unroll
    for (int half = 0; half < 2; ++half) {
      const int c2 = c + half * 4;
      float acc[4] = {0.f, 0.f, 0.f, 0.f};
#pragma unroll
      for (int j = 0; j < 4; ++j) {
        const int tt = t - 3 + j;
        if (tt < 0) continue;
        const ushort4 x = *(const ushort4*)(Y + (size_t)(bt - 3 + j) * NBIG + 2048 + c2);
        const float xv[4] = {bf2f(x.x), bf2f(x.y), bf2f(x.z), bf2f(x.w)};
#pragma unroll
        for (int e = 0; e < 4; ++e) acc[e] += vcw[(c2 + e) * 4 + j] * xv[e];
      }
#pragma unroll
      for (int e = 0; e < 4; ++e) acc[e] = silu_f(acc[e]);
      float4 o = {acc[0], acc[1], acc[2], acc[3]};
      *(float4*)(vb + (size_t)bt * 2048 + c2) = o;
    }
  }
  // ---- per-step scalars: {g (log decay), beta} ----
  if (tid < 8) {
    const int hh = tid;
    const unsigned short* Yb = Y + (size_t)bt * NBIG;
    float a = bf2f(Yb[6144 + hh]) + dt_bias[hh];
    float sp = (a > 20.f) ? a : log1pf(expf(a));
    float g = -expf(A_log[hh]) * sp;
    float bp = bf2f(Yb[6152 + hh]);
    float be = 1.f / (1.f + expf(-bp));
    float2 o; o.x = g; o.y = be;
    scb[(size_t)bt * 8 + hh] = o;
  }
}

// ---------------- small NT GEMM on LDS operands: OUT[i][j] = sum_k A[i][k]*B[j][k] ----------------
// A: [M][K] bf16 LDS, B: [N][K] bf16 LDS. 4 waves. Output fp32 LDS (ld=N) or bf16 global (ldg).
template <int M, int N, int K, bool TOGLOB>
__device__ __forceinline__ void mm_nt_lds(const unsigned short* A, const unsigned short* B,
                                          float* outF, unsigned short* outG, int ldg, int tid) {
  constexpr int NT16 = N / 16;
  constexpr int PW = (M / 16) * NT16 / 4;
  const int w = tid >> 6, l = tid & 63;
  const int row = l & 15, ko = (l >> 4) * 8;
  f32x4 acc[PW];
#pragma unroll
  for (int i = 0; i < PW; ++i)
#pragma unroll
    for (int r = 0; r < 4; ++r) acc[i][r] = 0.f;
#pragma unroll
  for (int i = 0; i < PW; ++i) {
    const int ti = w + 4 * i;
    const int rt = ti / NT16, ct = ti % NT16;
#pragma unroll
    for (int kk = 0; kk < K / 32; ++kk) {
      bf16x8 af = *(const bf16x8*)(A + (rt * 16 + row) * K + kk * 32 + ko);
      bf16x8 bf = *(const bf16x8*)(B + (ct * 16 + row) * K + kk * 32 + ko);
      acc[i] = __builtin_amdgcn_mfma_f32_16x16x32_bf16(af, bf, acc[i], 0, 0, 0);
    }
  }
#pragma unroll
  for (int i = 0; i < PW; ++i) {
    const int ti = w + 4 * i;
    const int rt = ti / NT16, ct = ti % NT16;
    const int r0 = rt * 16 + (l >> 4) * 4;
    const int col = ct * 16 + (l & 15);
#pragma unroll
    for (int r = 0; r < 4; ++r) {
      if constexpr (TOGLOB) outG[(size_t)(r0 + r) * ldg + col] = f2bf(acc[i][r]);
      else                  outF[(r0 + r) * N + col] = acc[i][r];
    }
  }
}

// ---------------- phase 1: per-chunk UT transform (chunk C=64) ----------------
// per chunk-head ch = bh*16 + p: outputs W, Ub, Att, Qg, KgT, dec.
__global__ __launch_bounds__(256, 1) void chunk_prep(
    const unsigned short* __restrict__ qb, const unsigned short* __restrict__ kb,
    const float* __restrict__ vb, const float2* __restrict__ scb,
    unsigned short* __restrict__ Wg, unsigned short* __restrict__ Ubg,
    unsigned short* __restrict__ Attg, unsigned short* __restrict__ Qgg,
    unsigned short* __restrict__ KgTg, float* __restrict__ decg) {
  __shared__ unsigned short Kb_s[64 * 128];
  __shared__ unsigned short Qb_s[64 * 128];     // later reused as KbgT [128][64]
  __shared__ unsigned short VbT_s[256 * 64];    // beta*V transposed
  __shared__ unsigned short Mb_s[4096];         // I + A (bf16)
  __shared__ unsigned short Xrow_s[4096];       // X row-major bf16
  __shared__ unsigned short Xt_s[4096];         // X^T bf16
  __shared__ unsigned short Yt_s[4096];         // Y^T bf16
  __shared__ float F1_s[4096];                  // X fp32
  __shared__ float F2_s[4096];                  // GEMM scratch fp32
  __shared__ float carr_s[64];
  __shared__ float beta_s[64];

  const int tid = threadIdx.x;
  const int ch = blockIdx.x;
  const int bh = ch >> 4, p = ch & 15;
  const int b = bh >> 3, h = bh & 7;
  const size_t tbase = (size_t)b * T_LEN + p * 64;

  // 1. per-step scalars + cumulative log-decay (inclusive scan over 64 lanes of wave 0)
  if (tid < 64) {
    float2 gb = scb[(tbase + tid) * 8 + h];
    float c = gb.x;
#pragma unroll
    for (int d = 1; d < 64; d <<= 1) {
      float y = __shfl_up(c, d);
      if (tid >= d) c += y;
    }
    carr_s[tid] = c;
    beta_s[tid] = gb.y;
    if (tid == 63) decg[ch] = __expf(c);
  }
  // 2. stage K, Q chunks (bf16) via global_load_lds
#pragma unroll
  for (int i = 0; i < 4; ++i) {
    const int f = i * 256 + tid;
    const int t = f >> 4, c8 = f & 15;
    GLDS(kb + (tbase + t) * 1024 + h * 128 + c8 * 8, (char*)Kb_s + f * 16);
    GLDS(qb + (tbase + t) * 1024 + h * 128 + c8 * 8, (char*)Qb_s + f * 16);
  }
  __syncthreads();
  // 3. VbT[v][t] = bf16(beta_t * v[t][v])
#pragma unroll
  for (int i = 0; i < 16; ++i) {
    const int m = i * 256 + tid;
    const int t = m >> 6, c4 = (m & 63) * 4;
    float4 v = *(const float4*)(vb + (tbase + t) * 2048 + h * 256 + c4);
    const float bt = beta_s[t];
    VbT_s[(c4 + 0) * 64 + t] = f2bf(bt * v.x);
    VbT_s[(c4 + 1) * 64 + t] = f2bf(bt * v.y);
    VbT_s[(c4 + 2) * 64 + t] = f2bf(bt * v.z);
    VbT_s[(c4 + 3) * 64 + t] = f2bf(bt * v.w);
  }
  __syncthreads();
  // 4. A_raw = K K^T
  mm_nt_lds<64, 64, 128, false>(Kb_s, Kb_s, F2_s, nullptr, 0, tid);
  __syncthreads();
  // 5. M = I + A, X0 = I - A  (A[t][j] = beta_t exp(c_t-c_j) (k_t.k_j), j<t)
#pragma unroll
  for (int i = 0; i < 16; ++i) {
    const int idx = i * 256 + tid;
    const int t = idx >> 6, j = idx & 63;
    const float kk = F2_s[idx];
    const float av = (j < t) ? beta_s[t] * __expf(carr_s[t] - carr_s[j]) * kk : 0.f;
    const float dg = (t == j) ? 1.f : 0.f;
    Mb_s[idx] = f2bf(dg + av);
    const float x0 = dg - av;
    F1_s[idx] = x0;
    const unsigned short xb = f2bf(x0);
    Xrow_s[idx] = xb;
    Xt_s[j * 64 + t] = xb;
  }
  __syncthreads();
  // 6. Newton x5: X <- X(2I - M X)   (exact: A nilpotent, err = A^64 = 0)
  for (int it = 0; it < 5; ++it) {
    mm_nt_lds<64, 64, 64, false>(Mb_s, Xt_s, F2_s, nullptr, 0, tid);   // Y = M X
    __syncthreads();
#pragma unroll
    for (int i = 0; i < 16; ++i) {
      const int idx = i * 256 + tid;
      Yt_s[(idx & 63) * 64 + (idx >> 6)] = f2bf(F2_s[idx]);
    }
    __syncthreads();
    mm_nt_lds<64, 64, 64, false>(Xrow_s, Yt_s, F2_s, nullptr, 0, tid); // P = X Y
    __syncthreads();
#pragma unroll
    for (int i = 0; i < 16; ++i) {
      const int idx = i * 256 + tid;
      const float xn = 2.f * F1_s[idx] - F2_s[idx];
      F1_s[idx] = xn;
      const unsigned short xb = f2bf(xn);
      Xrow_s[idx] = xb;
      Xt_s[(idx & 63) * 64 + (idx >> 6)] = xb;
    }
    __syncthreads();
  }
  // 7. AttRaw = Q K^T
  mm_nt_lds<64, 64, 128, false>(Qb_s, Kb_s, F2_s, nullptr, 0, tid);
  __syncthreads();
  const float ctot = carr_s[63];
  // 8. Att (incl diag), Qg, KgT -> global
#pragma unroll
  for (int i = 0; i < 16; ++i) {
    const int idx = i * 256 + tid;
    const int t = idx >> 6, j = idx & 63;
    const float av = (j <= t) ? __expf(carr_s[t] - carr_s[j]) * F2_s[idx] : 0.f;
    Attg[(size_t)ch * 4096 + idx] = f2bf(av);
  }
#pragma unroll
  for (int i = 0; i < 32; ++i) {
    const int idx = i * 256 + tid;
    const int t = idx >> 7, d = idx & 127;
    Qgg[(size_t)ch * 8192 + idx] = f2bf(__expf(carr_s[t]) * bf2f(Qb_s[idx]));
  }
#pragma unroll
  for (int i = 0; i < 32; ++i) {
    const int idx = i * 256 + tid;
    const int d = idx >> 6, t = idx & 63;
    KgTg[(size_t)ch * 8192 + idx] = f2bf(__expf(ctot - carr_s[t]) * bf2f(Kb_s[t * 128 + d]));
  }
  __syncthreads();   // Qb reads done before reuse
  // 9. KbgT[d][t] = bf16(beta_t exp(c_t) k[t][d])  (into Qb space)
  unsigned short* KbgT = Qb_s;
#pragma unroll
  for (int i = 0; i < 32; ++i) {
    const int idx = i * 256 + tid;
    const int d = idx >> 6, t = idx & 63;
    KbgT[idx] = f2bf(beta_s[t] * __expf(carr_s[t]) * bf2f(Kb_s[t * 128 + d]));
  }
  __syncthreads();
  // 10. W = T (betaG.K)  [64x128];  Ub = T (betaV)  [64x256]  -> global bf16
  mm_nt_lds<64, 128, 64, true>(Xrow_s, KbgT, nullptr, Wg + (size_t)ch * 8192, 128, tid);
  mm_nt_lds<64, 256, 64, true>(Xrow_s, VbT_s, nullptr, Ubg + (size_t)ch * 16384, 256, tid);
}

// ---------------- phase 2: serial chunk recurrence (MFMA), 16 bh x 8 v-blocks ----------------
// stage buffer (ushort offsets): W@0(8192) Att@8192(4096) Qg@12288(8192) KgT@20480(8192) Ub@28672(2048)
__device__ __forceinline__ void p2_stage(
    const unsigned short* Wg, const unsigned short* Attg, const unsigned short* Qgg,
    const unsigned short* KgTg, const unsigned short* Ubg,
    int ch, int vb, unsigned short* buf, int tid) {
#pragma unroll
  for (int i = 0; i < 4; ++i) {
    const int f = i * 256 + tid;
    GLDS(Wg + (size_t)ch * 8192 + f * 8, (char*)buf + f * 16);
  }
#pragma unroll
  for (int i = 0; i < 2; ++i) {
    const int f = i * 256 + tid;
    GLDS(Attg + (size_t)ch * 4096 + f * 8, (char*)(buf + 8192) + f * 16);
  }
#pragma unroll
  for (int i = 0; i < 4; ++i) {
    const int f = i * 256 + tid;
    GLDS(Qgg + (size_t)ch * 8192 + f * 8, (char*)(buf + 12288) + f * 16);
  }
#pragma unroll
  for (int i = 0; i < 4; ++i) {
    const int f = i * 256 + tid;
    GLDS(KgTg + (size_t)ch * 8192 + f * 8, (char*)(buf + 20480) + f * 16);
  }
  {
    const int f = tid;
    const int t = f >> 2, c8 = f & 3;
    GLDS(Ubg + (size_t)ch * 16384 + t * 256 + vb * 32 + c8 * 8, (char*)(buf + 28672) + f * 16);
  }
}

__global__ __launch_bounds__(256, 1) void scan_chunks(
    const unsigned short* __restrict__ Wg, const unsigned short* __restrict__ Ubg,
    const unsigned short* __restrict__ Attg, const unsigned short* __restrict__ Qgg,
    const unsigned short* __restrict__ KgTg, const float* __restrict__ decg,
    float* __restrict__ osc) {
  __shared__ float StT_s[32 * 128];            // S^T fp32 [vcol][d]
  __shared__ unsigned short StTb_s[32 * 128];  // S^T bf16
  __shared__ unsigned short uT_s[32 * 64];     // u^T bf16 [vcol][t]
  __shared__ unsigned short stage_s[2][30720];

  const int tid = threadIdx.x;
  const int w = tid >> 6, l = tid & 63;
  const int row = l & 15, ko = (l >> 4) * 8;
  const int blk = blockIdx.x;                  // vb*16 + bh  (same-bh blocks share an XCD)
  const int vb = blk >> 4, bh = blk & 15;
  const int b = bh >> 3, h = bh & 7;

  for (int i = tid; i < 4096; i += 256) { StT_s[i] = 0.f; StTb_s[i] = 0; }
  p2_stage(Wg, Attg, Qgg, KgTg, Ubg, bh * 16, vb, stage_s[0], tid);

  for (int p = 0; p < 16; ++p) {
    unsigned short* bufc = stage_s[p & 1];
    const unsigned short* Wl   = bufc;
    const unsigned short* Attl = bufc + 8192;
    const unsigned short* Qgl  = bufc + 12288;
    const unsigned short* KgTl = bufc + 20480;
    const unsigned short* Ubl  = bufc + 28672;
    __syncthreads();   // staged buf + previous S writes visible (vmcnt drained)

    // ---- u = Ub - W S : acc [64x32], 8 tiles, 2/wave ----
    f32x4 uacc[2];
#pragma unroll
    for (int i = 0; i < 2; ++i)
#pragma unroll
      for (int r = 0; r < 4; ++r) uacc[i][r] = 0.f;
#pragma unroll
    for (int i = 0; i < 2; ++i) {
      const int ti = w + 4 * i;
      const int rt = ti >> 1, ct = ti & 1;
#pragma unroll
      for (int kk = 0; kk < 4; ++kk) {
        bf16x8 af = *(const bf16x8*)(Wl + (rt * 16 + row) * 128 + kk * 32 + ko);
        bf16x8 bf = *(const bf16x8*)(StTb_s + (ct * 16 + row) * 128 + kk * 32 + ko);
        uacc[i] = __builtin_amdgcn_mfma_f32_16x16x32_bf16(af, bf, uacc[i], 0, 0, 0);
      }
    }
#pragma unroll
    for (int i = 0; i < 2; ++i) {
      const int ti = w + 4 * i;
      const int rt = ti >> 1, ct = ti & 1;
      const int r0 = rt * 16 + (l >> 4) * 4;
      const int col = ct * 16 + (l & 15);
#pragma unroll
      for (int r = 0; r < 4; ++r) {
        const int t = r0 + r;
        const float ubv = bf2f(Ubl[t * 32 + col]);
        uT_s[col * 64 + t] = f2bf(ubv - uacc[i][r]);
      }
    }
    __syncthreads();   // uT ready
    if (p < 15)
      p2_stage(Wg, Attg, Qgg, KgTg, Ubg, bh * 16 + p + 1, vb, stage_s[(p + 1) & 1], tid);

    // ---- O = Qg S + Att u : acc [64x32] ----
    f32x4 oacc[2];
#pragma unroll
    for (int i = 0; i < 2; ++i)
#pragma unroll
      for (int r = 0; r < 4; ++r) oacc[i][r] = 0.f;
#pragma unroll
    for (int i = 0; i < 2; ++i) {
      const int ti = w + 4 * i;
      const int rt = ti >> 1, ct = ti & 1;
#pragma unroll
      for (int kk = 0; kk < 4; ++kk) {
        bf16x8 af = *(const bf16x8*)(Qgl + (rt * 16 + row) * 128 + kk * 32 + ko);
        bf16x8 bf = *(const bf16x8*)(StTb_s + (ct * 16 + row) * 128 + kk * 32 + ko);
        oacc[i] = __builtin_amdgcn_mfma_f32_16x16x32_bf16(af, bf, oacc[i], 0, 0, 0);
      }
#pragma unroll
      for (int kk = 0; kk < 2; ++kk) {
        bf16x8 af = *(const bf16x8*)(Attl + (rt * 16 + row) * 64 + kk * 32 + ko);
        bf16x8 bf = *(const bf16x8*)(uT_s + (ct * 16 + row) * 64 + kk * 32 + ko);
        oacc[i] = __builtin_amdgcn_mfma_f32_16x16x32_bf16(af, bf, oacc[i], 0, 0, 0);
      }
    }
    // ---- Snew^T = dec*S^T + (u^T)(KgT^T) : acc [32x128], 16 tiles, 4/wave ----
    f32x4 sacc[4];
#pragma unroll
    for (int i = 0; i < 4; ++i)
#pragma unroll
      for (int r = 0; r < 4; ++r) sacc[i][r] = 0.f;
#pragma unroll
    for (int i = 0; i < 4; ++i) {
      const int ti = w + 4 * i;
      const int srt = ti >> 3, sct = ti & 7;
#pragma unroll
      for (int kk = 0; kk < 2; ++kk) {
        bf16x8 af = *(const bf16x8*)(uT_s + (srt * 16 + row) * 64 + kk * 32 + ko);
        bf16x8 bf = *(const bf16x8*)(KgTl + (sct * 16 + row) * 64 + kk * 32 + ko);
        sacc[i] = __builtin_amdgcn_mfma_f32_16x16x32_bf16(af, bf, sacc[i], 0, 0, 0);
      }
    }
    const float dec = decg[bh * 16 + p];
    __syncthreads();   // all reads of StT/StTb done before overwrite

    // epilogues
#pragma unroll
    for (int i = 0; i < 2; ++i) {
      const int ti = w + 4 * i;
      const int rt = ti >> 1, ct = ti & 1;
      const int r0 = rt * 16 + (l >> 4) * 4;
      const int col = ct * 16 + (l & 15);
#pragma unroll
      for (int r = 0; r < 4; ++r) {
        const size_t trow = (size_t)b * T_LEN + p * 64 + r0 + r;
        osc[(trow * 8 + h) * 256 + vb * 32 + col] = oacc[i][r];
      }
    }
#pragma unroll
    for (int i = 0; i < 4; ++i) {
      const int ti = w + 4 * i;
      const int srt = ti >> 3, sct = ti & 7;
      const int r0 = srt * 16 + (l >> 4) * 4;
      const int cold = sct * 16 + (l & 15);
#pragma unroll
      for (int r = 0; r < 4; ++r) {
        const int idx = (r0 + r) * 128 + cold;
        const float sn = fmaf(dec, StT_s[idx], sacc[i][r]);
        StT_s[idx] = sn;
        StTb_s[idx] = f2bf(sn);
      }
    }
  }
}

// ---------------- gated RMSNorm + silu(gate) -> bf16 ----------------
__global__ __launch_bounds__(256) void rmsgate(
    const float* __restrict__ ob, const unsigned short* __restrict__ Y,
    const float* __restrict__ onw, unsigned short* __restrict__ Obf) {
  const int bt = blockIdx.x;
  const int tid = threadIdx.x;
  const int c = tid * 8;                // head = c/256 = tid/32
  const float* orow = ob + (size_t)bt * 2048 + c;
  const unsigned short* grow = Y + (size_t)bt * NBIG + 4096 + c;
  const float4 o0 = *(const float4*)orow, o1 = *(const float4*)(orow + 4);
  const ushort4 g0 = *(const ushort4*)grow, g1 = *(const ushort4*)(grow + 4);
  const float ov[8] = {o0.x, o0.y, o0.z, o0.w, o1.x, o1.y, o1.z, o1.w};
  const float gv[8] = {bf2f(g0.x), bf2f(g0.y), bf2f(g0.z), bf2f(g0.w),
                       bf2f(g1.x), bf2f(g1.y), bf2f(g1.z), bf2f(g1.w)};
  float ss = 0.f;
#pragma unroll
  for (int e = 0; e < 8; ++e) ss += ov[e] * ov[e];
#pragma unroll
  for (int m = 16; m >= 1; m >>= 1) ss += __shfl_xor(ss, m);
  const float rn = rsqrtf(ss * (1.f / 256.f) + 1e-5f);
  const int dv = c & 255;
  unsigned short rr[8];
#pragma unroll
  for (int e = 0; e < 8; ++e) {
    const float val = ov[e] * rn * onw[dv + e] * silu_f(gv[e]);
    rr[e] = f2bf(val);
  }
  ushort4 r0 = {rr[0], rr[1], rr[2], rr[3]};
  ushort4 r1 = {rr[4], rr[5], rr[6], rr[7]};
  *(ushort4*)(Obf + (size_t)bt * 2048 + c) = r0;
  *(ushort4*)(Obf + (size_t)bt * 2048 + c + 4) = r1;
}

extern "C" void kernel_launch(void* const* d_in, const int* in_sizes, int n_in,
                              void* d_out, int out_size, void* d_ws, size_t ws_size,
                              hipStream_t stream) {
  (void)in_sizes; (void)n_in; (void)out_size; (void)ws_size;
  const float* h    = (const float*)d_in[0];
  const float* qw   = (const float*)d_in[1];
  const float* kw   = (const float*)d_in[2];
  const float* vw   = (const float*)d_in[3];
  const float* aw   = (const float*)d_in[4];
  const float* bw   = (const float*)d_in[5];
  const float* gw   = (const float*)d_in[6];
  const float* ow   = (const float*)d_in[7];
  const float* qcw  = (const float*)d_in[8];
  const float* kcw  = (const float*)d_in[9];
  const float* vcw  = (const float*)d_in[10];
  const float* Alog = (const float*)d_in[11];
  const float* dtb  = (const float*)d_in[12];
  const float* onw  = (const float*)d_in[13];

  char* ws = (char*)d_ws;
  size_t off = 0;
  auto alloc = [&](size_t bytes) {
    char* p = ws + off;
    off = (off + bytes + 255) & ~(size_t)255;
    return p;
  };
  unsigned short* qb   = (unsigned short*)alloc(2048ull * 1024 * 2);
  unsigned short* kb   = (unsigned short*)alloc(2048ull * 1024 * 2);
  float* vb            = (float*)alloc(2048ull * 2048 * 4);
  float2* scb          = (float2*)alloc(2048ull * 8 * 8);
  unsigned short* hbf  = (unsigned short*)alloc(2048ull * 2048 * 2);
  unsigned short* Wb   = (unsigned short*)alloc((size_t)NBIG * 2048 * 2);
  unsigned short* owb  = (unsigned short*)alloc(2048ull * 2048 * 2);
  unsigned short* Ybf  = (unsigned short*)alloc(2048ull * NBIG * 2);
  float* osc           = (float*)alloc(2048ull * 2048 * 4);
  unsigned short* Obf  = (unsigned short*)alloc(2048ull * 2048 * 2);
  unsigned short* Wg   = (unsigned short*)alloc(256ull * 8192 * 2);
  unsigned short* Ubg  = (unsigned short*)alloc(256ull * 16384 * 2);
  unsigned short* Attg = (unsigned short*)alloc(256ull * 4096 * 2);
  unsigned short* Qgg  = (unsigned short*)alloc(256ull * 8192 * 2);
  unsigned short* KgTg = (unsigned short*)alloc(256ull * 8192 * 2);
  float* decg          = (float*)alloc(256ull * 4);

  cvt_bf16<<<4096, 256, 0, stream>>>(h, hbf, 1048576);
  build_w<<<12800, 256, 0, stream>>>(qw, kw, vw, gw, aw, bw, Wb);
  cvt_bf16<<<4096, 256, 0, stream>>>(ow, owb, 1048576);
  gemm_big<<<200, 512, 0, stream>>>((const bf16*)hbf, (const bf16*)Wb, Ybf, 2048, NBIG, 2048);
  convnorm<<<2048, 256, 0, stream>>>(Ybf, qcw, kcw, vcw, Alog, dtb, qb, kb, vb, scb);
  chunk_prep<<<256, 256, 0, stream>>>(qb, kb, vb, scb, Wg, Ubg, Attg, Qgg, KgTg, decg);
  scan_chunks<<<128, 256, 0, stream>>>(Wg, Ubg, Attg, Qgg, KgTg, decg, osc);
  rmsgate<<<2048, 256, 0, stream>>>(osc, Ybf, onw, Obf);
  gemm_nt<false><<<dim3(16, 16), 256, 0, stream>>>((const bf16*)Obf, (const bf16*)owb,
                                                   d_out, 2048, 2048, 2048);
}

// Round 6
// 318.016 us; speedup vs baseline: 1.9617x; 1.0086x over previous
//
#include <hip/hip_runtime.h>
#include <cstdint>

#define T_LEN 1024
#define NBIG  6400     // padded N for fused projection GEMM (6160 real cols, 25 x 256 tiles)
#define SCALE_Q 0.08838834764831843f   // DK^-0.5

typedef __bf16 bf16;
typedef __bf16 bf16x8 __attribute__((ext_vector_type(8)));
typedef float  f32x4  __attribute__((ext_vector_type(4)));

__device__ __forceinline__ unsigned short f2bf(float f) {
  unsigned int u = __builtin_bit_cast(unsigned int, f);
  u += 0x7FFFu + ((u >> 16) & 1u);          // RNE
  return (unsigned short)(u >> 16);
}
__device__ __forceinline__ float bf2f(unsigned short u) {
  return __builtin_bit_cast(float, (unsigned int)u << 16);
}
__device__ __forceinline__ float silu_f(float x) { return x / (1.f + __expf(-x)); }

#define GLDS(src, dst) \
  __builtin_amdgcn_global_load_lds( \
      (__attribute__((address_space(1))) void*)(void*)(src), \
      (__attribute__((address_space(3))) void*)(void*)(dst), 16, 0, 0)

// ---------------- fp32 -> bf16 conversion (4 elems/thread) ----------------
__global__ __launch_bounds__(256) void cvt_bf16(const float* __restrict__ in,
                                                unsigned short* __restrict__ out, int n4) {
  int idx = blockIdx.x * 256 + threadIdx.x;
  if (idx >= n4) return;
  float4 f = ((const float4*)in)[idx];
  ushort4 o = { f2bf(f.x), f2bf(f.y), f2bf(f.z), f2bf(f.w) };
  ((ushort4*)out)[idx] = o;
}

// ------------- build concatenated weight matrix W[NBIG][2048] bf16 -------------
__global__ __launch_bounds__(256) void build_w(
    const float* __restrict__ qw, const float* __restrict__ kw,
    const float* __restrict__ vw, const float* __restrict__ gw,
    const float* __restrict__ aw, const float* __restrict__ bw,
    unsigned short* __restrict__ W) {
  int idx = blockIdx.x * 256 + threadIdx.x;   // quad id, exact grid
  int r = idx >> 9;                           // row (2048/4 = 512 quads per row)
  int c = (idx & 511) << 2;
  const float* src;
  if      (r < 1024) src = qw + (size_t)r * 2048;
  else if (r < 2048) src = kw + (size_t)(r - 1024) * 2048;
  else if (r < 4096) src = vw + (size_t)(r - 2048) * 2048;
  else if (r < 6144) src = gw + (size_t)(r - 4096) * 2048;
  else if (r < 6152) src = aw + (size_t)(r - 6144) * 2048;
  else if (r < 6160) src = bw + (size_t)(r - 6152) * 2048;
  else               src = nullptr;
  ushort4 o;
  if (src) {
    float4 f = *(const float4*)(src + c);
    o = { f2bf(f.x), f2bf(f.y), f2bf(f.z), f2bf(f.w) };
  } else {
    o = { 0, 0, 0, 0 };
  }
  *(ushort4*)(W + (size_t)r * 2048 + c) = o;
}

// ============ big NT GEMM: 256x256 tile, BK=32, 4-deep ring, 1-barrier pipelined ============
// C[M][N] = A[M][K] * B[N][K]^T, bf16 in, bf16 out. 512 threads = 8 waves (2M x 4N).
// K-step: {STAGEA(kt+3); ds_read af1; MFMA(af0) | STAGEB(kt+3); MFMA(af1);
//          lgkmcnt(0); vmcnt(8); s_barrier; ds_read next af0/bfr from buf kt+1}.
// One barrier per K-step; counted vmcnt never reaches 0; no sched walls so the
// compiler interleaves ds_read/GLDS under the MFMA clusters (T3+T4).
// LDS swizzle (proven 0-conflict in R3/R4): logical k-slot s of row r at phys s ^ ((r>>1)&3).
__global__ __launch_bounds__(512, 2) void gemm_big(
    const bf16* __restrict__ A, const bf16* __restrict__ Bm,
    unsigned short* __restrict__ C, int M, int N, int K) {
  __shared__ bf16 LA[4][256 * 32];
  __shared__ bf16 LB[4][256 * 32];
  const int tid = threadIdx.x;
  const int lane = tid & 63;
  const int wid = tid >> 6;
  const int wm = wid >> 2, wn = wid & 3;
  const int bid = blockIdx.x;
  const long brow = (long)(bid & 7) * 256;    // XCD x owns row-panel x (A panel L2-resident)
  const long bcol = (long)(bid >> 3) * 256;

  f32x4 acc[8][4];
#pragma unroll
  for (int m = 0; m < 8; ++m)
#pragma unroll
    for (int n = 0; n < 4; ++n)
#pragma unroll
      for (int r = 0; r < 4; ++r) acc[m][n][r] = 0.f;

  // staging: thread covers physical (row = tid>>2 [+128 for 2nd load], pslot = tid&3);
  // its global source is the logical slot that belongs there: lsl = pslot ^ ((row>>1)&3).
  const int srow = tid >> 2;
  const int slsl = (tid & 3) ^ ((tid >> 3) & 3);
  const bf16* Ag0 = A + (brow + srow) * (long)K + slsl * 8;
  const bf16* Ag1 = A + (brow + 128 + srow) * (long)K + slsl * 8;
  const bf16* Bg0 = Bm + (bcol + srow) * (long)K + slsl * 8;
  const bf16* Bg1 = Bm + (bcol + 128 + srow) * (long)K + slsl * 8;
  bf16* la0 = &LA[0][0] + tid * 8;   // linear dest: base + tid*16B
  bf16* lb0 = &LB[0][0] + tid * 8;

#define STAGEA(kt, bb)                                         \
  {                                                            \
    const long ko = (long)(kt) * 32;                           \
    GLDS(Ag0 + ko, la0 + (bb) * 8192);                         \
    GLDS(Ag1 + ko, la0 + (bb) * 8192 + 4096);                  \
  }
#define STAGEB(kt, bb)                                         \
  {                                                            \
    const long ko = (long)(kt) * 32;                           \
    GLDS(Bg0 + ko, lb0 + (bb) * 8192);                         \
    GLDS(Bg1 + ko, lb0 + (bb) * 8192 + 4096);                  \
  }

  // read offsets (halfwords): row*32 + (ks ^ ((r16>>1)&3))*8
  const int r16 = lane & 15;
  const int ks = lane >> 4;
  const int pso = (ks ^ ((r16 >> 1) & 3)) * 8;
  int rdA[8], rdB[4];
#pragma unroll
  for (int i = 0; i < 8; ++i) rdA[i] = (wm * 128 + i * 16 + r16) * 32 + pso;
#pragma unroll
  for (int j = 0; j < 4; ++j) rdB[j] = (wn * 64 + j * 16 + r16) * 32 + pso;

  const int nkt = K >> 5;
  STAGEA(0, 0); STAGEB(0, 0);
  STAGEA(1, 1); STAGEB(1, 1);
  STAGEA(2, 2); STAGEB(2, 2);   // 12 loads in flight

  asm volatile("s_waitcnt vmcnt(8)" ::: "memory");   // buf0 landed
  __builtin_amdgcn_s_barrier();

  bf16x8 af0[4], af1[4], bfr[4];
#pragma unroll
  for (int j = 0; j < 4; ++j) bfr[j] = *(const bf16x8*)(&LB[0][0] + rdB[j]);
#pragma unroll
  for (int i = 0; i < 4; ++i) af0[i] = *(const bf16x8*)(&LA[0][0] + rdA[i]);

  for (int kt = 0; kt < nkt; ++kt) {
    const int kts = (kt + 3 < nkt) ? kt + 3 : nkt - 1;  // clamp src, keep count uniform
    const int bs = (kt + 3) & 3;                        // == (kt-1)&3: read-complete buffer
    const int bb = kt & 3;
    const int nb = (kt + 1) & 3;
    const bf16* lA = &LA[bb][0];

    STAGEA(kts, bs);
#pragma unroll
    for (int i = 0; i < 4; ++i) af1[i] = *(const bf16x8*)(lA + rdA[4 + i]);
    __builtin_amdgcn_s_setprio(1);
#pragma unroll
    for (int i = 0; i < 4; ++i)
#pragma unroll
      for (int j = 0; j < 4; ++j)
        acc[i][j] = __builtin_amdgcn_mfma_f32_16x16x32_bf16(af0[i], bfr[j], acc[i][j], 0, 0, 0);
    __builtin_amdgcn_s_setprio(0);

    STAGEB(kts, bs);
    __builtin_amdgcn_s_setprio(1);
#pragma unroll
    for (int i = 0; i < 4; ++i)
#pragma unroll
      for (int j = 0; j < 4; ++j)
        acc[4 + i][j] = __builtin_amdgcn_mfma_f32_16x16x32_bf16(af1[i], bfr[j], acc[4 + i][j], 0, 0, 0);
    __builtin_amdgcn_s_setprio(0);

    // end of K-step: kt+1's loads landed (8 newer stay in flight); own ds_reads drained
    asm volatile("s_waitcnt lgkmcnt(0)" ::: "memory");
    asm volatile("s_waitcnt vmcnt(8)" ::: "memory");
    __builtin_amdgcn_s_barrier();
    const bf16* lAn = &LA[nb][0];
    const bf16* lBn = &LB[nb][0];
#pragma unroll
    for (int j = 0; j < 4; ++j) bfr[j] = *(const bf16x8*)(lBn + rdB[j]);
#pragma unroll
    for (int i = 0; i < 4; ++i) af0[i] = *(const bf16x8*)(lAn + rdA[i]);
  }
#undef STAGEA
#undef STAGEB

  // epilogue: C/D layout col=lane&15, row=(lane>>4)*4+r
  const long row0 = brow + wm * 128 + ((lane >> 4) * 4);
  const long col0 = bcol + wn * 64 + (lane & 15);
#pragma unroll
  for (int m = 0; m < 8; ++m)
#pragma unroll
    for (int n = 0; n < 4; ++n)
#pragma unroll
      for (int r = 0; r < 4; ++r)
        C[(row0 + m * 16 + r) * (long)N + col0 + n * 16] = f2bf(acc[m][n][r]);
}

// ---------------- NT GEMM: C[M][N] = A[M][K] * B[N][K]^T, bf16 in ----------------
// m97 structure: 128x128 tile, BK=64, 4 waves (2x2), 16x16x32 MFMA, global_load_lds 16B
template <bool BF16OUT>
__global__ __launch_bounds__(256) void gemm_nt(
    const bf16* __restrict__ A, const bf16* __restrict__ Bm,
    void* __restrict__ Cv, int M, int N, int K) {
  __shared__ bf16 As[128 * 64];
  __shared__ bf16 Bs[128 * 64];
  const int tid = threadIdx.x;
  const int l = tid & 63;
  const int w = tid >> 6;
  const int wm = w >> 1, wn = w & 1;
  const long brow = (long)blockIdx.y * 128;
  const long bcol = (long)blockIdx.x * 128;

  f32x4 acc[4][4];
#pragma unroll
  for (int i = 0; i < 4; ++i)
#pragma unroll
    for (int j = 0; j < 4; ++j)
#pragma unroll
      for (int r = 0; r < 4; ++r) acc[i][j][r] = 0.f;

  const int rs = w * 8 + (l >> 3);   // staging row within 32-row group
  const int cs = (l & 7) * 8;        // staging col (elems)
  const bf16* Ag = A + (brow + rs) * (long)K + cs;
  const bf16* Bg = Bm + (bcol + rs) * (long)K + cs;
  bf16* AsW = As + tid * 8;          // == (rs*64 + cs), linear in lane order
  bf16* BsW = Bs + tid * 8;

  const int nkt = K >> 6;
  for (int kt = 0; kt < nkt; ++kt) {
    __syncthreads();
    const long ko = (long)kt * 64;
#pragma unroll
    for (int i = 0; i < 4; ++i) {
      GLDS(Ag + (long)i * 32 * K + ko, AsW + i * 32 * 64);
      GLDS(Bg + (long)i * 32 * K + ko, BsW + i * 32 * 64);
    }
    __syncthreads();
    const int row = l & 15;
    const int kof = (l >> 4) * 8;
#pragma unroll
    for (int kk = 0; kk < 2; ++kk) {
      bf16x8 af[4], bfr[4];
#pragma unroll
      for (int m = 0; m < 4; ++m)
        af[m] = *(const bf16x8*)(As + (wm * 64 + m * 16 + row) * 64 + kk * 32 + kof);
#pragma unroll
      for (int n = 0; n < 4; ++n)
        bfr[n] = *(const bf16x8*)(Bs + (wn * 64 + n * 16 + row) * 64 + kk * 32 + kof);
#pragma unroll
      for (int m = 0; m < 4; ++m)
#pragma unroll
        for (int n = 0; n < 4; ++n)
          acc[m][n] = __builtin_amdgcn_mfma_f32_16x16x32_bf16(af[m], bfr[n], acc[m][n], 0, 0, 0);
    }
  }
  // epilogue: C/D layout col=lane&15, row=(lane>>4)*4+r  [m89/m91 verified]
  const long row0 = brow + wm * 64 + ((l >> 4) * 4);
  const long col0 = bcol + wn * 64 + (l & 15);
#pragma unroll
  for (int m = 0; m < 4; ++m)
#pragma unroll
    for (int n = 0; n < 4; ++n)
#pragma unroll
      for (int r = 0; r < 4; ++r) {
        if constexpr (BF16OUT)
          ((unsigned short*)Cv)[(row0 + m * 16 + r) * (long)N + col0 + n * 16] = f2bf(acc[m][n][r]);
        else
          ((float*)Cv)[(row0 + m * 16 + r) * (long)N + col0 + n * 16] = acc[m][n][r];
      }
}

// ------------- conv(K=4)+SiLU+l2norm for q,k (bf16 out); conv+SiLU for v; scalars -------------
__global__ __launch_bounds__(256) void convnorm(
    const unsigned short* __restrict__ Y,
    const float* __restrict__ qcw, const float* __restrict__ kcw, const float* __restrict__ vcw,
    const float* __restrict__ A_log, const float* __restrict__ dt_bias,
    unsigned short* __restrict__ qb, unsigned short* __restrict__ kb,
    float* __restrict__ vb, float2* __restrict__ scb) {
  const int bt = blockIdx.x;            // b*T + t
  const int t = bt & (T_LEN - 1);
  const int tid = threadIdx.x;

  // ---- q: channels tid*4 .. +3 ----
  {
    const int c = tid * 4;
    float acc[4] = {0.f, 0.f, 0.f, 0.f};
#pragma unroll
    for (int j = 0; j < 4; ++j) {
      const int tt = t - 3 + j;
      if (tt < 0) continue;
      const ushort4 x = *(const ushort4*)(Y + (size_t)(bt - 3 + j) * NBIG + c);
      const float xv[4] = {bf2f(x.x), bf2f(x.y), bf2f(x.z), bf2f(x.w)};
#pragma unroll
      for (int e = 0; e < 4; ++e) acc[e] += qcw[(c + e) * 4 + j] * xv[e];
    }
    float ss = 0.f;
#pragma unroll
    for (int e = 0; e < 4; ++e) { acc[e] = silu_f(acc[e]); ss += acc[e] * acc[e]; }
#pragma unroll
    for (int m = 16; m >= 1; m >>= 1) ss += __shfl_xor(ss, m);
    const float rn = rsqrtf(ss + 1e-6f) * SCALE_Q;   // fold DK^-0.5 into q
    ushort4 o = {f2bf(acc[0] * rn), f2bf(acc[1] * rn), f2bf(acc[2] * rn), f2bf(acc[3] * rn)};
    *(ushort4*)(qb + (size_t)bt * 1024 + c) = o;
  }
  // ---- k ----
  {
    const int c = tid * 4;
    float acc[4] = {0.f, 0.f, 0.f, 0.f};
#pragma unroll
    for (int j = 0; j < 4; ++j) {
      const int tt = t - 3 + j;
      if (tt < 0) continue;
      const ushort4 x = *(const ushort4*)(Y + (size_t)(bt - 3 + j) * NBIG + 1024 + c);
      const float xv[4] = {bf2f(x.x), bf2f(x.y), bf2f(x.z), bf2f(x.w)};
#pragma unroll
      for (int e = 0; e < 4; ++e) acc[e] += kcw[(c + e) * 4 + j] * xv[e];
    }
    float ss = 0.f;
#pragma unroll
    for (int e = 0; e < 4; ++e) { acc[e] = silu_f(acc[e]); ss += acc[e] * acc[e]; }
#pragma unroll
    for (int m = 16; m >= 1; m >>= 1) ss += __shfl_xor(ss, m);
    const float rn = rsqrtf(ss + 1e-6f);
    ushort4 o = {f2bf(acc[0] * rn), f2bf(acc[1] * rn), f2bf(acc[2] * rn), f2bf(acc[3] * rn)};
    *(ushort4*)(kb + (size_t)bt * 1024 + c) = o;
  }
  // ---- v: channels tid*8 .. +7 (fp32 out; beta applied in chunk_prep) ----
  {
    const int c = tid * 8;
#pragma unroll
    for (int half = 0; half < 2; ++half) {
      const int c2 = c + half * 4;
      float acc[4] = {0.f, 0.f, 0.f, 0.f};
#pragma unroll
      for (int j = 0; j < 4; ++j) {
        const int tt = t - 3 + j;
        if (tt < 0) continue;
        const ushort4 x = *(const ushort4*)(Y + (size_t)(bt - 3 + j) * NBIG + 2048 + c2);
        const float xv[4] = {bf2f(x.x), bf2f(x.y), bf2f(x.z), bf2f(x.w)};
#pragma unroll
        for (int e = 0; e < 4; ++e) acc[e] += vcw[(c2 + e) * 4 + j] * xv[e];
      }
#pragma unroll
      for (int e = 0; e < 4; ++e) acc[e] = silu_f(acc[e]);
      float4 o = {acc[0], acc[1], acc[2], acc[3]};
      *(float4*)(vb + (size_t)bt * 2048 + c2) = o;
    }
  }
  // ---- per-step scalars: {g (log decay), beta} ----
  if (tid < 8) {
    const int hh = tid;
    const unsigned short* Yb = Y + (size_t)bt * NBIG;
    float a = bf2f(Yb[6144 + hh]) + dt_bias[hh];
    float sp = (a > 20.f) ? a : log1pf(expf(a));
    float g = -expf(A_log[hh]) * sp;
    float bp = bf2f(Yb[6152 + hh]);
    float be = 1.f / (1.f + expf(-bp));
    float2 o; o.x = g; o.y = be;
    scb[(size_t)bt * 8 + hh] = o;
  }
}

// ---------------- small NT GEMM on LDS operands: OUT[i][j] = sum_k A[i][k]*B[j][k] ----------------
// A: [M][K] bf16 LDS, B: [N][K] bf16 LDS. 4 waves. Output fp32 LDS (ld=N) or bf16 global (ldg).
template <int M, int N, int K, bool TOGLOB>
__device__ __forceinline__ void mm_nt_lds(const unsigned short* A, const unsigned short* B,
                                          float* outF, unsigned short* outG, int ldg, int tid) {
  constexpr int NT16 = N / 16;
  constexpr int PW = (M / 16) * NT16 / 4;
  const int w = tid >> 6, l = tid & 63;
  const int row = l & 15, ko = (l >> 4) * 8;
  f32x4 acc[PW];
#pragma unroll
  for (int i = 0; i < PW; ++i)
#pragma unroll
    for (int r = 0; r < 4; ++r) acc[i][r] = 0.f;
#pragma unroll
  for (int i = 0; i < PW; ++i) {
    const int ti = w + 4 * i;
    const int rt = ti / NT16, ct = ti % NT16;
#pragma unroll
    for (int kk = 0; kk < K / 32; ++kk) {
      bf16x8 af = *(const bf16x8*)(A + (rt * 16 + row) * K + kk * 32 + ko);
      bf16x8 bf = *(const bf16x8*)(B + (ct * 16 + row) * K + kk * 32 + ko);
      acc[i] = __builtin_amdgcn_mfma_f32_16x16x32_bf16(af, bf, acc[i], 0, 0, 0);
    }
  }
#pragma unroll
  for (int i = 0; i < PW; ++i) {
    const int ti = w + 4 * i;
    const int rt = ti / NT16, ct = ti % NT16;
    const int r0 = rt * 16 + (l >> 4) * 4;
    const int col = ct * 16 + (l & 15);
#pragma unroll
    for (int r = 0; r < 4; ++r) {
      if constexpr (TOGLOB) outG[(size_t)(r0 + r) * ldg + col] = f2bf(acc[i][r]);
      else                  outF[(r0 + r) * N + col] = acc[i][r];
    }
  }
}

// ---------------- phase 1: per-chunk UT transform (chunk C=64) ----------------
// per chunk-head ch = bh*16 + p: outputs W, Ub, Att, Qg, KgT, dec.
__global__ __launch_bounds__(256, 1) void chunk_prep(
    const unsigned short* __restrict__ qb, const unsigned short* __restrict__ kb,
    const float* __restrict__ vb, const float2* __restrict__ scb,
    unsigned short* __restrict__ Wg, unsigned short* __restrict__ Ubg,
    unsigned short* __restrict__ Attg, unsigned short* __restrict__ Qgg,
    unsigned short* __restrict__ KgTg, float* __restrict__ decg) {
  __shared__ unsigned short Kb_s[64 * 128];
  __shared__ unsigned short Qb_s[64 * 128];     // later reused as KbgT [128][64]
  __shared__ unsigned short VbT_s[256 * 64];    // beta*V transposed
  __shared__ unsigned short Mb_s[4096];         // I + A (bf16)
  __shared__ unsigned short Xrow_s[4096];       // X row-major bf16
  __shared__ unsigned short Xt_s[4096];         // X^T bf16
  __shared__ unsigned short Yt_s[4096];         // Y^T bf16
  __shared__ float F1_s[4096];                  // X fp32
  __shared__ float F2_s[4096];                  // GEMM scratch fp32
  __shared__ float carr_s[64];
  __shared__ float beta_s[64];

  const int tid = threadIdx.x;
  const int ch = blockIdx.x;
  const int bh = ch >> 4, p = ch & 15;
  const int b = bh >> 3, h = bh & 7;
  const size_t tbase = (size_t)b * T_LEN + p * 64;

  // 1. per-step scalars + cumulative log-decay (inclusive scan over 64 lanes of wave 0)
  if (tid < 64) {
    float2 gb = scb[(tbase + tid) * 8 + h];
    float c = gb.x;
#pragma unroll
    for (int d = 1; d < 64; d <<= 1) {
      float y = __shfl_up(c, d);
      if (tid >= d) c += y;
    }
    carr_s[tid] = c;
    beta_s[tid] = gb.y;
    if (tid == 63) decg[ch] = __expf(c);
  }
  // 2. stage K, Q chunks (bf16) via global_load_lds
#pragma unroll
  for (int i = 0; i < 4; ++i) {
    const int f = i * 256 + tid;
    const int t = f >> 4, c8 = f & 15;
    GLDS(kb + (tbase + t) * 1024 + h * 128 + c8 * 8, (char*)Kb_s + f * 16);
    GLDS(qb + (tbase + t) * 1024 + h * 128 + c8 * 8, (char*)Qb_s + f * 16);
  }
  __syncthreads();
  // 3. VbT[v][t] = bf16(beta_t * v[t][v])
#pragma unroll
  for (int i = 0; i < 16; ++i) {
    const int m = i * 256 + tid;
    const int t = m >> 6, c4 = (m & 63) * 4;
    float4 v = *(const float4*)(vb + (tbase + t) * 2048 + h * 256 + c4);
    const float bt = beta_s[t];
    VbT_s[(c4 + 0) * 64 + t] = f2bf(bt * v.x);
    VbT_s[(c4 + 1) * 64 + t] = f2bf(bt * v.y);
    VbT_s[(c4 + 2) * 64 + t] = f2bf(bt * v.z);
    VbT_s[(c4 + 3) * 64 + t] = f2bf(bt * v.w);
  }
  __syncthreads();
  // 4. A_raw = K K^T
  mm_nt_lds<64, 64, 128, false>(Kb_s, Kb_s, F2_s, nullptr, 0, tid);
  __syncthreads();
  // 5. M = I + A, X0 = I - A  (A[t][j] = beta_t exp(c_t-c_j) (k_t.k_j), j<t)
#pragma unroll
  for (int i = 0; i < 16; ++i) {
    const int idx = i * 256 + tid;
    const int t = idx >> 6, j = idx & 63;
    const float kk = F2_s[idx];
    const float av = (j < t) ? beta_s[t] * __expf(carr_s[t] - carr_s[j]) * kk : 0.f;
    const float dg = (t == j) ? 1.f : 0.f;
    Mb_s[idx] = f2bf(dg + av);
    const float x0 = dg - av;
    F1_s[idx] = x0;
    const unsigned short xb = f2bf(x0);
    Xrow_s[idx] = xb;
    Xt_s[j * 64 + t] = xb;
  }
  __syncthreads();
  // 6. Newton x5: X <- X(2I - M X)   (exact: A nilpotent, err = A^64 = 0)
  for (int it = 0; it < 5; ++it) {
    mm_nt_lds<64, 64, 64, false>(Mb_s, Xt_s, F2_s, nullptr, 0, tid);   // Y = M X
    __syncthreads();
#pragma unroll
    for (int i = 0; i < 16; ++i) {
      const int idx = i * 256 + tid;
      Yt_s[(idx & 63) * 64 + (idx >> 6)] = f2bf(F2_s[idx]);
    }
    __syncthreads();
    mm_nt_lds<64, 64, 64, false>(Xrow_s, Yt_s, F2_s, nullptr, 0, tid); // P = X Y
    __syncthreads();
#pragma unroll
    for (int i = 0; i < 16; ++i) {
      const int idx = i * 256 + tid;
      const float xn = 2.f * F1_s[idx] - F2_s[idx];
      F1_s[idx] = xn;
      const unsigned short xb = f2bf(xn);
      Xrow_s[idx] = xb;
      Xt_s[(idx & 63) * 64 + (idx >> 6)] = xb;
    }
    __syncthreads();
  }
  // 7. AttRaw = Q K^T
  mm_nt_lds<64, 64, 128, false>(Qb_s, Kb_s, F2_s, nullptr, 0, tid);
  __syncthreads();
  const float ctot = carr_s[63];
  // 8. Att (incl diag), Qg, KgT -> global
#pragma unroll
  for (int i = 0; i < 16; ++i) {
    const int idx = i * 256 + tid;
    const int t = idx >> 6, j = idx & 63;
    const float av = (j <= t) ? __expf(carr_s[t] - carr_s[j]) * F2_s[idx] : 0.f;
    Attg[(size_t)ch * 4096 + idx] = f2bf(av);
  }
#pragma unroll
  for (int i = 0; i < 32; ++i) {
    const int idx = i * 256 + tid;
    const int t = idx >> 7, d = idx & 127;
    Qgg[(size_t)ch * 8192 + idx] = f2bf(__expf(carr_s[t]) * bf2f(Qb_s[idx]));
  }
#pragma unroll
  for (int i = 0; i < 32; ++i) {
    const int idx = i * 256 + tid;
    const int d = idx >> 6, t = idx & 63;
    KgTg[(size_t)ch * 8192 + idx] = f2bf(__expf(ctot - carr_s[t]) * bf2f(Kb_s[t * 128 + d]));
  }
  __syncthreads();   // Qb reads done before reuse
  // 9. KbgT[d][t] = bf16(beta_t exp(c_t) k[t][d])  (into Qb space)
  unsigned short* KbgT = Qb_s;
#pragma unroll
  for (int i = 0; i < 32; ++i) {
    const int idx = i * 256 + tid;
    const int d = idx >> 6, t = idx & 63;
    KbgT[idx] = f2bf(beta_s[t] * __expf(carr_s[t]) * bf2f(Kb_s[t * 128 + d]));
  }
  __syncthreads();
  // 10. W = T (betaG.K)  [64x128];  Ub = T (betaV)  [64x256]  -> global bf16
  mm_nt_lds<64, 128, 64, true>(Xrow_s, KbgT, nullptr, Wg + (size_t)ch * 8192, 128, tid);
  mm_nt_lds<64, 256, 64, true>(Xrow_s, VbT_s, nullptr, Ubg + (size_t)ch * 16384, 256, tid);
}

// ---------------- phase 2: serial chunk recurrence (MFMA), 16 bh x 8 v-blocks ----------------
// stage buffer (ushort offsets): W@0(8192) Att@8192(4096) Qg@12288(8192) KgT@20480(8192) Ub@28672(2048)
__device__ __forceinline__ void p2_stage(
    const unsigned short* Wg, const unsigned short* Attg, const unsigned short* Qgg,
    const unsigned short* KgTg, const unsigned short* Ubg,
    int ch, int vb, unsigned short* buf, int tid) {
#pragma unroll
  for (int i = 0; i < 4; ++i) {
    const int f = i * 256 + tid;
    GLDS(Wg + (size_t)ch * 8192 + f * 8, (char*)buf + f * 16);
  }
#pragma unroll
  for (int i = 0; i < 2; ++i) {
    const int f = i * 256 + tid;
    GLDS(Attg + (size_t)ch * 4096 + f * 8, (char*)(buf + 8192) + f * 16);
  }
#pragma unroll
  for (int i = 0; i < 4; ++i) {
    const int f = i * 256 + tid;
    GLDS(Qgg + (size_t)ch * 8192 + f * 8, (char*)(buf + 12288) + f * 16);
  }
#pragma unroll
  for (int i = 0; i < 4; ++i) {
    const int f = i * 256 + tid;
    GLDS(KgTg + (size_t)ch * 8192 + f * 8, (char*)(buf + 20480) + f * 16);
  }
  {
    const int f = tid;
    const int t = f >> 2, c8 = f & 3;
    GLDS(Ubg + (size_t)ch * 16384 + t * 256 + vb * 32 + c8 * 8, (char*)(buf + 28672) + f * 16);
  }
}

__global__ __launch_bounds__(256, 1) void scan_chunks(
    const unsigned short* __restrict__ Wg, const unsigned short* __restrict__ Ubg,
    const unsigned short* __restrict__ Attg, const unsigned short* __restrict__ Qgg,
    const unsigned short* __restrict__ KgTg, const float* __restrict__ decg,
    float* __restrict__ osc) {
  __shared__ float StT_s[32 * 128];            // S^T fp32 [vcol][d]
  __shared__ unsigned short StTb_s[32 * 128];  // S^T bf16
  __shared__ unsigned short uT_s[32 * 64];     // u^T bf16 [vcol][t]
  __shared__ unsigned short stage_s[2][30720];

  const int tid = threadIdx.x;
  const int w = tid >> 6, l = tid & 63;
  const int row = l & 15, ko = (l >> 4) * 8;
  const int blk = blockIdx.x;                  // vb*16 + bh  (same-bh blocks share an XCD)
  const int vb = blk >> 4, bh = blk & 15;
  const int b = bh >> 3, h = bh & 7;

  for (int i = tid; i < 4096; i += 256) { StT_s[i] = 0.f; StTb_s[i] = 0; }
  p2_stage(Wg, Attg, Qgg, KgTg, Ubg, bh * 16, vb, stage_s[0], tid);

  for (int p = 0; p < 16; ++p) {
    unsigned short* bufc = stage_s[p & 1];
    const unsigned short* Wl   = bufc;
    const unsigned short* Attl = bufc + 8192;
    const unsigned short* Qgl  = bufc + 12288;
    const unsigned short* KgTl = bufc + 20480;
    const unsigned short* Ubl  = bufc + 28672;
    __syncthreads();   // staged buf + previous S writes visible (vmcnt drained)

    // ---- u = Ub - W S : acc [64x32], 8 tiles, 2/wave ----
    f32x4 uacc[2];
#pragma unroll
    for (int i = 0; i < 2; ++i)
#pragma unroll
      for (int r = 0; r < 4; ++r) uacc[i][r] = 0.f;
#pragma unroll
    for (int i = 0; i < 2; ++i) {
      const int ti = w + 4 * i;
      const int rt = ti >> 1, ct = ti & 1;
#pragma unroll
      for (int kk = 0; kk < 4; ++kk) {
        bf16x8 af = *(const bf16x8*)(Wl + (rt * 16 + row) * 128 + kk * 32 + ko);
        bf16x8 bf = *(const bf16x8*)(StTb_s + (ct * 16 + row) * 128 + kk * 32 + ko);
        uacc[i] = __builtin_amdgcn_mfma_f32_16x16x32_bf16(af, bf, uacc[i], 0, 0, 0);
      }
    }
#pragma unroll
    for (int i = 0; i < 2; ++i) {
      const int ti = w + 4 * i;
      const int rt = ti >> 1, ct = ti & 1;
      const int r0 = rt * 16 + (l >> 4) * 4;
      const int col = ct * 16 + (l & 15);
#pragma unroll
      for (int r = 0; r < 4; ++r) {
        const int t = r0 + r;
        const float ubv = bf2f(Ubl[t * 32 + col]);
        uT_s[col * 64 + t] = f2bf(ubv - uacc[i][r]);
      }
    }
    __syncthreads();   // uT ready
    if (p < 15)
      p2_stage(Wg, Attg, Qgg, KgTg, Ubg, bh * 16 + p + 1, vb, stage_s[(p + 1) & 1], tid);

    // ---- O = Qg S + Att u : acc [64x32] ----
    f32x4 oacc[2];
#pragma unroll
    for (int i = 0; i < 2; ++i)
#pragma unroll
      for (int r = 0; r < 4; ++r) oacc[i][r] = 0.f;
#pragma unroll
    for (int i = 0; i < 2; ++i) {
      const int ti = w + 4 * i;
      const int rt = ti >> 1, ct = ti & 1;
#pragma unroll
      for (int kk = 0; kk < 4; ++kk) {
        bf16x8 af = *(const bf16x8*)(Qgl + (rt * 16 + row) * 128 + kk * 32 + ko);
        bf16x8 bf = *(const bf16x8*)(StTb_s + (ct * 16 + row) * 128 + kk * 32 + ko);
        oacc[i] = __builtin_amdgcn_mfma_f32_16x16x32_bf16(af, bf, oacc[i], 0, 0, 0);
      }
#pragma unroll
      for (int kk = 0; kk < 2; ++kk) {
        bf16x8 af = *(const bf16x8*)(Attl + (rt * 16 + row) * 64 + kk * 32 + ko);
        bf16x8 bf = *(const bf16x8*)(uT_s + (ct * 16 + row) * 64 + kk * 32 + ko);
        oacc[i] = __builtin_amdgcn_mfma_f32_16x16x32_bf16(af, bf, oacc[i], 0, 0, 0);
      }
    }
    // ---- Snew^T = dec*S^T + (u^T)(KgT^T) : acc [32x128], 16 tiles, 4/wave ----
    f32x4 sacc[4];
#pragma unroll
    for (int i = 0; i < 4; ++i)
#pragma unroll
      for (int r = 0; r < 4; ++r) sacc[i][r] = 0.f;
#pragma unroll
    for (int i = 0; i < 4; ++i) {
      const int ti = w + 4 * i;
      const int srt = ti >> 3, sct = ti & 7;
#pragma unroll
      for (int kk = 0; kk < 2; ++kk) {
        bf16x8 af = *(const bf16x8*)(uT_s + (srt * 16 + row) * 64 + kk * 32 + ko);
        bf16x8 bf = *(const bf16x8*)(KgTl + (sct * 16 + row) * 64 + kk * 32 + ko);
        sacc[i] = __builtin_amdgcn_mfma_f32_16x16x32_bf16(af, bf, sacc[i], 0, 0, 0);
      }
    }
    const float dec = decg[bh * 16 + p];
    __syncthreads();   // all reads of StT/StTb done before overwrite

    // epilogues
#pragma unroll
    for (int i = 0; i < 2; ++i) {
      const int ti = w + 4 * i;
      const int rt = ti >> 1, ct = ti & 1;
      const int r0 = rt * 16 + (l >> 4) * 4;
      const int col = ct * 16 + (l & 15);
#pragma unroll
      for (int r = 0; r < 4; ++r) {
        const size_t trow = (size_t)b * T_LEN + p * 64 + r0 + r;
        osc[(trow * 8 + h) * 256 + vb * 32 + col] = oacc[i][r];
      }
    }
#pragma unroll
    for (int i = 0; i < 4; ++i) {
      const int ti = w + 4 * i;
      const int srt = ti >> 3, sct = ti & 7;
      const int r0 = srt * 16 + (l >> 4) * 4;
      const int cold = sct * 16 + (l & 15);
#pragma unroll
      for (int r = 0; r < 4; ++r) {
        const int idx = (r0 + r) * 128 + cold;
        const float sn = fmaf(dec, StT_s[idx], sacc[i][r]);
        StT_s[idx] = sn;
        StTb_s[idx] = f2bf(sn);
      }
    }
  }
}

// ---------------- gated RMSNorm + silu(gate) -> bf16 ----------------
__global__ __launch_bounds__(256) void rmsgate(
    const float* __restrict__ ob, const unsigned short* __restrict__ Y,
    const float* __restrict__ onw, unsigned short* __restrict__ Obf) {
  const int bt = blockIdx.x;
  const int tid = threadIdx.x;
  const int c = tid * 8;                // head = c/256 = tid/32
  const float* orow = ob + (size_t)bt * 2048 + c;
  const unsigned short* grow = Y + (size_t)bt * NBIG + 4096 + c;
  const float4 o0 = *(const float4*)orow, o1 = *(const float4*)(orow + 4);
  const ushort4 g0 = *(const ushort4*)grow, g1 = *(const ushort4*)(grow + 4);
  const float ov[8] = {o0.x, o0.y, o0.z, o0.w, o1.x, o1.y, o1.z, o1.w};
  const float gv[8] = {bf2f(g0.x), bf2f(g0.y), bf2f(g0.z), bf2f(g0.w),
                       bf2f(g1.x), bf2f(g1.y), bf2f(g1.z), bf2f(g1.w)};
  float ss = 0.f;
#pragma unroll
  for (int e = 0; e < 8; ++e) ss += ov[e] * ov[e];
#pragma unroll
  for (int m = 16; m >= 1; m >>= 1) ss += __shfl_xor(ss, m);
  const float rn = rsqrtf(ss * (1.f / 256.f) + 1e-5f);
  const int dv = c & 255;
  unsigned short rr[8];
#pragma unroll
  for (int e = 0; e < 8; ++e) {
    const float val = ov[e] * rn * onw[dv + e] * silu_f(gv[e]);
    rr[e] = f2bf(val);
  }
  ushort4 r0 = {rr[0], rr[1], rr[2], rr[3]};
  ushort4 r1 = {rr[4], rr[5], rr[6], rr[7]};
  *(ushort4*)(Obf + (size_t)bt * 2048 + c) = r0;
  *(ushort4*)(Obf + (size_t)bt * 2048 + c + 4) = r1;
}

extern "C" void kernel_launch(void* const* d_in, const int* in_sizes, int n_in,
                              void* d_out, int out_size, void* d_ws, size_t ws_size,
                              hipStream_t stream) {
  (void)in_sizes; (void)n_in; (void)out_size; (void)ws_size;
  const float* h    = (const float*)d_in[0];
  const float* qw   = (const float*)d_in[1];
  const float* kw   = (const float*)d_in[2];
  const float* vw   = (const float*)d_in[3];
  const float* aw   = (const float*)d_in[4];
  const float* bw   = (const float*)d_in[5];
  const float* gw   = (const float*)d_in[6];
  const float* ow   = (const float*)d_in[7];
  const float* qcw  = (const float*)d_in[8];
  const float* kcw  = (const float*)d_in[9];
  const float* vcw  = (const float*)d_in[10];
  const float* Alog = (const float*)d_in[11];
  const float* dtb  = (const float*)d_in[12];
  const float* onw  = (const float*)d_in[13];

  char* ws = (char*)d_ws;
  size_t off = 0;
  auto alloc = [&](size_t bytes) {
    char* p = ws + off;
    off = (off + bytes + 255) & ~(size_t)255;
    return p;
  };
  unsigned short* qb   = (unsigned short*)alloc(2048ull * 1024 * 2);
  unsigned short* kb   = (unsigned short*)alloc(2048ull * 1024 * 2);
  float* vb            = (float*)alloc(2048ull * 2048 * 4);
  float2* scb          = (float2*)alloc(2048ull * 8 * 8);
  unsigned short* hbf  = (unsigned short*)alloc(2048ull * 2048 * 2);
  unsigned short* Wb   = (unsigned short*)alloc((size_t)NBIG * 2048 * 2);
  unsigned short* owb  = (unsigned short*)alloc(2048ull * 2048 * 2);
  unsigned short* Ybf  = (unsigned short*)alloc(2048ull * NBIG * 2);
  float* osc           = (float*)alloc(2048ull * 2048 * 4);
  unsigned short* Obf  = (unsigned short*)alloc(2048ull * 2048 * 2);
  unsigned short* Wg   = (unsigned short*)alloc(256ull * 8192 * 2);
  unsigned short* Ubg  = (unsigned short*)alloc(256ull * 16384 * 2);
  unsigned short* Attg = (unsigned short*)alloc(256ull * 4096 * 2);
  unsigned short* Qgg  = (unsigned short*)alloc(256ull * 8192 * 2);
  unsigned short* KgTg = (unsigned short*)alloc(256ull * 8192 * 2);
  float* decg          = (float*)alloc(256ull * 4);

  cvt_bf16<<<4096, 256, 0, stream>>>(h, hbf, 1048576);
  build_w<<<12800, 256, 0, stream>>>(qw, kw, vw, gw, aw, bw, Wb);
  cvt_bf16<<<4096, 256, 0, stream>>>(ow, owb, 1048576);
  gemm_big<<<200, 512, 0, stream>>>((const bf16*)hbf, (const bf16*)Wb, Ybf, 2048, NBIG, 2048);
  convnorm<<<2048, 256, 0, stream>>>(Ybf, qcw, kcw, vcw, Alog, dtb, qb, kb, vb, scb);
  chunk_prep<<<256, 256, 0, stream>>>(qb, kb, vb, scb, Wg, Ubg, Attg, Qgg, KgTg, decg);
  scan_chunks<<<128, 256, 0, stream>>>(Wg, Ubg, Attg, Qgg, KgTg, decg, osc);
  rmsgate<<<2048, 256, 0, stream>>>(osc, Ybf, onw, Obf);
  gemm_nt<false><<<dim3(16, 16), 256, 0, stream>>>((const bf16*)Obf, (const bf16*)owb,
                                                   d_out, 2048, 2048, 2048);
}